// Round 1
// baseline (6317.826 us; speedup 1.0000x reference)
//
#include <hip/hip_runtime.h>
#include <cstdint>

typedef unsigned short u16;
typedef __attribute__((ext_vector_type(8))) short bf16x8;
typedef __attribute__((ext_vector_type(8))) unsigned short u16x8;
typedef __attribute__((ext_vector_type(4))) float f32x4;

struct us4 { u16 a, b, c, d; };

__device__ __forceinline__ u16 f2bf(float f) {
    uint32_t u = __float_as_uint(f);
    uint32_t r = (u + 0x7FFFu + ((u >> 16) & 1u)) >> 16;
    return (u16)r;
}
__device__ __forceinline__ float bf2f(u16 h) { return __uint_as_float(((uint32_t)h) << 16); }
__device__ __forceinline__ float sigm(float x) { return 1.f / (1.f + expf(-x)); }
__device__ __forceinline__ float dot4(float4 a, float4 b) {
    return a.x * b.x + a.y * b.y + a.z * b.z + a.w * b.w;
}
__device__ __forceinline__ float wave_sum(float v) {
#pragma unroll
    for (int o = 32; o; o >>= 1) v += __shfl_down(v, o);
    return v;
}
__device__ __forceinline__ float wave_max(float v) {
#pragma unroll
    for (int o = 32; o; o >>= 1) v = fmaxf(v, __shfl_down(v, o));
    return v;
}

// ---------------------------------------------------------------------------
// Generic 128x128-tile BT GEMM: C[M,N] = A[M,K] * B[N,K]^T
// SPLIT: A,B given as (hi,lo) bf16 pairs; 3 MFMAs per frag-pair -> fp32-grade.
// AMODE 0: A row-major (lda, strideA*z). AMODE 1: scores gather from h_all:
//          row m (per batch z): t=m%40, dd=m/40 -> h_all[(t+1)*128 + z*16+dd].
// EPI 0: C=acc  1: C=acc+bias[col]  2: CH/CL = hi/lo bf16
//     3: CH = bf16(tanh(acc))       4: CH = bf16(acc)
// All M multiples of 128, N multiples of 128, K multiples of 32 by construction.
// ---------------------------------------------------------------------------
template <bool SPLIT, int AMODE, int EPI>
__global__ __launch_bounds__(256) void gemm_bt(
    const u16* __restrict__ AH, const u16* __restrict__ AL, int lda, long strideA,
    const u16* __restrict__ BH, const u16* __restrict__ BL, int ldb, long strideB,
    float* __restrict__ C, u16* __restrict__ CH, u16* __restrict__ CL,
    int ldc, long strideC, const float* __restrict__ bias, int K)
{
    constexpr int TL = 40;           // padded LDS row stride (bf16 elems)
    constexpr int CHK = 128 * TL;
    __shared__ u16 sm[(SPLIT ? 4 : 2) * CHK];
    u16* sAH = sm;
    u16* sBH = sm + CHK;
    u16* sAL = SPLIT ? sm + 2 * CHK : sm;
    u16* sBL = SPLIT ? sm + 3 * CHK : sm;

    const int tid = threadIdx.x;
    const int lane = tid & 63, w = tid >> 6;
    const int wm = w >> 1, wn = w & 1;
    const int lane15 = lane & 15, q8 = (lane >> 4) << 3;
    const int n0 = blockIdx.x * 128, m0 = blockIdx.y * 128, z = blockIdx.z;

    const int r = tid >> 2, c8 = (tid & 3) * 8;

    long aoff[2], boff[2];
#pragma unroll
    for (int h2 = 0; h2 < 2; ++h2) {
        int row = r + (h2 << 6);
        if (AMODE == 0) {
            aoff[h2] = strideA * z + (long)(m0 + row) * lda + c8;
        } else {
            int m = m0 + row;
            int t = m % 40, dd = m / 40;
            aoff[h2] = ((long)(t + 1) * 128 + (z * 16 + dd)) * 512 + c8;
        }
        boff[h2] = strideB * z + (long)(n0 + row) * ldb + c8;
    }

    f32x4 acc[4][4] = {};

    for (int k0 = 0; k0 < K; k0 += 32) {
#pragma unroll
        for (int h2 = 0; h2 < 2; ++h2) {
            int row = r + (h2 << 6);
            int sidx = row * TL + c8;
            *(u16x8*)&sAH[sidx] = *(const u16x8*)&AH[aoff[h2] + k0];
            *(u16x8*)&sBH[sidx] = *(const u16x8*)&BH[boff[h2] + k0];
            if constexpr (SPLIT) {
                *(u16x8*)&sAL[sidx] = *(const u16x8*)&AL[aoff[h2] + k0];
                *(u16x8*)&sBL[sidx] = *(const u16x8*)&BL[boff[h2] + k0];
            }
        }
        __syncthreads();

        bf16x8 a[4], b[4], al[4], bl[4];
#pragma unroll
        for (int i = 0; i < 4; ++i) {
            a[i] = *(const bf16x8*)&sAH[(wm * 64 + i * 16 + lane15) * TL + q8];
            b[i] = *(const bf16x8*)&sBH[(wn * 64 + i * 16 + lane15) * TL + q8];
            if constexpr (SPLIT) {
                al[i] = *(const bf16x8*)&sAL[(wm * 64 + i * 16 + lane15) * TL + q8];
                bl[i] = *(const bf16x8*)&sBL[(wn * 64 + i * 16 + lane15) * TL + q8];
            }
        }
#pragma unroll
        for (int mt = 0; mt < 4; ++mt)
#pragma unroll
            for (int nt = 0; nt < 4; ++nt) {
                acc[mt][nt] = __builtin_amdgcn_mfma_f32_16x16x32_bf16(a[mt], b[nt], acc[mt][nt], 0, 0, 0);
                if constexpr (SPLIT) {
                    acc[mt][nt] = __builtin_amdgcn_mfma_f32_16x16x32_bf16(a[mt], bl[nt], acc[mt][nt], 0, 0, 0);
                    acc[mt][nt] = __builtin_amdgcn_mfma_f32_16x16x32_bf16(al[mt], b[nt], acc[mt][nt], 0, 0, 0);
                }
            }
        __syncthreads();
    }

#pragma unroll
    for (int mt = 0; mt < 4; ++mt)
#pragma unroll
        for (int nt = 0; nt < 4; ++nt)
#pragma unroll
            for (int i = 0; i < 4; ++i) {
                int row = m0 + wm * 64 + mt * 16 + ((lane >> 4) << 2) + i;
                int col = n0 + wn * 64 + nt * 16 + lane15;
                long off = strideC * z + (long)row * ldc + col;
                float v = acc[mt][nt][i];
                if constexpr (EPI == 0) {
                    C[off] = v;
                } else if constexpr (EPI == 1) {
                    C[off] = v + bias[col];
                } else if constexpr (EPI == 2) {
                    u16 h_ = f2bf(v);
                    CH[off] = h_;
                    CL[off] = f2bf(v - bf2f(h_));
                } else if constexpr (EPI == 3) {
                    CH[off] = f2bf(tanhf(v));
                } else {
                    CH[off] = f2bf(v);
                }
            }
}

// ---------------------------------------------------------------------------
// Word-level LSTM step (fused split-bf16 MFMA h@Whh^T + LSTM elementwise).
// grid 64 x 256. Wave W: rows r0=(W>>5)*16 (b2), units u0=(W&31)*16.
// gates = xW[t] (precomputed x@Wih^T + biases, fp32) + h@Whh^T (split-MFMA).
// ---------------------------------------------------------------------------
__global__ __launch_bounds__(256) void word_step(
    const u16* __restrict__ hH, const u16* __restrict__ hL,
    u16* __restrict__ hHo, u16* __restrict__ hLo,
    const u16* __restrict__ WhhH, const u16* __restrict__ WhhL,
    const float* __restrict__ xWt, float* __restrict__ wc)
{
    const int tid = threadIdx.x;
    const int w = tid >> 6, lane = tid & 63;
    const int W = blockIdx.x * 4 + w;
    const int r0 = (W >> 5) << 4;
    const int u0 = (W & 31) << 4;
    const int lane15 = lane & 15, q8 = (lane >> 4) << 3;

    f32x4 acc[4] = {};
    const long arow = (long)(r0 + lane15) * 512 + q8;
    long brow[4];
#pragma unroll
    for (int g = 0; g < 4; ++g) brow[g] = (long)(g * 512 + u0 + lane15) * 512 + q8;

    for (int k0 = 0; k0 < 512; k0 += 32) {
        bf16x8 aH = *(const bf16x8*)&hH[arow + k0];
        bf16x8 aL = *(const bf16x8*)&hL[arow + k0];
#pragma unroll
        for (int g = 0; g < 4; ++g) {
            bf16x8 bH = *(const bf16x8*)&WhhH[brow[g] + k0];
            bf16x8 bL = *(const bf16x8*)&WhhL[brow[g] + k0];
            acc[g] = __builtin_amdgcn_mfma_f32_16x16x32_bf16(aH, bH, acc[g], 0, 0, 0);
            acc[g] = __builtin_amdgcn_mfma_f32_16x16x32_bf16(aH, bL, acc[g], 0, 0, 0);
            acc[g] = __builtin_amdgcn_mfma_f32_16x16x32_bf16(aL, bH, acc[g], 0, 0, 0);
        }
    }

#pragma unroll
    for (int i = 0; i < 4; ++i) {
        int b2 = r0 + ((lane >> 4) << 2) + i;
        int u = u0 + lane15;
        const float* xr = xWt + (long)b2 * 2048;
        float gi = acc[0][i] + xr[u];
        float gf = acc[1][i] + xr[512 + u];
        float gg = acc[2][i] + xr[1024 + u];
        float go = acc[3][i] + xr[1536 + u];
        long cidx = (long)b2 * 512 + u;
        float cc = wc[cidx];
        cc = sigm(gf) * cc + sigm(gi) * tanhf(gg);
        wc[cidx] = cc;
        float hv = sigm(go) * tanhf(cc);
        u16 hh = f2bf(hv);
        hHo[cidx] = hh;
        hLo[cidx] = f2bf(hv - bf2f(hh));
    }
}

// ------------------------- doc-level loop kernels --------------------------
__global__ void doc_init(const float* __restrict__ enc0, const float* __restrict__ emb,
                         float* __restrict__ dh, float* __restrict__ dc, float* __restrict__ dx)
{
    int idx = blockIdx.x * 256 + threadIdx.x;   // 4096
    int b = idx >> 9, d = idx & 511;
    const float* p = enc0 + (long)b * 400 * 512 + d;
    float s = 0.f;
#pragma unroll 4
    for (int j = 0; j < 400; ++j) s += p[(long)j * 512];
    s *= (1.f / 400.f);
    dh[idx] = s;
    dc[idx] = s;
    dx[idx] = emb[2 * 512 + d];                 // embed_tokens[SOD]
}

__global__ __launch_bounds__(256) void doc_lstm(
    const float* __restrict__ x, const float* __restrict__ hin,
    float* __restrict__ hout, float* __restrict__ c,
    const float* __restrict__ wih, const float* __restrict__ whh,
    const float* __restrict__ bih, const float* __restrict__ bhh)
{
    int tid = threadIdx.x;
    int b = tid & 7, ul = tid >> 3;
    int u = blockIdx.x * 32 + ul;
    const float4* xv = (const float4*)(x + b * 512);
    const float4* hv = (const float4*)(hin + b * 512);
    float acc[4];
#pragma unroll
    for (int g = 0; g < 4; ++g) {
        int row = g * 512 + u;
        const float4* wi = (const float4*)(wih + (long)row * 512);
        const float4* wh = (const float4*)(whh + (long)row * 512);
        float s = 0.f;
#pragma unroll 4
        for (int k = 0; k < 128; ++k) s += dot4(wi[k], xv[k]) + dot4(wh[k], hv[k]);
        acc[g] = s + bih[row] + bhh[row];
    }
    float cc = c[b * 512 + u];
    cc = sigm(acc[1]) * cc + sigm(acc[0]) * tanhf(acc[2]);
    c[b * 512 + u] = cc;
    hout[b * 512 + u] = sigm(acc[3]) * tanhf(cc);
}

__global__ __launch_bounds__(512) void doc_attend(
    const float* __restrict__ h, const float* __restrict__ enc0,
    const unsigned char* __restrict__ mask,
    const float* __restrict__ wq, const float* __restrict__ wo,
    float* __restrict__ doc_x, float* __restrict__ sentS,
    float* __restrict__ out_last, int t)
{
    const int b = blockIdx.x, tid = threadIdx.x;
    const int wv = tid >> 6, lane = tid & 63;
    __shared__ float hs[512], qs[512], sc[400], ctxs[512], red[8];

    hs[tid] = h[b * 512 + tid];
    __syncthreads();

    {   // q = h @ wq^T
        const float4* wr = (const float4*)(wq + (long)tid * 512);
        const float4* hv = (const float4*)hs;
        float s = 0.f;
#pragma unroll 8
        for (int k = 0; k < 128; ++k) s += dot4(wr[k], hv[k]);
        qs[tid] = s;
    }
    __syncthreads();

    // scores: s[j] = enc0[b,j,:] . q
    for (int j = wv; j < 400; j += 8) {
        const float4* er = (const float4*)(enc0 + ((long)b * 400 + j) * 512);
        const float4* qv = (const float4*)qs;
        float s = dot4(er[lane * 2], qv[lane * 2]) + dot4(er[lane * 2 + 1], qv[lane * 2 + 1]);
        s = wave_sum(s);
        if (lane == 0) sc[j] = mask[b * 400 + j] ? -1e9f : s;
    }
    __syncthreads();

    // softmax over 400
    float v = (tid < 400) ? sc[tid] : -1e30f;
    float mv = wave_max(v);
    if (lane == 0) red[wv] = mv;
    __syncthreads();
    if (tid == 0) {
        float M = red[0];
#pragma unroll
        for (int i = 1; i < 8; ++i) M = fmaxf(M, red[i]);
        red[0] = M;
    }
    __syncthreads();
    const float M = red[0];
    float e = (tid < 400) ? expf(v - M) : 0.f;
    __syncthreads();
    float sv = wave_sum(e);
    if (lane == 0) red[wv] = sv;
    __syncthreads();
    if (tid == 0) {
        float S = 0.f;
#pragma unroll
        for (int i = 0; i < 8; ++i) S += red[i];
        red[0] = S;
    }
    __syncthreads();
    if (tid < 400) sc[tid] = e / red[0];
    __syncthreads();

    // ctx[e] = sum_j p[j] * enc0[b,j,e]
    {
        const float* ep = enc0 + (long)b * 400 * 512 + tid;
        float s = 0.f;
#pragma unroll 4
        for (int j = 0; j < 400; ++j) s += sc[j] * ep[(long)j * 512];
        ctxs[tid] = s;
    }
    __syncthreads();

    // out = tanh([ctx, h] @ wo^T)
    {
        const float4* wr = (const float4*)(wo + (long)tid * 1024);
        const float4* cv = (const float4*)ctxs;
        const float4* hv = (const float4*)hs;
        float s = 0.f;
#pragma unroll 8
        for (int k = 0; k < 128; ++k) s += dot4(wr[k], cv[k]) + dot4(wr[128 + k], hv[k]);
        float val = tanhf(s);
        doc_x[b * 512 + tid] = val;
        sentS[((b << 4) + t) * 512 + tid] = val;
        if (t == 15) out_last[b * 512 + tid] = val;
    }
}

// ------------------------------ prep kernels -------------------------------
__global__ void split_f32(const float* __restrict__ src, u16* __restrict__ H,
                          u16* __restrict__ L, long n4)
{
    long i = (long)blockIdx.x * 256 + threadIdx.x;
    if (i >= n4) return;
    float4 v = ((const float4*)src)[i];
    u16 h0 = f2bf(v.x), h1 = f2bf(v.y), h2 = f2bf(v.z), h3 = f2bf(v.w);
    ((us4*)H)[i] = {h0, h1, h2, h3};
    ((us4*)L)[i] = {f2bf(v.x - bf2f(h0)), f2bf(v.y - bf2f(h1)),
                    f2bf(v.z - bf2f(h2)), f2bf(v.w - bf2f(h3))};
}

__global__ void tobf16(const float* __restrict__ src, u16* __restrict__ H, long n4)
{
    long i = (long)blockIdx.x * 256 + threadIdx.x;
    if (i >= n4) return;
    float4 v = ((const float4*)src)[i];
    ((us4*)H)[i] = {f2bf(v.x), f2bf(v.y), f2bf(v.z), f2bf(v.w)};
}

__global__ void wq_transpose(const float* __restrict__ wq, u16* __restrict__ H, u16* __restrict__ L)
{
    int idx = blockIdx.x * 256 + threadIdx.x;   // 262144 -> out[e][d]
    int e = idx >> 9, d = idx & 511;
    float v = wq[(long)d * 512 + e];
    u16 h = f2bf(v);
    H[idx] = h;
    L[idx] = f2bf(v - bf2f(h));
}

__global__ void enc1t_kernel(const float* __restrict__ enc1, u16* __restrict__ out)
{
    long idx = (long)blockIdx.x * 256 + threadIdx.x;   // 8*512*416
    if (idx >= 8L * 512 * 416) return;
    int j = (int)(idx % 416);
    long be = idx / 416;
    int e = (int)(be % 512);
    int b = (int)(be / 512);
    float v = (j < 400) ? enc1[((long)b * 400 + j) * 512 + e] : 0.f;
    out[idx] = f2bf(v);
}

__global__ void pos_kernel(const int* __restrict__ toks, int* __restrict__ posb)
{
    int b2 = threadIdx.x;   // 128
    int ne = 0;
    for (int s = 0; s < 40; ++s) ne |= (toks[b2 * 40 + s] != 1);
    posb[b2] = ne ? (2 + (b2 & 15)) : 1;
}

__global__ void xin_kernel(const int* __restrict__ toks, const float* __restrict__ emb,
                           const float* __restrict__ spe, const int* __restrict__ posb,
                           u16* __restrict__ xH, u16* __restrict__ xL)
{
    int g = blockIdx.x * 256 + threadIdx.x;   // 327680
    int m = g >> 6, e0 = (g & 63) << 3;
    int t = m >> 7, b2 = m & 127;             // row m = t*128 + b2
    int tok = toks[b2 * 40 + t];
    int pos = posb[b2];
    const float* ep = emb + (long)tok * 512 + e0;
    const float* sp = spe + (long)pos * 512 + e0;
    long o = (long)m * 512 + e0;
#pragma unroll
    for (int j = 0; j < 8; ++j) {
        float v = ep[j] + sp[j];
        u16 h = f2bf(v);
        xH[o + j] = h;
        xL[o + j] = f2bf(v - bf2f(h));
    }
}

__global__ void bias_comb(const float* __restrict__ a, const float* __restrict__ b,
                          float* __restrict__ o)
{
    int i = blockIdx.x * 256 + threadIdx.x;
    if (i < 2048) o[i] = a[i] + b[i];
}

__global__ void word_init(const float* __restrict__ ss, u16* __restrict__ h0H,
                          u16* __restrict__ h0L, float* __restrict__ wc)
{
    int i = blockIdx.x * 256 + threadIdx.x;   // 65536
    float v = ss[i];
    u16 h = f2bf(v);
    h0H[i] = h;
    h0L[i] = f2bf(v - bf2f(h));
    wc[i] = v;
}

__global__ void cat_h_kernel(const u16* __restrict__ hAll, u16* __restrict__ cat)
{
    long g = (long)blockIdx.x * 256 + threadIdx.x;   // 327680
    int r = (int)(g >> 6), e0 = (int)(g & 63) << 3;
    int t = r % 40, b2 = r / 40;
    u16x8 v = *(const u16x8*)&hAll[((long)(t + 1) * 128 + b2) * 512 + e0];
    *(u16x8*)&cat[(long)r * 1024 + 512 + e0] = v;
}

__global__ __launch_bounds__(256) void word_softmax(
    const float* __restrict__ sc, const unsigned char* __restrict__ mask,
    float* __restrict__ pout, u16* __restrict__ pbf)
{
    const int r = blockIdx.x, tid = threadIdx.x;   // r = b2*40 + t
    const int b = r / 640;
    const int wv = tid >> 6, lane = tid & 63;
    __shared__ float red[4];
    const int j1 = tid + 256;
    float v0 = sc[(long)r * 512 + tid];
    if (mask[b * 400 + tid]) v0 = -1e9f;
    float v1 = -1e30f;
    if (j1 < 400) {
        v1 = sc[(long)r * 512 + j1];
        if (mask[b * 400 + j1]) v1 = -1e9f;
    }
    float mv = wave_max(fmaxf(v0, v1));
    if (lane == 0) red[wv] = mv;
    __syncthreads();
    if (tid == 0) red[0] = fmaxf(fmaxf(red[0], red[1]), fmaxf(red[2], red[3]));
    __syncthreads();
    const float M = red[0];
    float e0 = expf(v0 - M);
    float e1 = (j1 < 400) ? expf(v1 - M) : 0.f;
    __syncthreads();
    float sv = wave_sum(e0 + e1);
    if (lane == 0) red[wv] = sv;
    __syncthreads();
    if (tid == 0) red[0] = red[0] + red[1] + red[2] + red[3];
    __syncthreads();
    const float inv = 1.f / red[0];
    float p0 = e0 * inv;
    pout[(long)r * 400 + tid] = p0;
    pbf[(long)r * 416 + tid] = f2bf(p0);
    if (j1 < 400) {
        float p1 = e1 * inv;
        pout[(long)r * 400 + j1] = p1;
        pbf[(long)r * 416 + j1] = f2bf(p1);
    } else if (j1 < 416) {
        pbf[(long)r * 416 + j1] = 0;
    }
}

// ---------------------------------------------------------------------------
extern "C" void kernel_launch(void* const* d_in, const int* in_sizes, int n_in,
                              void* d_out, int out_size, void* d_ws, size_t ws_size,
                              hipStream_t stream)
{
    (void)in_sizes; (void)n_in; (void)out_size; (void)ws_size;

    const int*   toks  = (const int*)  d_in[0];
    const float* enc0  = (const float*)d_in[1];
    const float* enc1  = (const float*)d_in[2];
    const unsigned char* mask = (const unsigned char*)d_in[3];  // all-false; byte-read safe
    const float* emb   = (const float*)d_in[4];
    const float* spe   = (const float*)d_in[5];
    const float* wih_d = (const float*)d_in[6];
    const float* whh_d = (const float*)d_in[7];
    const float* bih_d = (const float*)d_in[8];
    const float* bhh_d = (const float*)d_in[9];
    const float* wq_d  = (const float*)d_in[10];
    const float* wo_d  = (const float*)d_in[11];
    const float* wih_w = (const float*)d_in[12];
    const float* whh_w = (const float*)d_in[13];
    const float* bih_w = (const float*)d_in[14];
    const float* bhh_w = (const float*)d_in[15];
    const float* wq_w  = (const float*)d_in[16];
    const float* wo_w  = (const float*)d_in[17];
    const float* fcw   = (const float*)d_in[18];
    const float* fcb   = (const float*)d_in[19];

    float* out_dec  = (float*)d_out;                  // [8,640,32000]
    float* out_attn = out_dec + 163840000L;           // [8,16,400] zeros
    float* out_watt = out_attn + 51200;               // [128,40,400]
    float* out_last = out_watt + 2048000;             // [8,512]

    char* wsp = (char*)d_ws;
    auto alloc = [&](size_t bytes) -> void* {
        void* p = wsp;
        wsp += (bytes + 255) & ~(size_t)255;
        return p;
    };

    float* xW    = (float*)alloc(40L * 128 * 2048 * 4);   // precomputed x@Wih^T + biases
    u16* hAllH   = (u16*)alloc(41L * 128 * 512 * 2);      // h slots 0..40 (hi)
    u16* hAllL   = (u16*)alloc(41L * 128 * 512 * 2);      // (lo)
    float* wc    = (float*)alloc(128L * 512 * 4);
    u16* xinH    = (u16*)alloc(5120L * 512 * 2);
    u16* xinL    = (u16*)alloc(5120L * 512 * 2);
    u16* WihH    = (u16*)alloc(2048L * 512 * 2);
    u16* WihL    = (u16*)alloc(2048L * 512 * 2);
    u16* WhhH    = (u16*)alloc(2048L * 512 * 2);
    u16* WhhL    = (u16*)alloc(2048L * 512 * 2);
    u16* wqTH    = (u16*)alloc(512L * 512 * 2);
    u16* wqTL    = (u16*)alloc(512L * 512 * 2);
    u16* enc1H   = (u16*)alloc(3200L * 512 * 2);
    u16* enc1L   = (u16*)alloc(3200L * 512 * 2);
    u16* sq1H    = (u16*)alloc(3328L * 512 * 2);          // 128 slack rows for N-pad reads
    u16* sq1L    = (u16*)alloc(3328L * 512 * 2);
    float* wsS   = (float*)alloc(5120L * 512 * 4);        // scores, ldc=512 (cols>=400 junk)
    u16* Pbf     = (u16*)alloc(5120L * 416 * 2);          // probs bf16, K-padded
    u16* enc1T   = (u16*)alloc(8L * 512 * 416 * 2);       // enc1 transposed + K-pad
    u16* catB    = (u16*)alloc(5120L * 1024 * 2);         // [ctx, h] bf16
    u16* woB     = (u16*)alloc(512L * 1024 * 2);
    u16* Alog    = (u16*)alloc(5120L * 512 * 2);          // tanh(out-proj) bf16
    u16* fcwB    = (u16*)alloc(32000L * 512 * 2);
    float* biasc = (float*)alloc(2048 * 4);
    float* dhA   = (float*)alloc(8L * 512 * 4);
    float* dhB   = (float*)alloc(8L * 512 * 4);
    float* dc    = (float*)alloc(8L * 512 * 4);
    float* dx    = (float*)alloc(8L * 512 * 4);
    float* sentS = (float*)alloc(128L * 512 * 4);
    int* posb    = (int*)alloc(128 * 4);

    // attn_scores output is all zeros
    hipMemsetAsync(out_attn, 0, 51200 * sizeof(float), stream);

    // ---- prep ----
    split_f32<<<dim3(1024), 256, 0, stream>>>(wih_w, WihH, WihL, 262144L);
    split_f32<<<dim3(1024), 256, 0, stream>>>(whh_w, WhhH, WhhL, 262144L);
    split_f32<<<dim3(1600), 256, 0, stream>>>(enc1, enc1H, enc1L, 409600L);
    wq_transpose<<<dim3(1024), 256, 0, stream>>>(wq_w, wqTH, wqTL);
    tobf16<<<dim3(512), 256, 0, stream>>>(wo_w, woB, 131072L);
    tobf16<<<dim3(16000), 256, 0, stream>>>(fcw, fcwB, 4096000L);
    enc1t_kernel<<<dim3(6656), 256, 0, stream>>>(enc1, enc1T);
    pos_kernel<<<dim3(1), 128, 0, stream>>>(toks, posb);
    xin_kernel<<<dim3(1280), 256, 0, stream>>>(toks, emb, spe, posb, xinH, xinL);
    bias_comb<<<dim3(8), 256, 0, stream>>>(bih_w, bhh_w, biasc);

    // srcq1 = enc1 @ wq_w   [3200,512]x[512,512] split-accurate -> hi/lo
    gemm_bt<true, 0, 2><<<dim3(4, 25, 1), 256, 0, stream>>>(
        enc1H, enc1L, 512, 0, wqTH, wqTL, 512, 0,
        nullptr, sq1H, sq1L, 512, 0, nullptr, 512);

    // xW = x_in @ Wih^T + (b_ih + b_hh)   [5120,512]x[2048,512]^T
    gemm_bt<true, 0, 1><<<dim3(16, 40, 1), 256, 0, stream>>>(
        xinH, xinL, 512, 0, WihH, WihL, 512, 0,
        xW, nullptr, nullptr, 2048, 0, biasc, 512);

    // ---- document-level loop (fp32) ----
    doc_init<<<dim3(16), 256, 0, stream>>>(enc0, emb, dhA, dc, dx);
    for (int t = 0; t < 16; ++t) {
        float* hin  = (t & 1) ? dhB : dhA;
        float* hout = (t & 1) ? dhA : dhB;
        doc_lstm<<<dim3(16), 256, 0, stream>>>(dx, hin, hout, dc, wih_d, whh_d, bih_d, bhh_d);
        doc_attend<<<dim3(8), 512, 0, stream>>>(hout, enc0, mask, wq_d, wo_d,
                                                dx, sentS, out_last, t);
    }

    // ---- word-level LSTM recurrence ----
    word_init<<<dim3(256), 256, 0, stream>>>(sentS, hAllH, hAllL, wc);
    for (int t = 0; t < 40; ++t) {
        word_step<<<dim3(64), 256, 0, stream>>>(
            hAllH + (long)t * 65536, hAllL + (long)t * 65536,
            hAllH + (long)(t + 1) * 65536, hAllL + (long)(t + 1) * 65536,
            WhhH, WhhL, xW + (long)t * 128 * 2048, wc);
    }

    // ---- batched word attention ----
    // scores[b2*40+t][j] = h_all[t+1][b2] . srcq1[b][j]   (split, A gathered)
    gemm_bt<true, 1, 0><<<dim3(4, 5, 8), 256, 0, stream>>>(
        hAllH, hAllL, 0, 0, sq1H, sq1L, 512, 204800L,
        wsS, nullptr, nullptr, 512, 327680L, nullptr, 512);

    word_softmax<<<dim3(5120), 256, 0, stream>>>(wsS, mask, out_watt, Pbf);

    cat_h_kernel<<<dim3(1280), 256, 0, stream>>>(hAllH, catB);

    // ctx = P @ enc1   -> cat[:, 0:512]  (plain bf16, loose path)
    gemm_bt<false, 0, 4><<<dim3(4, 5, 8), 256, 0, stream>>>(
        Pbf, nullptr, 416, 266240L, enc1T, nullptr, 416, 212992L,
        nullptr, catB, nullptr, 1024, 655360L, nullptr, 416);

    // out = tanh(cat @ wo^T) -> Alog bf16
    gemm_bt<false, 0, 3><<<dim3(4, 40, 1), 256, 0, stream>>>(
        catB, nullptr, 1024, 0, woB, nullptr, 1024, 0,
        nullptr, Alog, nullptr, 512, 0, nullptr, 1024);

    // logits = out @ fc_w^T + fc_b -> dec_outs (fp32)
    gemm_bt<false, 0, 1><<<dim3(250, 40, 1), 256, 0, stream>>>(
        Alog, nullptr, 512, 0, fcwB, nullptr, 512, 0,
        out_dec, nullptr, nullptr, 32000, 0, fcb, 512);
}

// Round 3
// 3190.987 us; speedup vs baseline: 1.9799x; 1.9799x over previous
//
#include <hip/hip_runtime.h>
#include <cstdint>

typedef unsigned short u16;
typedef __attribute__((ext_vector_type(8))) short bf16x8;
typedef __attribute__((ext_vector_type(8))) unsigned short u16x8;
typedef __attribute__((ext_vector_type(4))) float f32x4;

struct us4 { u16 a, b, c, d; };

__device__ __forceinline__ u16 f2bf(float f) {
    uint32_t u = __float_as_uint(f);
    uint32_t r = (u + 0x7FFFu + ((u >> 16) & 1u)) >> 16;
    return (u16)r;
}
__device__ __forceinline__ float bf2f(u16 h) { return __uint_as_float(((uint32_t)h) << 16); }
__device__ __forceinline__ float sigm(float x) { return 1.f / (1.f + expf(-x)); }
__device__ __forceinline__ float dot4(float4 a, float4 b) {
    return a.x * b.x + a.y * b.y + a.z * b.z + a.w * b.w;
}
__device__ __forceinline__ float wave_sum(float v) {
#pragma unroll
    for (int o = 32; o; o >>= 1) v += __shfl_down(v, o);
    return v;
}
__device__ __forceinline__ float wave_max(float v) {
#pragma unroll
    for (int o = 32; o; o >>= 1) v = fmaxf(v, __shfl_down(v, o));
    return v;
}

// Device-scope software grid barrier (all blocks co-resident: grid=64 << 256 CUs).
// bar[0] = arrive count, bar[1] = generation. Both zeroed by prep_all each launch.
__device__ __forceinline__ void grid_barrier(int* bar, int nblk) {
    __syncthreads();
    if (threadIdx.x == 0) {
        __threadfence();
        int g = __hip_atomic_load(bar + 1, __ATOMIC_RELAXED, __HIP_MEMORY_SCOPE_AGENT);
        if (__hip_atomic_fetch_add(bar, 1, __ATOMIC_ACQ_REL, __HIP_MEMORY_SCOPE_AGENT) == nblk - 1) {
            __hip_atomic_store(bar, 0, __ATOMIC_RELAXED, __HIP_MEMORY_SCOPE_AGENT);
            __hip_atomic_store(bar + 1, g + 1, __ATOMIC_RELEASE, __HIP_MEMORY_SCOPE_AGENT);
        } else {
            while (__hip_atomic_load(bar + 1, __ATOMIC_ACQUIRE, __HIP_MEMORY_SCOPE_AGENT) == g) {
                __builtin_amdgcn_s_sleep(1);
            }
        }
        __threadfence();
    }
    __syncthreads();
}

// ---------------------------------------------------------------------------
// Generic 128x128-tile BT GEMM: C[M,N] = A[M,K] * B[N,K]^T   (unchanged, proven)
// ---------------------------------------------------------------------------
template <bool SPLIT, int AMODE, int EPI>
__global__ __launch_bounds__(256) void gemm_bt(
    const u16* __restrict__ AH, const u16* __restrict__ AL, int lda, long strideA,
    const u16* __restrict__ BH, const u16* __restrict__ BL, int ldb, long strideB,
    float* __restrict__ C, u16* __restrict__ CH, u16* __restrict__ CL,
    int ldc, long strideC, const float* __restrict__ bias, int K)
{
    constexpr int TL = 40;
    constexpr int CHK = 128 * TL;
    __shared__ u16 sm[(SPLIT ? 4 : 2) * CHK];
    u16* sAH = sm;
    u16* sBH = sm + CHK;
    u16* sAL = SPLIT ? sm + 2 * CHK : sm;
    u16* sBL = SPLIT ? sm + 3 * CHK : sm;

    const int tid = threadIdx.x;
    const int lane = tid & 63, w = tid >> 6;
    const int wm = w >> 1, wn = w & 1;
    const int lane15 = lane & 15, q8 = (lane >> 4) << 3;
    const int n0 = blockIdx.x * 128, m0 = blockIdx.y * 128, z = blockIdx.z;

    const int r = tid >> 2, c8 = (tid & 3) * 8;

    long aoff[2], boff[2];
#pragma unroll
    for (int h2 = 0; h2 < 2; ++h2) {
        int row = r + (h2 << 6);
        if (AMODE == 0) {
            aoff[h2] = strideA * z + (long)(m0 + row) * lda + c8;
        } else {
            int m = m0 + row;
            int t = m % 40, dd = m / 40;
            aoff[h2] = ((long)(t + 1) * 128 + (z * 16 + dd)) * 512 + c8;
        }
        boff[h2] = strideB * z + (long)(n0 + row) * ldb + c8;
    }

    f32x4 acc[4][4] = {};

    for (int k0 = 0; k0 < K; k0 += 32) {
#pragma unroll
        for (int h2 = 0; h2 < 2; ++h2) {
            int row = r + (h2 << 6);
            int sidx = row * TL + c8;
            *(u16x8*)&sAH[sidx] = *(const u16x8*)&AH[aoff[h2] + k0];
            *(u16x8*)&sBH[sidx] = *(const u16x8*)&BH[boff[h2] + k0];
            if constexpr (SPLIT) {
                *(u16x8*)&sAL[sidx] = *(const u16x8*)&AL[aoff[h2] + k0];
                *(u16x8*)&sBL[sidx] = *(const u16x8*)&BL[boff[h2] + k0];
            }
        }
        __syncthreads();

        bf16x8 a[4], b[4], al[4], bl[4];
#pragma unroll
        for (int i = 0; i < 4; ++i) {
            a[i] = *(const bf16x8*)&sAH[(wm * 64 + i * 16 + lane15) * TL + q8];
            b[i] = *(const bf16x8*)&sBH[(wn * 64 + i * 16 + lane15) * TL + q8];
            if constexpr (SPLIT) {
                al[i] = *(const bf16x8*)&sAL[(wm * 64 + i * 16 + lane15) * TL + q8];
                bl[i] = *(const bf16x8*)&sBL[(wn * 64 + i * 16 + lane15) * TL + q8];
            }
        }
#pragma unroll
        for (int mt = 0; mt < 4; ++mt)
#pragma unroll
            for (int nt = 0; nt < 4; ++nt) {
                acc[mt][nt] = __builtin_amdgcn_mfma_f32_16x16x32_bf16(a[mt], b[nt], acc[mt][nt], 0, 0, 0);
                if constexpr (SPLIT) {
                    acc[mt][nt] = __builtin_amdgcn_mfma_f32_16x16x32_bf16(a[mt], bl[nt], acc[mt][nt], 0, 0, 0);
                    acc[mt][nt] = __builtin_amdgcn_mfma_f32_16x16x32_bf16(al[mt], b[nt], acc[mt][nt], 0, 0, 0);
                }
            }
        __syncthreads();
    }

#pragma unroll
    for (int mt = 0; mt < 4; ++mt)
#pragma unroll
        for (int nt = 0; nt < 4; ++nt)
#pragma unroll
            for (int i = 0; i < 4; ++i) {
                int row = m0 + wm * 64 + mt * 16 + ((lane >> 4) << 2) + i;
                int col = n0 + wn * 64 + nt * 16 + lane15;
                long off = strideC * z + (long)row * ldc + col;
                float v = acc[mt][nt][i];
                if constexpr (EPI == 0) {
                    C[off] = v;
                } else if constexpr (EPI == 1) {
                    C[off] = v + bias[col];
                } else if constexpr (EPI == 2) {
                    u16 h_ = f2bf(v);
                    CH[off] = h_;
                    CL[off] = f2bf(v - bf2f(h_));
                } else if constexpr (EPI == 3) {
                    CH[off] = f2bf(tanhf(v));
                } else {
                    CH[off] = f2bf(v);
                }
            }
}

// ---------------------------------------------------------------------------
// Doc-level loop: ONE kernel, 64 blocks x 256, grid barriers between phases.
// Uses precomputed E0q = enc0 @ wq_doc (fp32).
// ---------------------------------------------------------------------------
__global__ __launch_bounds__(256) void doc_mega(
    const float* __restrict__ enc0, const float* __restrict__ E0q,
    const unsigned char* __restrict__ mask, const float* __restrict__ emb,
    const float* __restrict__ wih_d, const float* __restrict__ whh_d,
    const float* __restrict__ bih_d, const float* __restrict__ bhh_d,
    const float* __restrict__ wo_d,
    float* __restrict__ dx, float* __restrict__ dhA, float* __restrict__ dhB,
    float* __restrict__ dc, float* __restrict__ dsc, float* __restrict__ dctx,
    float* __restrict__ dsent, float* __restrict__ out_last, int* bar)
{
    __shared__ float sm_[8448];
    float* xh = sm_;              // [8][1024]
    float* gates = sm_ + 8192;    // [8][32]

    const int blk = blockIdx.x, tid = threadIdx.x;
    const int w = tid >> 6, lane = tid & 63;

    // ---- init: dh = dc = mean_j enc0[b,j,:], dx = emb[SOD] ----
    {
        int b = blk >> 3, e0 = (blk & 7) << 6;
        int e = e0 + (tid & 63), strip = tid >> 6;
        const float* p0 = enc0 + ((long)b * 400 + strip) * 512 + e;
        float s = 0.f;
        for (int j = strip; j < 400; j += 4) { s += *p0; p0 += 4 * 512; }
        sm_[strip * 64 + (tid & 63)] = s;
        __syncthreads();
        if (tid < 64) {
            float m = (sm_[tid] + sm_[64 + tid] + sm_[128 + tid] + sm_[192 + tid]) * (1.f / 400.f);
            dhA[b * 512 + e0 + tid] = m;
            dc[b * 512 + e0 + tid] = m;
            dx[b * 512 + e0 + tid] = emb[2 * 512 + e0 + tid];
        }
    }
    grid_barrier(bar, 64);

    for (int t = 0; t < 16; ++t) {
        float* hin  = (t & 1) ? dhB : dhA;
        float* hout = (t & 1) ? dhA : dhB;

        // ---- phase 1: LSTM gates + elementwise ----
        {
            for (int q = tid; q < 2048; q += 256) {
                int b = q >> 8, cc = q & 255;
                float4 v = (cc < 128) ? ((const float4*)dx)[b * 128 + cc]
                                      : ((const float4*)hin)[b * 128 + (cc - 128)];
                ((float4*)xh)[q] = v;
            }
            __syncthreads();
            for (int rp = w * 8; rp < w * 8 + 8; ++rp) {
                int ul = rp >> 2, g = rp & 3;
                int row = g * 512 + (blk << 3) + ul;
                const float4* wi = (const float4*)(wih_d + (long)row * 512) + lane * 2;
                const float4* wh = (const float4*)(whh_d + (long)row * 512) + lane * 2;
                float4 wi0 = wi[0], wi1 = wi[1], wh0 = wh[0], wh1 = wh[1];
                float part[8];
#pragma unroll
                for (int b = 0; b < 8; ++b) {
                    const float4* xb = (const float4*)(xh + b * 1024) + lane * 2;
                    const float4* hb = (const float4*)(xh + b * 1024 + 512) + lane * 2;
                    part[b] = dot4(wi0, xb[0]) + dot4(wi1, xb[1]) + dot4(wh0, hb[0]) + dot4(wh1, hb[1]);
                }
#pragma unroll
                for (int b = 0; b < 8; ++b) {
                    float s = wave_sum(part[b]);
                    if (lane == 0) gates[b * 32 + rp] = s;
                }
            }
            __syncthreads();
            if (tid < 64) {
                int b = tid >> 3, ul = tid & 7, u = (blk << 3) + ul;
                float gi = gates[b * 32 + ul * 4 + 0] + bih_d[u] + bhh_d[u];
                float gf = gates[b * 32 + ul * 4 + 1] + bih_d[512 + u] + bhh_d[512 + u];
                float gg = gates[b * 32 + ul * 4 + 2] + bih_d[1024 + u] + bhh_d[1024 + u];
                float go = gates[b * 32 + ul * 4 + 3] + bih_d[1536 + u] + bhh_d[1536 + u];
                float cc = dc[b * 512 + u];
                cc = sigm(gf) * cc + sigm(gi) * tanhf(gg);
                dc[b * 512 + u] = cc;
                hout[b * 512 + u] = sigm(go) * tanhf(cc);
            }
        }
        grid_barrier(bar, 64);

        // ---- phase 2: scores s[b,j] = E0q[b,j,:] . h_b ----
        {
            int b = blk >> 3, js = blk & 7;
            if (tid < 128) ((float4*)xh)[tid] = ((const float4*)hout)[b * 128 + tid];
            __syncthreads();
            for (int jj = w; jj < 50; jj += 4) {
                int j = js * 50 + jj;
                const float4* er = (const float4*)(E0q + ((long)b * 400 + j) * 512) + lane * 2;
                const float4* hv = (const float4*)xh + lane * 2;
                float s = dot4(er[0], hv[0]) + dot4(er[1], hv[1]);
                s = wave_sum(s);
                if (lane == 0) dsc[b * 400 + j] = mask[b * 400 + j] ? -1e9f : s;
            }
        }
        grid_barrier(bar, 64);

        // ---- phase 3: softmax (two elements per thread: tid, tid+256) + ctx ----
        {
            int b = blk >> 3, e0 = (blk & 7) << 6;
            int j1 = tid + 256;
            float v0 = (tid < 400) ? dsc[b * 400 + tid] : -1e30f;
            float v1 = (j1 < 400) ? dsc[b * 400 + j1] : -1e30f;
            float m = wave_max(fmaxf(v0, v1));
            if (lane == 0) xh[512 + w] = m;
            __syncthreads();
            float M = fmaxf(fmaxf(xh[512], xh[513]), fmaxf(xh[514], xh[515]));
            float ev0 = (tid < 400) ? expf(v0 - M) : 0.f;
            float ev1 = (j1 < 400) ? expf(v1 - M) : 0.f;
            float sv = wave_sum(ev0 + ev1);
            if (lane == 0) xh[516 + w] = sv;
            __syncthreads();
            float S = xh[516] + xh[517] + xh[518] + xh[519];
            __syncthreads();
            if (tid < 400) xh[tid] = ev0 / S;
            if (j1 < 400) xh[j1] = ev1 / S;
            __syncthreads();
            int e_ = e0 + (tid & 63), strip = tid >> 6;
            const float* ep = enc0 + ((long)b * 400 + strip) * 512 + e_;
            float acc = 0.f;
            for (int j = strip; j < 400; j += 4) { acc += xh[j] * (*ep); ep += 4 * 512; }
            xh[640 + strip * 64 + (tid & 63)] = acc;
            __syncthreads();
            if (tid < 64)
                dctx[b * 512 + e0 + tid] =
                    xh[640 + tid] + xh[704 + tid] + xh[768 + tid] + xh[832 + tid];
        }
        grid_barrier(bar, 64);

        // ---- phase 4: out = tanh([ctx,h] @ wo^T); feeds next x ----
        {
            for (int q = tid; q < 2048; q += 256) {
                int b = q >> 8, cc = q & 255;
                float4 v = (cc < 128) ? ((const float4*)dctx)[b * 128 + cc]
                                      : ((const float4*)hout)[b * 128 + (cc - 128)];
                ((float4*)xh)[q] = v;
            }
            __syncthreads();
#pragma unroll
            for (int rr = 0; rr < 2; ++rr) {
                int d = (blk << 3) + w * 2 + rr;
                const float4* wr = (const float4*)(wo_d + (long)d * 1024) + lane * 4;
                float4 w0 = wr[0], w1 = wr[1], w2 = wr[2], w3 = wr[3];
                float part[8];
#pragma unroll
                for (int b = 0; b < 8; ++b) {
                    const float4* cb = (const float4*)(xh + b * 1024) + lane * 4;
                    part[b] = dot4(w0, cb[0]) + dot4(w1, cb[1]) + dot4(w2, cb[2]) + dot4(w3, cb[3]);
                }
#pragma unroll
                for (int b = 0; b < 8; ++b) {
                    float s = wave_sum(part[b]);
                    if (lane == 0) {
                        float val = tanhf(s);
                        dx[b * 512 + d] = val;
                        dsent[((b << 4) + t) * 512 + d] = val;
                        if (t == 15) out_last[b * 512 + d] = val;
                    }
                }
            }
        }
        grid_barrier(bar, 64);
    }
}

// ---------------------------------------------------------------------------
// Word-level loop: ONE kernel, 64 blocks x 256, 40 steps with grid barriers.
// ---------------------------------------------------------------------------
__global__ __launch_bounds__(256) void word_mega(
    const float* __restrict__ sentS,
    u16* __restrict__ hAllH, u16* __restrict__ hAllL,
    const u16* __restrict__ WhhH, const u16* __restrict__ WhhL,
    const float* __restrict__ xW, float* __restrict__ wc,
    u16* __restrict__ catB, int* bar)
{
    const int tid = threadIdx.x, blk = blockIdx.x;

    // init: hAll[0] (hi/lo) + wc from sentS
    {
        int q = blk * 256 + tid;              // 16384 f4
        float4 v = ((const float4*)sentS)[q];
        float vv[4] = {v.x, v.y, v.z, v.w};
#pragma unroll
        for (int j = 0; j < 4; ++j) {
            int i = q * 4 + j;
            u16 hh = f2bf(vv[j]);
            hAllH[i] = hh;
            hAllL[i] = f2bf(vv[j] - bf2f(hh));
            wc[i] = vv[j];
        }
    }
    grid_barrier(bar, 64);

    const int w = tid >> 6, lane = tid & 63;
    const int W = blk * 4 + w;
    const int r0 = (W >> 5) << 4;
    const int u0 = (W & 31) << 4;
    const int lane15 = lane & 15, q8 = (lane >> 4) << 3;
    const long arow = (long)(r0 + lane15) * 512 + q8;
    long brow[4];
#pragma unroll
    for (int g = 0; g < 4; ++g) brow[g] = (long)(g * 512 + u0 + lane15) * 512 + q8;

    for (int t = 0; t < 40; ++t) {
        const u16* hH = hAllH + (long)t * 65536;
        const u16* hL = hAllL + (long)t * 65536;
        f32x4 acc[4] = {};
        for (int k0 = 0; k0 < 512; k0 += 32) {
            bf16x8 aH = *(const bf16x8*)&hH[arow + k0];
            bf16x8 aL = *(const bf16x8*)&hL[arow + k0];
#pragma unroll
            for (int g = 0; g < 4; ++g) {
                bf16x8 bH = *(const bf16x8*)&WhhH[brow[g] + k0];
                bf16x8 bL = *(const bf16x8*)&WhhL[brow[g] + k0];
                acc[g] = __builtin_amdgcn_mfma_f32_16x16x32_bf16(aH, bH, acc[g], 0, 0, 0);
                acc[g] = __builtin_amdgcn_mfma_f32_16x16x32_bf16(aH, bL, acc[g], 0, 0, 0);
                acc[g] = __builtin_amdgcn_mfma_f32_16x16x32_bf16(aL, bH, acc[g], 0, 0, 0);
            }
        }
        const float* xWt = xW + (long)t * 262144;
        u16* hHo = hAllH + (long)(t + 1) * 65536;
        u16* hLo = hAllL + (long)(t + 1) * 65536;
#pragma unroll
        for (int i = 0; i < 4; ++i) {
            int b2 = r0 + ((lane >> 4) << 2) + i;
            int u = u0 + lane15;
            const float* xr = xWt + (long)b2 * 2048;
            float gi = acc[0][i] + xr[u];
            float gf = acc[1][i] + xr[512 + u];
            float gg = acc[2][i] + xr[1024 + u];
            float go = acc[3][i] + xr[1536 + u];
            long cidx = (long)b2 * 512 + u;
            float cc = wc[cidx];
            cc = sigm(gf) * cc + sigm(gi) * tanhf(gg);
            wc[cidx] = cc;
            float hv = sigm(go) * tanhf(cc);
            u16 hh = f2bf(hv);
            hHo[cidx] = hh;
            hLo[cidx] = f2bf(hv - bf2f(hh));
            catB[((long)b2 * 40 + t) * 1024 + 512 + u] = hh;
        }
        grid_barrier(bar, 64);
    }
}

// ---------------------------------------------------------------------------
// All prep work in one region-dispatched kernel (also zeroes out_attn & bars).
// ---------------------------------------------------------------------------
__device__ __forceinline__ void split1(const float* __restrict__ src,
                                       u16* __restrict__ H, u16* __restrict__ L, long i)
{
    float4 v = ((const float4*)src)[i];
    u16 h0 = f2bf(v.x), h1 = f2bf(v.y), h2 = f2bf(v.z), h3 = f2bf(v.w);
    ((us4*)H)[i] = {h0, h1, h2, h3};
    ((us4*)L)[i] = {f2bf(v.x - bf2f(h0)), f2bf(v.y - bf2f(h1)),
                    f2bf(v.z - bf2f(h2)), f2bf(v.w - bf2f(h3))};
}
__device__ __forceinline__ void wqT1(const float* __restrict__ wq,
                                     u16* __restrict__ H, u16* __restrict__ L, int idx)
{
    int e = idx >> 9, d = idx & 511;
    float v = wq[(long)d * 512 + e];
    u16 h = f2bf(v);
    H[idx] = h;
    L[idx] = f2bf(v - bf2f(h));
}

__global__ __launch_bounds__(256) void prep_all(
    const float* __restrict__ wih_w, const float* __restrict__ whh_w,
    const float* __restrict__ enc1, const float* __restrict__ enc0,
    const float* __restrict__ wq_w, const float* __restrict__ wq_d,
    const float* __restrict__ wo_w, const float* __restrict__ fcw,
    const int* __restrict__ toks, const float* __restrict__ emb,
    const float* __restrict__ spe,
    const float* __restrict__ bih_w, const float* __restrict__ bhh_w,
    u16* __restrict__ WihH, u16* __restrict__ WihL,
    u16* __restrict__ WhhH, u16* __restrict__ WhhL,
    u16* __restrict__ enc1H, u16* __restrict__ enc1L,
    u16* __restrict__ enc0H, u16* __restrict__ enc0L,
    u16* __restrict__ wqTH, u16* __restrict__ wqTL,
    u16* __restrict__ wqdTH, u16* __restrict__ wqdTL,
    u16* __restrict__ woB, u16* __restrict__ fcwB, u16* __restrict__ enc1T,
    u16* __restrict__ xinH, u16* __restrict__ xinL,
    float* __restrict__ biasc, float* __restrict__ out_attn, int* __restrict__ bar)
{
    int b = blockIdx.x;
    const int tid = threadIdx.x;

    if (b < 1024) { split1(wih_w, WihH, WihL, (long)b * 256 + tid); return; }
    b -= 1024;
    if (b < 1024) { split1(whh_w, WhhH, WhhL, (long)b * 256 + tid); return; }
    b -= 1024;
    if (b < 1600) { split1(enc1, enc1H, enc1L, (long)b * 256 + tid); return; }
    b -= 1600;
    if (b < 1600) { split1(enc0, enc0H, enc0L, (long)b * 256 + tid); return; }
    b -= 1600;
    if (b < 1024) { wqT1(wq_w, wqTH, wqTL, b * 256 + tid); return; }
    b -= 1024;
    if (b < 1024) { wqT1(wq_d, wqdTH, wqdTL, b * 256 + tid); return; }
    b -= 1024;
    if (b < 512) {   // wo -> bf16
        long i = (long)b * 256 + tid;
        float4 v = ((const float4*)wo_w)[i];
        ((us4*)woB)[i] = {f2bf(v.x), f2bf(v.y), f2bf(v.z), f2bf(v.w)};
        return;
    }
    b -= 512;
    if (b < 16000) {  // fcw -> bf16
        long i = (long)b * 256 + tid;
        float4 v = ((const float4*)fcw)[i];
        ((us4*)fcwB)[i] = {f2bf(v.x), f2bf(v.y), f2bf(v.z), f2bf(v.w)};
        return;
    }
    b -= 16000;
    if (b < 6656) {  // enc1 transposed + K-pad: out[b][e][j]
        long idx = (long)b * 256 + tid;          // 8*512*416
        int j = (int)(idx % 416);
        long be = idx / 416;
        int e = (int)(be % 512);
        int bb = (int)(be / 512);
        float v = (j < 400) ? enc1[((long)bb * 400 + j) * 512 + e] : 0.f;
        enc1T[idx] = f2bf(v);
        return;
    }
    b -= 6656;
    if (b < 1280) {  // x_in = emb[tok] + spe[pos]  (pos inline)
        int g = b * 256 + tid;                   // 327680
        int m = g >> 6, e0 = (g & 63) << 3;
        int t = m >> 7, b2 = m & 127;
        int ne = 0;
        for (int s = 0; s < 40; ++s) ne |= (toks[b2 * 40 + s] != 1);
        int pos = ne ? (2 + (b2 & 15)) : 1;
        const float* ep = emb + (long)toks[b2 * 40 + t] * 512 + e0;
        const float* sp = spe + (long)pos * 512 + e0;
        long o = (long)m * 512 + e0;
#pragma unroll
        for (int j = 0; j < 8; ++j) {
            float v = ep[j] + sp[j];
            u16 h = f2bf(v);
            xinH[o + j] = h;
            xinL[o + j] = f2bf(v - bf2f(h));
        }
        return;
    }
    b -= 1280;
    if (b < 1) {     // combined word biases
        for (int i = tid; i < 2048; i += 256) biasc[i] = bih_w[i] + bhh_w[i];
        return;
    }
    b -= 1;
    if (b < 200) {   // zero attn_scores output
        out_attn[b * 256 + tid] = 0.f;
        return;
    }
    b -= 200;
    if (tid < 8) bar[tid] = 0;   // zero grid-barrier state
}

__global__ __launch_bounds__(256) void word_softmax(
    const float* __restrict__ sc, const unsigned char* __restrict__ mask,
    float* __restrict__ pout, u16* __restrict__ pbf)
{
    const int r = blockIdx.x, tid = threadIdx.x;
    const int b = r / 640;
    const int wv = tid >> 6, lane = tid & 63;
    __shared__ float red[4];
    const int j1 = tid + 256;
    float v0 = sc[(long)r * 512 + tid];
    if (mask[b * 400 + tid]) v0 = -1e9f;
    float v1 = -1e30f;
    if (j1 < 400) {
        v1 = sc[(long)r * 512 + j1];
        if (mask[b * 400 + j1]) v1 = -1e9f;
    }
    float mv = wave_max(fmaxf(v0, v1));
    if (lane == 0) red[wv] = mv;
    __syncthreads();
    if (tid == 0) red[0] = fmaxf(fmaxf(red[0], red[1]), fmaxf(red[2], red[3]));
    __syncthreads();
    const float M = red[0];
    float e0 = expf(v0 - M);
    float e1 = (j1 < 400) ? expf(v1 - M) : 0.f;
    __syncthreads();
    float sv = wave_sum(e0 + e1);
    if (lane == 0) red[wv] = sv;
    __syncthreads();
    if (tid == 0) red[0] = red[0] + red[1] + red[2] + red[3];
    __syncthreads();
    const float inv = 1.f / red[0];
    float p0 = e0 * inv;
    pout[(long)r * 400 + tid] = p0;
    pbf[(long)r * 416 + tid] = f2bf(p0);
    if (j1 < 400) {
        float p1 = e1 * inv;
        pout[(long)r * 400 + j1] = p1;
        pbf[(long)r * 416 + j1] = f2bf(p1);
    } else if (j1 < 416) {
        pbf[(long)r * 416 + j1] = 0;
    }
}

// ---------------------------------------------------------------------------
extern "C" void kernel_launch(void* const* d_in, const int* in_sizes, int n_in,
                              void* d_out, int out_size, void* d_ws, size_t ws_size,
                              hipStream_t stream)
{
    (void)in_sizes; (void)n_in; (void)out_size; (void)ws_size;

    const int*   toks  = (const int*)  d_in[0];
    const float* enc0  = (const float*)d_in[1];
    const float* enc1  = (const float*)d_in[2];
    const unsigned char* mask = (const unsigned char*)d_in[3];
    const float* emb   = (const float*)d_in[4];
    const float* spe   = (const float*)d_in[5];
    const float* wih_d = (const float*)d_in[6];
    const float* whh_d = (const float*)d_in[7];
    const float* bih_d = (const float*)d_in[8];
    const float* bhh_d = (const float*)d_in[9];
    const float* wq_d  = (const float*)d_in[10];
    const float* wo_d  = (const float*)d_in[11];
    const float* wih_w = (const float*)d_in[12];
    const float* whh_w = (const float*)d_in[13];
    const float* bih_w = (const float*)d_in[14];
    const float* bhh_w = (const float*)d_in[15];
    const float* wq_w  = (const float*)d_in[16];
    const float* wo_w  = (const float*)d_in[17];
    const float* fcw   = (const float*)d_in[18];
    const float* fcb   = (const float*)d_in[19];

    float* out_dec  = (float*)d_out;                  // [8,640,32000]
    float* out_attn = out_dec + 163840000L;           // [8,16,400] zeros
    float* out_watt = out_attn + 51200;               // [128,40,400]
    float* out_last = out_watt + 2048000;             // [8,512]

    char* wsp = (char*)d_ws;
    auto alloc = [&](size_t bytes) -> void* {
        void* p = wsp;
        wsp += (bytes + 255) & ~(size_t)255;
        return p;
    };

    float* xW    = (float*)alloc(40L * 128 * 2048 * 4);
    u16* hAllH   = (u16*)alloc(41L * 128 * 512 * 2);
    u16* hAllL   = (u16*)alloc(41L * 128 * 512 * 2);
    float* wc    = (float*)alloc(128L * 512 * 4);
    u16* xinH    = (u16*)alloc(5120L * 512 * 2);
    u16* xinL    = (u16*)alloc(5120L * 512 * 2);
    u16* WihH    = (u16*)alloc(2048L * 512 * 2);
    u16* WihL    = (u16*)alloc(2048L * 512 * 2);
    u16* WhhH    = (u16*)alloc(2048L * 512 * 2);
    u16* WhhL    = (u16*)alloc(2048L * 512 * 2);
    u16* wqTH    = (u16*)alloc(512L * 512 * 2);
    u16* wqTL    = (u16*)alloc(512L * 512 * 2);
    u16* wqdTH   = (u16*)alloc(512L * 512 * 2);
    u16* wqdTL   = (u16*)alloc(512L * 512 * 2);
    u16* enc1H   = (u16*)alloc(3200L * 512 * 2);
    u16* enc1L   = (u16*)alloc(3200L * 512 * 2);
    u16* enc0H   = (u16*)alloc(3200L * 512 * 2);
    u16* enc0L   = (u16*)alloc(3200L * 512 * 2);
    u16* sq1H    = (u16*)alloc(3328L * 512 * 2);
    u16* sq1L    = (u16*)alloc(3328L * 512 * 2);
    float* E0q   = (float*)alloc(3200L * 512 * 4);
    float* wsS   = (float*)alloc(5120L * 512 * 4);
    u16* Pbf     = (u16*)alloc(5120L * 416 * 2);
    u16* enc1T   = (u16*)alloc(8L * 512 * 416 * 2);
    u16* catB    = (u16*)alloc(5120L * 1024 * 2);
    u16* woB     = (u16*)alloc(512L * 1024 * 2);
    u16* Alog    = (u16*)alloc(5120L * 512 * 2);
    u16* fcwB    = (u16*)alloc(32000L * 512 * 2);
    float* biasc = (float*)alloc(2048 * 4);
    float* dhA   = (float*)alloc(8L * 512 * 4);
    float* dhB   = (float*)alloc(8L * 512 * 4);
    float* dc    = (float*)alloc(8L * 512 * 4);
    float* dx    = (float*)alloc(8L * 512 * 4);
    float* dsc   = (float*)alloc(8L * 400 * 4);
    float* dctx  = (float*)alloc(8L * 512 * 4);
    float* dsent = (float*)alloc(128L * 512 * 4);
    int* bar     = (int*)alloc(64);

    // ---- 1: all prep (also zeroes out_attn and barrier state) ----
    prep_all<<<dim3(31946), 256, 0, stream>>>(
        wih_w, whh_w, enc1, enc0, wq_w, wq_d, wo_w, fcw, toks, emb, spe,
        bih_w, bhh_w,
        WihH, WihL, WhhH, WhhL, enc1H, enc1L, enc0H, enc0L,
        wqTH, wqTL, wqdTH, wqdTL, woB, fcwB, enc1T, xinH, xinL,
        biasc, out_attn, bar);

    // ---- 2-4: input-side GEMMs (split-accurate) ----
    gemm_bt<true, 0, 2><<<dim3(4, 25, 1), 256, 0, stream>>>(
        enc1H, enc1L, 512, 0, wqTH, wqTL, 512, 0,
        nullptr, sq1H, sq1L, 512, 0, nullptr, 512);

    gemm_bt<true, 0, 0><<<dim3(4, 25, 1), 256, 0, stream>>>(
        enc0H, enc0L, 512, 0, wqdTH, wqdTL, 512, 0,
        E0q, nullptr, nullptr, 512, 0, nullptr, 512);

    gemm_bt<true, 0, 1><<<dim3(16, 40, 1), 256, 0, stream>>>(
        xinH, xinL, 512, 0, WihH, WihL, 512, 0,
        xW, nullptr, nullptr, 2048, 0, biasc, 512);

    // ---- 5: document-level loop (single kernel) ----
    doc_mega<<<dim3(64), 256, 0, stream>>>(
        enc0, E0q, mask, emb, wih_d, whh_d, bih_d, bhh_d, wo_d,
        dx, dhA, dhB, dc, dsc, dctx, dsent, out_last, bar);

    // ---- 6: word-level LSTM recurrence (single kernel) ----
    word_mega<<<dim3(64), 256, 0, stream>>>(
        dsent, hAllH, hAllL, WhhH, WhhL, xW, wc, catB, bar + 2);

    // ---- 7: batched word attention scores ----
    gemm_bt<true, 1, 0><<<dim3(4, 5, 8), 256, 0, stream>>>(
        hAllH, hAllL, 0, 0, sq1H, sq1L, 512, 204800L,
        wsS, nullptr, nullptr, 512, 327680L, nullptr, 512);

    // ---- 8: softmax -> out_watt + Pbf ----
    word_softmax<<<dim3(5120), 256, 0, stream>>>(wsS, mask, out_watt, Pbf);

    // ---- 9: ctx = P @ enc1 -> catB[:, 0:512] ----
    gemm_bt<false, 0, 4><<<dim3(4, 5, 8), 256, 0, stream>>>(
        Pbf, nullptr, 416, 266240L, enc1T, nullptr, 416, 212992L,
        nullptr, catB, nullptr, 1024, 655360L, nullptr, 416);

    // ---- 10: out = tanh(cat @ wo^T) ----
    gemm_bt<false, 0, 3><<<dim3(4, 40, 1), 256, 0, stream>>>(
        catB, nullptr, 1024, 0, woB, nullptr, 1024, 0,
        nullptr, Alog, nullptr, 512, 0, nullptr, 1024);

    // ---- 11: logits ----
    gemm_bt<false, 0, 1><<<dim3(250, 40, 1), 256, 0, stream>>>(
        Alog, nullptr, 512, 0, fcwB, nullptr, 512, 0,
        out_dec, nullptr, nullptr, 32000, 0, fcb, 512);
}

// Round 4
// 2708.563 us; speedup vs baseline: 2.3325x; 1.1781x over previous
//
#include <hip/hip_runtime.h>
#include <cstdint>

typedef unsigned short u16;
typedef __attribute__((ext_vector_type(8))) short bf16x8;
typedef __attribute__((ext_vector_type(8))) unsigned short u16x8;
typedef __attribute__((ext_vector_type(4))) float f32x4;

struct us4 { u16 a, b, c, d; };

__device__ __forceinline__ u16 f2bf(float f) {
    uint32_t u = __float_as_uint(f);
    uint32_t r = (u + 0x7FFFu + ((u >> 16) & 1u)) >> 16;
    return (u16)r;
}
__device__ __forceinline__ float bf2f(u16 h) { return __uint_as_float(((uint32_t)h) << 16); }
__device__ __forceinline__ float sigm(float x) { return 1.f / (1.f + expf(-x)); }
__device__ __forceinline__ float dot4(float4 a, float4 b) {
    return a.x * b.x + a.y * b.y + a.z * b.z + a.w * b.w;
}
__device__ __forceinline__ float wave_sum(float v) {
#pragma unroll
    for (int o = 32; o; o >>= 1) v += __shfl_down(v, o);
    return v;
}
__device__ __forceinline__ float wave_max(float v) {
#pragma unroll
    for (int o = 32; o; o >>= 1) v = fmaxf(v, __shfl_down(v, o));
    return v;
}

// Device-scope software grid barrier. RELAXED poll (no per-poll L2 invalidate;
// one trailing fence gives acquire semantics once). bar zeroed by prep_all.
__device__ __forceinline__ void grid_barrier(int* bar, int nblk) {
    __syncthreads();
    if (threadIdx.x == 0) {
        __threadfence();
        int g = __hip_atomic_load(bar + 1, __ATOMIC_RELAXED, __HIP_MEMORY_SCOPE_AGENT);
        if (__hip_atomic_fetch_add(bar, 1, __ATOMIC_ACQ_REL, __HIP_MEMORY_SCOPE_AGENT) == nblk - 1) {
            __hip_atomic_store(bar, 0, __ATOMIC_RELAXED, __HIP_MEMORY_SCOPE_AGENT);
            __hip_atomic_store(bar + 1, g + 1, __ATOMIC_RELEASE, __HIP_MEMORY_SCOPE_AGENT);
        } else {
            while (__hip_atomic_load(bar + 1, __ATOMIC_RELAXED, __HIP_MEMORY_SCOPE_AGENT) == g) {
                __builtin_amdgcn_s_sleep(1);
            }
        }
        __threadfence();
    }
    __syncthreads();
}

// ---------------------------------------------------------------------------
// Generic 128x128-tile BT GEMM: C[M,N] = A[M,K] * B[N,K]^T   (unchanged, proven)
// ---------------------------------------------------------------------------
template <bool SPLIT, int AMODE, int EPI>
__global__ __launch_bounds__(256) void gemm_bt(
    const u16* __restrict__ AH, const u16* __restrict__ AL, int lda, long strideA,
    const u16* __restrict__ BH, const u16* __restrict__ BL, int ldb, long strideB,
    float* __restrict__ C, u16* __restrict__ CH, u16* __restrict__ CL,
    int ldc, long strideC, const float* __restrict__ bias, int K)
{
    constexpr int TL = 40;
    constexpr int CHK = 128 * TL;
    __shared__ u16 sm[(SPLIT ? 4 : 2) * CHK];
    u16* sAH = sm;
    u16* sBH = sm + CHK;
    u16* sAL = SPLIT ? sm + 2 * CHK : sm;
    u16* sBL = SPLIT ? sm + 3 * CHK : sm;

    const int tid = threadIdx.x;
    const int lane = tid & 63, w = tid >> 6;
    const int wm = w >> 1, wn = w & 1;
    const int lane15 = lane & 15, q8 = (lane >> 4) << 3;
    const int n0 = blockIdx.x * 128, m0 = blockIdx.y * 128, z = blockIdx.z;

    const int r = tid >> 2, c8 = (tid & 3) * 8;

    long aoff[2], boff[2];
#pragma unroll
    for (int h2 = 0; h2 < 2; ++h2) {
        int row = r + (h2 << 6);
        if (AMODE == 0) {
            aoff[h2] = strideA * z + (long)(m0 + row) * lda + c8;
        } else {
            int m = m0 + row;
            int t = m % 40, dd = m / 40;
            aoff[h2] = ((long)(t + 1) * 128 + (z * 16 + dd)) * 512 + c8;
        }
        boff[h2] = strideB * z + (long)(n0 + row) * ldb + c8;
    }

    f32x4 acc[4][4] = {};

    for (int k0 = 0; k0 < K; k0 += 32) {
#pragma unroll
        for (int h2 = 0; h2 < 2; ++h2) {
            int row = r + (h2 << 6);
            int sidx = row * TL + c8;
            *(u16x8*)&sAH[sidx] = *(const u16x8*)&AH[aoff[h2] + k0];
            *(u16x8*)&sBH[sidx] = *(const u16x8*)&BH[boff[h2] + k0];
            if constexpr (SPLIT) {
                *(u16x8*)&sAL[sidx] = *(const u16x8*)&AL[aoff[h2] + k0];
                *(u16x8*)&sBL[sidx] = *(const u16x8*)&BL[boff[h2] + k0];
            }
        }
        __syncthreads();

        bf16x8 a[4], b[4], al[4], bl[4];
#pragma unroll
        for (int i = 0; i < 4; ++i) {
            a[i] = *(const bf16x8*)&sAH[(wm * 64 + i * 16 + lane15) * TL + q8];
            b[i] = *(const bf16x8*)&sBH[(wn * 64 + i * 16 + lane15) * TL + q8];
            if constexpr (SPLIT) {
                al[i] = *(const bf16x8*)&sAL[(wm * 64 + i * 16 + lane15) * TL + q8];
                bl[i] = *(const bf16x8*)&sBL[(wn * 64 + i * 16 + lane15) * TL + q8];
            }
        }
#pragma unroll
        for (int mt = 0; mt < 4; ++mt)
#pragma unroll
            for (int nt = 0; nt < 4; ++nt) {
                acc[mt][nt] = __builtin_amdgcn_mfma_f32_16x16x32_bf16(a[mt], b[nt], acc[mt][nt], 0, 0, 0);
                if constexpr (SPLIT) {
                    acc[mt][nt] = __builtin_amdgcn_mfma_f32_16x16x32_bf16(a[mt], bl[nt], acc[mt][nt], 0, 0, 0);
                    acc[mt][nt] = __builtin_amdgcn_mfma_f32_16x16x32_bf16(al[mt], b[nt], acc[mt][nt], 0, 0, 0);
                }
            }
        __syncthreads();
    }

#pragma unroll
    for (int mt = 0; mt < 4; ++mt)
#pragma unroll
        for (int nt = 0; nt < 4; ++nt)
#pragma unroll
            for (int i = 0; i < 4; ++i) {
                int row = m0 + wm * 64 + mt * 16 + ((lane >> 4) << 2) + i;
                int col = n0 + wn * 64 + nt * 16 + lane15;
                long off = strideC * z + (long)row * ldc + col;
                float v = acc[mt][nt][i];
                if constexpr (EPI == 0) {
                    C[off] = v;
                } else if constexpr (EPI == 1) {
                    C[off] = v + bias[col];
                } else if constexpr (EPI == 2) {
                    u16 h_ = f2bf(v);
                    CH[off] = h_;
                    CL[off] = f2bf(v - bf2f(h_));
                } else if constexpr (EPI == 3) {
                    CH[off] = f2bf(tanhf(v));
                } else {
                    CH[off] = f2bf(v);
                }
            }
}

// ---------------------------------------------------------------------------
// Doc-level loop v2: 128 blocks x 128 threads, 3 grid barriers per step.
// A: LSTM gates via split-bf16 MFMA on permuted weights Wp[u*4+g][x|h].
// B: scores (E0q . h) + whoh = Who . h.
// C: softmax + out = tanh(sum_j p_j * E0o[b,j,:] + whoh)  (coalesced E0o).
// ---------------------------------------------------------------------------
__global__ __launch_bounds__(128) void doc_mega(
    const float* __restrict__ enc0, const float* __restrict__ E0q,
    const float* __restrict__ E0o, const unsigned char* __restrict__ mask,
    const float* __restrict__ emb,
    const u16* __restrict__ WpH, const u16* __restrict__ WpL,
    const float* __restrict__ biasd, const float* __restrict__ wo_d,
    float* __restrict__ dx, float* __restrict__ dhA, float* __restrict__ dhB,
    float* __restrict__ dc, float* __restrict__ dsc, float* __restrict__ whoh,
    float* __restrict__ dsent, float* __restrict__ out_last, int* bar)
{
    __shared__ u16 xhH[16 * 1032];    // bf16-hi staging, rows 8..15 zero pad
    __shared__ u16 xhL[16 * 1032];
    __shared__ float tileC[16 * 17];
    __shared__ float aux2[1024];

    const int blk = blockIdx.x, tid = threadIdx.x;
    const int w = tid >> 6, lane = tid & 63;
    const int b_ = blk >> 4, s = blk & 15;
    const int lane15 = lane & 15, q8 = (lane >> 4) << 3;

    for (int q = tid; q < 8 * 1032; q += 128) { xhH[8 * 1032 + q] = 0; xhL[8 * 1032 + q] = 0; }

    // ---- init: dh = dc = mean_j enc0[b,j,:], dx = emb[SOD] ----
    {
        int dd = tid & 31, part = tid >> 5;
        const float* p0 = enc0 + ((long)b_ * 400 + part * 100) * 512 + s * 32 + dd;
        float sm = 0.f;
        for (int j = 0; j < 100; ++j) { sm += *p0; p0 += 512; }
        aux2[part * 32 + dd] = sm;
        __syncthreads();
        if (tid < 32) {
            float m = (aux2[tid] + aux2[32 + tid] + aux2[64 + tid] + aux2[96 + tid]) * (1.f / 400.f);
            int e = s * 32 + tid;
            dhA[b_ * 512 + e] = m;
            dc[b_ * 512 + e] = m;
            dx[b_ * 512 + e] = emb[1024 + e];
        }
    }
    grid_barrier(bar, 128);

    const u16* bh_base = WpH + ((long)blk * 16 + lane15) * 1024 + q8;
    const u16* bl_base = WpL + ((long)blk * 16 + lane15) * 1024 + q8;
    const u16* ah_base = xhH + lane15 * 1032 + q8;
    const u16* al_base = xhL + lane15 * 1032 + q8;

    for (int t = 0; t < 16; ++t) {
        const float* hin = (t & 1) ? dhB : dhA;
        float* hout = (t & 1) ? dhA : dhB;

        // ---- A: stage xh (split bf16), MFMA gates, LSTM elementwise ----
        for (int q = tid; q < 2048; q += 128) {
            int b = q >> 8, c4 = q & 255;
            float4 v = (c4 < 128) ? ((const float4*)dx)[b * 128 + c4]
                                  : ((const float4*)hin)[b * 128 + c4 - 128];
            int o = b * 1032 + c4 * 4;
            u16 h0 = f2bf(v.x), h1 = f2bf(v.y), h2 = f2bf(v.z), h3 = f2bf(v.w);
            *(us4*)&xhH[o] = {h0, h1, h2, h3};
            *(us4*)&xhL[o] = {f2bf(v.x - bf2f(h0)), f2bf(v.y - bf2f(h1)),
                              f2bf(v.z - bf2f(h2)), f2bf(v.w - bf2f(h3))};
        }
        __syncthreads();

        f32x4 acc = {};
        for (int k0 = w * 512; k0 < w * 512 + 512; k0 += 32) {
            bf16x8 aH = *(const bf16x8*)&ah_base[k0];
            bf16x8 aL = *(const bf16x8*)&al_base[k0];
            bf16x8 bH = *(const bf16x8*)&bh_base[k0];
            bf16x8 bL = *(const bf16x8*)&bl_base[k0];
            acc = __builtin_amdgcn_mfma_f32_16x16x32_bf16(aH, bH, acc, 0, 0, 0);
            acc = __builtin_amdgcn_mfma_f32_16x16x32_bf16(aH, bL, acc, 0, 0, 0);
            acc = __builtin_amdgcn_mfma_f32_16x16x32_bf16(aL, bH, acc, 0, 0, 0);
        }
        if (w == 1) {
#pragma unroll
            for (int i = 0; i < 4; ++i)
                tileC[((lane >> 4) * 4 + i) * 17 + lane15] = acc[i];
        }
        __syncthreads();
        if (w == 0) {
#pragma unroll
            for (int i = 0; i < 4; ++i)
                tileC[((lane >> 4) * 4 + i) * 17 + lane15] += acc[i];
        }
        __syncthreads();
        if (tid < 32) {
            int b = tid & 7, u4 = tid >> 3;
            int u = blk * 4 + u4;
            float gi = tileC[b * 17 + u4 * 4 + 0] + biasd[u];
            float gf = tileC[b * 17 + u4 * 4 + 1] + biasd[512 + u];
            float gg = tileC[b * 17 + u4 * 4 + 2] + biasd[1024 + u];
            float go = tileC[b * 17 + u4 * 4 + 3] + biasd[1536 + u];
            float cc = dc[b * 512 + u];
            cc = sigm(gf) * cc + sigm(gi) * tanhf(gg);
            dc[b * 512 + u] = cc;
            hout[b * 512 + u] = sigm(go) * tanhf(cc);
        }
        grid_barrier(bar, 128);

        // ---- B: scores for j-slice + whoh for d-slice ----
        {
            ((float4*)aux2)[tid] = ((const float4*)hout)[b_ * 128 + tid];
            __syncthreads();
            for (int jj = w; jj < 25; jj += 2) {
                int j = s * 25 + jj;
                const float4* er = (const float4*)(E0q + ((long)b_ * 400 + j) * 512) + lane * 2;
                const float4* hv = (const float4*)aux2 + lane * 2;
                float sv = dot4(er[0], hv[0]) + dot4(er[1], hv[1]);
                sv = wave_sum(sv);
                if (lane == 0) dsc[b_ * 400 + j] = mask[b_ * 400 + j] ? -1e9f : sv;
            }
            for (int di = w; di < 32; di += 2) {
                int d = s * 32 + di;
                const float4* wr = (const float4*)(wo_d + (long)d * 1024 + 512) + lane * 2;
                const float4* hv = (const float4*)aux2 + lane * 2;
                float sv = dot4(wr[0], hv[0]) + dot4(wr[1], hv[1]);
                sv = wave_sum(sv);
                if (lane == 0) whoh[b_ * 512 + d] = sv;
            }
        }
        grid_barrier(bar, 128);

        // ---- C: softmax (redundant per block) + out via E0o ----
        {
            float v0 = dsc[b_ * 400 + tid];
            float v1 = dsc[b_ * 400 + tid + 128];
            float v2 = dsc[b_ * 400 + tid + 256];
            bool h3 = (tid + 384) < 400;
            float v3 = h3 ? dsc[b_ * 400 + tid + 384] : -1e30f;
            float mx = wave_max(fmaxf(fmaxf(v0, v1), fmaxf(v2, v3)));
            if (lane == 0) aux2[960 + w] = mx;
            __syncthreads();
            float M = fmaxf(aux2[960], aux2[961]);
            float e0 = expf(v0 - M), e1 = expf(v1 - M), e2 = expf(v2 - M);
            float e3 = h3 ? expf(v3 - M) : 0.f;
            float sv = wave_sum(e0 + e1 + e2 + e3);
            if (lane == 0) aux2[962 + w] = sv;
            __syncthreads();
            float inv = 1.f / (aux2[962] + aux2[963]);
            aux2[tid] = e0 * inv;
            aux2[tid + 128] = e1 * inv;
            aux2[tid + 256] = e2 * inv;
            if (h3) aux2[tid + 384] = e3 * inv;
            __syncthreads();
            int dd = tid & 31, part = tid >> 5;
            const float* eo = E0o + ((long)b_ * 400 + part * 100) * 512 + s * 32 + dd;
            float acc2 = 0.f;
            for (int j = 0; j < 100; ++j) { acc2 += aux2[part * 100 + j] * (*eo); eo += 512; }
            aux2[512 + part * 32 + dd] = acc2;
            __syncthreads();
            if (tid < 32) {
                int d = s * 32 + tid;
                float o = aux2[512 + tid] + aux2[544 + tid] + aux2[576 + tid] + aux2[608 + tid]
                        + whoh[b_ * 512 + d];
                float val = tanhf(o);
                dx[b_ * 512 + d] = val;
                dsent[((b_ << 4) + t) * 512 + d] = val;
                if (t == 15) out_last[b_ * 512 + d] = val;
            }
        }
        grid_barrier(bar, 128);
    }
}

// ---------------------------------------------------------------------------
// Word-level loop: ONE kernel, 64 blocks x 256, 40 steps with grid barriers.
// ---------------------------------------------------------------------------
__global__ __launch_bounds__(256) void word_mega(
    const float* __restrict__ sentS,
    u16* __restrict__ hAllH, u16* __restrict__ hAllL,
    const u16* __restrict__ WhhH, const u16* __restrict__ WhhL,
    const float* __restrict__ xW, float* __restrict__ wc,
    u16* __restrict__ catB, int* bar)
{
    const int tid = threadIdx.x, blk = blockIdx.x;

    {
        int q = blk * 256 + tid;
        float4 v = ((const float4*)sentS)[q];
        float vv[4] = {v.x, v.y, v.z, v.w};
#pragma unroll
        for (int j = 0; j < 4; ++j) {
            int i = q * 4 + j;
            u16 hh = f2bf(vv[j]);
            hAllH[i] = hh;
            hAllL[i] = f2bf(vv[j] - bf2f(hh));
            wc[i] = vv[j];
        }
    }
    grid_barrier(bar, 64);

    const int w = tid >> 6, lane = tid & 63;
    const int W = blk * 4 + w;
    const int r0 = (W >> 5) << 4;
    const int u0 = (W & 31) << 4;
    const int lane15 = lane & 15, q8 = (lane >> 4) << 3;
    const long arow = (long)(r0 + lane15) * 512 + q8;
    long brow[4];
#pragma unroll
    for (int g = 0; g < 4; ++g) brow[g] = (long)(g * 512 + u0 + lane15) * 512 + q8;

    for (int t = 0; t < 40; ++t) {
        const u16* hH = hAllH + (long)t * 65536;
        const u16* hL = hAllL + (long)t * 65536;
        f32x4 acc[4] = {};
        for (int k0 = 0; k0 < 512; k0 += 32) {
            bf16x8 aH = *(const bf16x8*)&hH[arow + k0];
            bf16x8 aL = *(const bf16x8*)&hL[arow + k0];
#pragma unroll
            for (int g = 0; g < 4; ++g) {
                bf16x8 bH = *(const bf16x8*)&WhhH[brow[g] + k0];
                bf16x8 bL = *(const bf16x8*)&WhhL[brow[g] + k0];
                acc[g] = __builtin_amdgcn_mfma_f32_16x16x32_bf16(aH, bH, acc[g], 0, 0, 0);
                acc[g] = __builtin_amdgcn_mfma_f32_16x16x32_bf16(aH, bL, acc[g], 0, 0, 0);
                acc[g] = __builtin_amdgcn_mfma_f32_16x16x32_bf16(aL, bH, acc[g], 0, 0, 0);
            }
        }
        const float* xWt = xW + (long)t * 262144;
        u16* hHo = hAllH + (long)(t + 1) * 65536;
        u16* hLo = hAllL + (long)(t + 1) * 65536;
#pragma unroll
        for (int i = 0; i < 4; ++i) {
            int b2 = r0 + ((lane >> 4) << 2) + i;
            int u = u0 + lane15;
            const float* xr = xWt + (long)b2 * 2048;
            float gi = acc[0][i] + xr[u];
            float gf = acc[1][i] + xr[512 + u];
            float gg = acc[2][i] + xr[1024 + u];
            float go = acc[3][i] + xr[1536 + u];
            long cidx = (long)b2 * 512 + u;
            float cc = wc[cidx];
            cc = sigm(gf) * cc + sigm(gi) * tanhf(gg);
            wc[cidx] = cc;
            float hv = sigm(go) * tanhf(cc);
            u16 hh = f2bf(hv);
            hHo[cidx] = hh;
            hLo[cidx] = f2bf(hv - bf2f(hh));
            catB[((long)b2 * 40 + t) * 1024 + 512 + u] = hh;
        }
        grid_barrier(bar, 64);
    }
}

// ---------------------------------------------------------------------------
// All prep work in one region-dispatched kernel (also zeroes out_attn & bars).
// ---------------------------------------------------------------------------
__device__ __forceinline__ void split1(const float* __restrict__ src,
                                       u16* __restrict__ H, u16* __restrict__ L, long i)
{
    float4 v = ((const float4*)src)[i];
    u16 h0 = f2bf(v.x), h1 = f2bf(v.y), h2 = f2bf(v.z), h3 = f2bf(v.w);
    ((us4*)H)[i] = {h0, h1, h2, h3};
    ((us4*)L)[i] = {f2bf(v.x - bf2f(h0)), f2bf(v.y - bf2f(h1)),
                    f2bf(v.z - bf2f(h2)), f2bf(v.w - bf2f(h3))};
}
__device__ __forceinline__ void wqT1(const float* __restrict__ wq,
                                     u16* __restrict__ H, u16* __restrict__ L, int idx)
{
    int e = idx >> 9, d = idx & 511;
    float v = wq[(long)d * 512 + e];
    u16 h = f2bf(v);
    H[idx] = h;
    L[idx] = f2bf(v - bf2f(h));
}

__global__ __launch_bounds__(256) void prep_all(
    const float* __restrict__ wih_w, const float* __restrict__ whh_w,
    const float* __restrict__ enc1, const float* __restrict__ enc0,
    const float* __restrict__ wq_w, const float* __restrict__ wq_d,
    const float* __restrict__ wo_w, const float* __restrict__ fcw,
    const int* __restrict__ toks, const float* __restrict__ emb,
    const float* __restrict__ spe,
    const float* __restrict__ bih_w, const float* __restrict__ bhh_w,
    const float* __restrict__ bih_d, const float* __restrict__ bhh_d,
    const float* __restrict__ wih_d, const float* __restrict__ whh_d,
    const float* __restrict__ wo_d,
    u16* __restrict__ WihH, u16* __restrict__ WihL,
    u16* __restrict__ WhhH, u16* __restrict__ WhhL,
    u16* __restrict__ enc1H, u16* __restrict__ enc1L,
    u16* __restrict__ enc0H, u16* __restrict__ enc0L,
    u16* __restrict__ wqTH, u16* __restrict__ wqTL,
    u16* __restrict__ wqdTH, u16* __restrict__ wqdTL,
    u16* __restrict__ woB, u16* __restrict__ fcwB, u16* __restrict__ enc1T,
    u16* __restrict__ xinH, u16* __restrict__ xinL,
    u16* __restrict__ woCH, u16* __restrict__ woCL,
    u16* __restrict__ WpH, u16* __restrict__ WpL,
    float* __restrict__ biasc, float* __restrict__ biasd,
    float* __restrict__ out_attn, int* __restrict__ bar)
{
    int b = blockIdx.x;
    const int tid = threadIdx.x;

    if (b < 1024) { split1(wih_w, WihH, WihL, (long)b * 256 + tid); return; }
    b -= 1024;
    if (b < 1024) { split1(whh_w, WhhH, WhhL, (long)b * 256 + tid); return; }
    b -= 1024;
    if (b < 1600) { split1(enc1, enc1H, enc1L, (long)b * 256 + tid); return; }
    b -= 1600;
    if (b < 1600) { split1(enc0, enc0H, enc0L, (long)b * 256 + tid); return; }
    b -= 1600;
    if (b < 1024) { wqT1(wq_w, wqTH, wqTL, b * 256 + tid); return; }
    b -= 1024;
    if (b < 1024) { wqT1(wq_d, wqdTH, wqdTL, b * 256 + tid); return; }
    b -= 1024;
    if (b < 512) {
        long i = (long)b * 256 + tid;
        float4 v = ((const float4*)wo_w)[i];
        ((us4*)woB)[i] = {f2bf(v.x), f2bf(v.y), f2bf(v.z), f2bf(v.w)};
        return;
    }
    b -= 512;
    if (b < 16000) {
        long i = (long)b * 256 + tid;
        float4 v = ((const float4*)fcw)[i];
        ((us4*)fcwB)[i] = {f2bf(v.x), f2bf(v.y), f2bf(v.z), f2bf(v.w)};
        return;
    }
    b -= 16000;
    if (b < 6656) {
        long idx = (long)b * 256 + tid;
        int j = (int)(idx % 416);
        long be = idx / 416;
        int e = (int)(be % 512);
        int bb = (int)(be / 512);
        float v = (j < 400) ? enc1[((long)bb * 400 + j) * 512 + e] : 0.f;
        enc1T[idx] = f2bf(v);
        return;
    }
    b -= 6656;
    if (b < 1280) {
        int g = b * 256 + tid;
        int m = g >> 6, e0 = (g & 63) << 3;
        int t = m >> 7, b2 = m & 127;
        int ne = 0;
        for (int s = 0; s < 40; ++s) ne |= (toks[b2 * 40 + s] != 1);
        int pos = ne ? (2 + (b2 & 15)) : 1;
        const float* ep = emb + (long)toks[b2 * 40 + t] * 512 + e0;
        const float* sp = spe + (long)pos * 512 + e0;
        long o = (long)m * 512 + e0;
#pragma unroll
        for (int j = 0; j < 8; ++j) {
            float v = ep[j] + sp[j];
            u16 h = f2bf(v);
            xinH[o + j] = h;
            xinL[o + j] = f2bf(v - bf2f(h));
        }
        return;
    }
    b -= 1280;
    if (b < 1) {   // combined biases (word + doc)
        for (int i = tid; i < 2048; i += 256) {
            biasc[i] = bih_w[i] + bhh_w[i];
            biasd[i] = bih_d[i] + bhh_d[i];
        }
        return;
    }
    b -= 1;
    if (b < 200) {
        out_attn[b * 256 + tid] = 0.f;
        return;
    }
    b -= 200;
    if (b < 1024) {  // split wo_d[:, :512] -> woC (for E0o GEMM)
        int i = b * 256 + tid;
        int d = i >> 9, e = i & 511;
        float v = wo_d[(long)d * 1024 + e];
        u16 h = f2bf(v);
        woCH[i] = h;
        woCL[i] = f2bf(v - bf2f(h));
        return;
    }
    b -= 1024;
    if (b < 1024) {  // permuted+split doc LSTM weights: Wp[u*4+g][x|h]
        long gidx = (long)b * 256 + tid;       // 2048*1024/8
        int r = (int)(gidx >> 7);
        int k8 = ((int)gidx & 127) * 8;
        int u = r >> 2, g = r & 3;
        long orow = (long)(g * 512 + u);
#pragma unroll
        for (int j = 0; j < 8; ++j) {
            int k = k8 + j;
            float v = (k < 512) ? wih_d[orow * 512 + k] : whh_d[orow * 512 + k - 512];
            u16 h = f2bf(v);
            WpH[(long)r * 1024 + k] = h;
            WpL[(long)r * 1024 + k] = f2bf(v - bf2f(h));
        }
        return;
    }
    b -= 1024;
    if (tid < 8) bar[tid] = 0;
}

__global__ __launch_bounds__(256) void word_softmax(
    const float* __restrict__ sc, const unsigned char* __restrict__ mask,
    float* __restrict__ pout, u16* __restrict__ pbf)
{
    const int r = blockIdx.x, tid = threadIdx.x;
    const int b = r / 640;
    const int wv = tid >> 6, lane = tid & 63;
    __shared__ float red[4];
    const int j1 = tid + 256;
    float v0 = sc[(long)r * 512 + tid];
    if (mask[b * 400 + tid]) v0 = -1e9f;
    float v1 = -1e30f;
    if (j1 < 400) {
        v1 = sc[(long)r * 512 + j1];
        if (mask[b * 400 + j1]) v1 = -1e9f;
    }
    float mv = wave_max(fmaxf(v0, v1));
    if (lane == 0) red[wv] = mv;
    __syncthreads();
    if (tid == 0) red[0] = fmaxf(fmaxf(red[0], red[1]), fmaxf(red[2], red[3]));
    __syncthreads();
    const float M = red[0];
    float e0 = expf(v0 - M);
    float e1 = (j1 < 400) ? expf(v1 - M) : 0.f;
    __syncthreads();
    float sv = wave_sum(e0 + e1);
    if (lane == 0) red[wv] = sv;
    __syncthreads();
    if (tid == 0) red[0] = red[0] + red[1] + red[2] + red[3];
    __syncthreads();
    const float inv = 1.f / red[0];
    float p0 = e0 * inv;
    pout[(long)r * 400 + tid] = p0;
    pbf[(long)r * 416 + tid] = f2bf(p0);
    if (j1 < 400) {
        float p1 = e1 * inv;
        pout[(long)r * 400 + j1] = p1;
        pbf[(long)r * 416 + j1] = f2bf(p1);
    } else if (j1 < 416) {
        pbf[(long)r * 416 + j1] = 0;
    }
}

// ---------------------------------------------------------------------------
extern "C" void kernel_launch(void* const* d_in, const int* in_sizes, int n_in,
                              void* d_out, int out_size, void* d_ws, size_t ws_size,
                              hipStream_t stream)
{
    (void)in_sizes; (void)n_in; (void)out_size; (void)ws_size;

    const int*   toks  = (const int*)  d_in[0];
    const float* enc0  = (const float*)d_in[1];
    const float* enc1  = (const float*)d_in[2];
    const unsigned char* mask = (const unsigned char*)d_in[3];
    const float* emb   = (const float*)d_in[4];
    const float* spe   = (const float*)d_in[5];
    const float* wih_d = (const float*)d_in[6];
    const float* whh_d = (const float*)d_in[7];
    const float* bih_d = (const float*)d_in[8];
    const float* bhh_d = (const float*)d_in[9];
    const float* wq_d  = (const float*)d_in[10];
    const float* wo_d  = (const float*)d_in[11];
    const float* wih_w = (const float*)d_in[12];
    const float* whh_w = (const float*)d_in[13];
    const float* bih_w = (const float*)d_in[14];
    const float* bhh_w = (const float*)d_in[15];
    const float* wq_w  = (const float*)d_in[16];
    const float* wo_w  = (const float*)d_in[17];
    const float* fcw   = (const float*)d_in[18];
    const float* fcb   = (const float*)d_in[19];

    float* out_dec  = (float*)d_out;                  // [8,640,32000]
    float* out_attn = out_dec + 163840000L;           // [8,16,400] zeros
    float* out_watt = out_attn + 51200;               // [128,40,400]
    float* out_last = out_watt + 2048000;             // [8,512]

    char* wsp = (char*)d_ws;
    auto alloc = [&](size_t bytes) -> void* {
        void* p = wsp;
        wsp += (bytes + 255) & ~(size_t)255;
        return p;
    };

    float* xW    = (float*)alloc(40L * 128 * 2048 * 4);
    u16* hAllH   = (u16*)alloc(41L * 128 * 512 * 2);
    u16* hAllL   = (u16*)alloc(41L * 128 * 512 * 2);
    float* wc    = (float*)alloc(128L * 512 * 4);
    u16* xinH    = (u16*)alloc(5120L * 512 * 2);
    u16* xinL    = (u16*)alloc(5120L * 512 * 2);
    u16* WihH    = (u16*)alloc(2048L * 512 * 2);
    u16* WihL    = (u16*)alloc(2048L * 512 * 2);
    u16* WhhH    = (u16*)alloc(2048L * 512 * 2);
    u16* WhhL    = (u16*)alloc(2048L * 512 * 2);
    u16* wqTH    = (u16*)alloc(512L * 512 * 2);
    u16* wqTL    = (u16*)alloc(512L * 512 * 2);
    u16* wqdTH   = (u16*)alloc(512L * 512 * 2);
    u16* wqdTL   = (u16*)alloc(512L * 512 * 2);
    u16* enc1H   = (u16*)alloc(3200L * 512 * 2);
    u16* enc1L   = (u16*)alloc(3200L * 512 * 2);
    u16* enc0H   = (u16*)alloc(3200L * 512 * 2);
    u16* enc0L   = (u16*)alloc(3200L * 512 * 2);
    u16* sq1H    = (u16*)alloc(3328L * 512 * 2);
    u16* sq1L    = (u16*)alloc(3328L * 512 * 2);
    float* E0q   = (float*)alloc(3200L * 512 * 4);
    float* E0o   = (float*)alloc(3200L * 512 * 4);
    u16* woCH    = (u16*)alloc(512L * 512 * 2);
    u16* woCL    = (u16*)alloc(512L * 512 * 2);
    u16* WpH     = (u16*)alloc(2048L * 1024 * 2);
    u16* WpL     = (u16*)alloc(2048L * 1024 * 2);
    float* wsS   = (float*)alloc(5120L * 512 * 4);
    u16* Pbf     = (u16*)alloc(5120L * 416 * 2);
    u16* enc1T   = (u16*)alloc(8L * 512 * 416 * 2);
    u16* catB    = (u16*)alloc(5120L * 1024 * 2);
    u16* woB     = (u16*)alloc(512L * 1024 * 2);
    u16* Alog    = (u16*)alloc(5120L * 512 * 2);
    u16* fcwB    = (u16*)alloc(32000L * 512 * 2);
    float* biasc = (float*)alloc(2048 * 4);
    float* biasd = (float*)alloc(2048 * 4);
    float* dhA   = (float*)alloc(8L * 512 * 4);
    float* dhB   = (float*)alloc(8L * 512 * 4);
    float* dc    = (float*)alloc(8L * 512 * 4);
    float* dx    = (float*)alloc(8L * 512 * 4);
    float* dsc   = (float*)alloc(8L * 400 * 4);
    float* whoh  = (float*)alloc(8L * 512 * 4);
    float* dsent = (float*)alloc(128L * 512 * 4);
    int* bar     = (int*)alloc(64);

    // ---- 1: all prep ----
    prep_all<<<dim3(33994), 256, 0, stream>>>(
        wih_w, whh_w, enc1, enc0, wq_w, wq_d, wo_w, fcw, toks, emb, spe,
        bih_w, bhh_w, bih_d, bhh_d, wih_d, whh_d, wo_d,
        WihH, WihL, WhhH, WhhL, enc1H, enc1L, enc0H, enc0L,
        wqTH, wqTL, wqdTH, wqdTL, woB, fcwB, enc1T, xinH, xinL,
        woCH, woCL, WpH, WpL, biasc, biasd, out_attn, bar);

    // ---- 2-5: input-side GEMMs (split-accurate) ----
    gemm_bt<true, 0, 2><<<dim3(4, 25, 1), 256, 0, stream>>>(
        enc1H, enc1L, 512, 0, wqTH, wqTL, 512, 0,
        nullptr, sq1H, sq1L, 512, 0, nullptr, 512);

    gemm_bt<true, 0, 0><<<dim3(4, 25, 1), 256, 0, stream>>>(
        enc0H, enc0L, 512, 0, wqdTH, wqdTL, 512, 0,
        E0q, nullptr, nullptr, 512, 0, nullptr, 512);

    gemm_bt<true, 0, 0><<<dim3(4, 25, 1), 256, 0, stream>>>(
        enc0H, enc0L, 512, 0, woCH, woCL, 512, 0,
        E0o, nullptr, nullptr, 512, 0, nullptr, 512);

    gemm_bt<true, 0, 1><<<dim3(16, 40, 1), 256, 0, stream>>>(
        xinH, xinL, 512, 0, WihH, WihL, 512, 0,
        xW, nullptr, nullptr, 2048, 0, biasc, 512);

    // ---- 6: document-level loop (single kernel) ----
    doc_mega<<<dim3(128), 128, 0, stream>>>(
        enc0, E0q, E0o, mask, emb, WpH, WpL, biasd, wo_d,
        dx, dhA, dhB, dc, dsc, whoh, dsent, out_last, bar);

    // ---- 7: word-level LSTM recurrence (single kernel) ----
    word_mega<<<dim3(64), 256, 0, stream>>>(
        dsent, hAllH, hAllL, WhhH, WhhL, xW, wc, catB, bar + 2);

    // ---- 8: batched word attention scores ----
    gemm_bt<true, 1, 0><<<dim3(4, 5, 8), 256, 0, stream>>>(
        hAllH, hAllL, 0, 0, sq1H, sq1L, 512, 204800L,
        wsS, nullptr, nullptr, 512, 327680L, nullptr, 512);

    // ---- 9: softmax -> out_watt + Pbf ----
    word_softmax<<<dim3(5120), 256, 0, stream>>>(wsS, mask, out_watt, Pbf);

    // ---- 10: ctx = P @ enc1 -> catB[:, 0:512] ----
    gemm_bt<false, 0, 4><<<dim3(4, 5, 8), 256, 0, stream>>>(
        Pbf, nullptr, 416, 266240L, enc1T, nullptr, 416, 212992L,
        nullptr, catB, nullptr, 1024, 655360L, nullptr, 416);

    // ---- 11: out = tanh(cat @ wo^T) ----
    gemm_bt<false, 0, 3><<<dim3(4, 40, 1), 256, 0, stream>>>(
        catB, nullptr, 1024, 0, woB, nullptr, 1024, 0,
        nullptr, Alog, nullptr, 512, 0, nullptr, 1024);

    // ---- 12: logits ----
    gemm_bt<false, 0, 1><<<dim3(250, 40, 1), 256, 0, stream>>>(
        Alog, nullptr, 512, 0, fcwB, nullptr, 512, 0,
        out_dec, nullptr, nullptr, 32000, 0, fcb, 512);
}

// Round 5
// 2560.262 us; speedup vs baseline: 2.4676x; 1.0579x over previous
//
#include <hip/hip_runtime.h>
#include <cstdint>

typedef unsigned short u16;
typedef __attribute__((ext_vector_type(8))) short bf16x8;
typedef __attribute__((ext_vector_type(8))) unsigned short u16x8;
typedef __attribute__((ext_vector_type(4))) float f32x4;

struct us4 { u16 a, b, c, d; };

__device__ __forceinline__ u16 f2bf(float f) {
    uint32_t u = __float_as_uint(f);
    uint32_t r = (u + 0x7FFFu + ((u >> 16) & 1u)) >> 16;
    return (u16)r;
}
__device__ __forceinline__ float bf2f(u16 h) { return __uint_as_float(((uint32_t)h) << 16); }
__device__ __forceinline__ float sigm(float x) { return 1.f / (1.f + expf(-x)); }
__device__ __forceinline__ float dot4(float4 a, float4 b) {
    return a.x * b.x + a.y * b.y + a.z * b.z + a.w * b.w;
}
__device__ __forceinline__ float wave_sum(float v) {
#pragma unroll
    for (int o = 32; o; o >>= 1) v += __shfl_down(v, o);
    return v;
}
__device__ __forceinline__ float wave_max(float v) {
#pragma unroll
    for (int o = 32; o; o >>= 1) v = fmaxf(v, __shfl_down(v, o));
    return v;
}

// Device-scope software grid barrier. RELAXED poll (no per-poll L2 invalidate;
// one trailing fence gives acquire semantics once). bar zeroed by prep_all.
__device__ __forceinline__ void grid_barrier(int* bar, int nblk) {
    __syncthreads();
    if (threadIdx.x == 0) {
        __threadfence();
        int g = __hip_atomic_load(bar + 1, __ATOMIC_RELAXED, __HIP_MEMORY_SCOPE_AGENT);
        if (__hip_atomic_fetch_add(bar, 1, __ATOMIC_ACQ_REL, __HIP_MEMORY_SCOPE_AGENT) == nblk - 1) {
            __hip_atomic_store(bar, 0, __ATOMIC_RELAXED, __HIP_MEMORY_SCOPE_AGENT);
            __hip_atomic_store(bar + 1, g + 1, __ATOMIC_RELEASE, __HIP_MEMORY_SCOPE_AGENT);
        } else {
            while (__hip_atomic_load(bar + 1, __ATOMIC_RELAXED, __HIP_MEMORY_SCOPE_AGENT) == g) {
                __builtin_amdgcn_s_sleep(1);
            }
        }
        __threadfence();
    }
    __syncthreads();
}

// ---------------------------------------------------------------------------
// Generic 128x128-tile BT GEMM: C[M,N] = A[M,K] * B[N,K]^T
// XMAJ=1: m-tile on blockIdx.x (consecutive bids share the B-tile -> L2 reuse)
// ---------------------------------------------------------------------------
template <bool SPLIT, int AMODE, int EPI, int XMAJ = 0>
__global__ __launch_bounds__(256) void gemm_bt(
    const u16* __restrict__ AH, const u16* __restrict__ AL, int lda, long strideA,
    const u16* __restrict__ BH, const u16* __restrict__ BL, int ldb, long strideB,
    float* __restrict__ C, u16* __restrict__ CH, u16* __restrict__ CL,
    int ldc, long strideC, const float* __restrict__ bias, int K)
{
    constexpr int TL = 40;
    constexpr int CHK = 128 * TL;
    __shared__ u16 sm[(SPLIT ? 4 : 2) * CHK];
    u16* sAH = sm;
    u16* sBH = sm + CHK;
    u16* sAL = SPLIT ? sm + 2 * CHK : sm;
    u16* sBL = SPLIT ? sm + 3 * CHK : sm;

    const int tid = threadIdx.x;
    const int lane = tid & 63, w = tid >> 6;
    const int wm = w >> 1, wn = w & 1;
    const int lane15 = lane & 15, q8 = (lane >> 4) << 3;
    const int n0 = (XMAJ ? blockIdx.y : blockIdx.x) * 128;
    const int m0 = (XMAJ ? blockIdx.x : blockIdx.y) * 128;
    const int z = blockIdx.z;

    const int r = tid >> 2, c8 = (tid & 3) * 8;

    long aoff[2], boff[2];
#pragma unroll
    for (int h2 = 0; h2 < 2; ++h2) {
        int row = r + (h2 << 6);
        if (AMODE == 0) {
            aoff[h2] = strideA * z + (long)(m0 + row) * lda + c8;
        } else {
            int m = m0 + row;
            int t = m % 40, dd = m / 40;
            aoff[h2] = ((long)(t + 1) * 128 + (z * 16 + dd)) * 512 + c8;
        }
        boff[h2] = strideB * z + (long)(n0 + row) * ldb + c8;
    }

    f32x4 acc[4][4] = {};

    for (int k0 = 0; k0 < K; k0 += 32) {
#pragma unroll
        for (int h2 = 0; h2 < 2; ++h2) {
            int row = r + (h2 << 6);
            int sidx = row * TL + c8;
            *(u16x8*)&sAH[sidx] = *(const u16x8*)&AH[aoff[h2] + k0];
            *(u16x8*)&sBH[sidx] = *(const u16x8*)&BH[boff[h2] + k0];
            if constexpr (SPLIT) {
                *(u16x8*)&sAL[sidx] = *(const u16x8*)&AL[aoff[h2] + k0];
                *(u16x8*)&sBL[sidx] = *(const u16x8*)&BL[boff[h2] + k0];
            }
        }
        __syncthreads();

        bf16x8 a[4], b[4], al[4], bl[4];
#pragma unroll
        for (int i = 0; i < 4; ++i) {
            a[i] = *(const bf16x8*)&sAH[(wm * 64 + i * 16 + lane15) * TL + q8];
            b[i] = *(const bf16x8*)&sBH[(wn * 64 + i * 16 + lane15) * TL + q8];
            if constexpr (SPLIT) {
                al[i] = *(const bf16x8*)&sAL[(wm * 64 + i * 16 + lane15) * TL + q8];
                bl[i] = *(const bf16x8*)&sBL[(wn * 64 + i * 16 + lane15) * TL + q8];
            }
        }
#pragma unroll
        for (int mt = 0; mt < 4; ++mt)
#pragma unroll
            for (int nt = 0; nt < 4; ++nt) {
                acc[mt][nt] = __builtin_amdgcn_mfma_f32_16x16x32_bf16(a[mt], b[nt], acc[mt][nt], 0, 0, 0);
                if constexpr (SPLIT) {
                    acc[mt][nt] = __builtin_amdgcn_mfma_f32_16x16x32_bf16(a[mt], bl[nt], acc[mt][nt], 0, 0, 0);
                    acc[mt][nt] = __builtin_amdgcn_mfma_f32_16x16x32_bf16(al[mt], b[nt], acc[mt][nt], 0, 0, 0);
                }
            }
        __syncthreads();
    }

#pragma unroll
    for (int mt = 0; mt < 4; ++mt)
#pragma unroll
        for (int nt = 0; nt < 4; ++nt)
#pragma unroll
            for (int i = 0; i < 4; ++i) {
                int row = m0 + wm * 64 + mt * 16 + ((lane >> 4) << 2) + i;
                int col = n0 + wn * 64 + nt * 16 + lane15;
                long off = strideC * z + (long)row * ldc + col;
                float v = acc[mt][nt][i];
                if constexpr (EPI == 0) {
                    C[off] = v;
                } else if constexpr (EPI == 1) {
                    C[off] = v + bias[col];
                } else if constexpr (EPI == 2) {
                    u16 h_ = f2bf(v);
                    CH[off] = h_;
                    CL[off] = f2bf(v - bf2f(h_));
                } else if constexpr (EPI == 3) {
                    CH[off] = f2bf(tanhf(v));
                } else {
                    CH[off] = f2bf(v);
                }
            }
}

// ---------------------------------------------------------------------------
// Doc-level loop v2: 128 blocks x 128 threads, 3 grid barriers per step.
// ---------------------------------------------------------------------------
__global__ __launch_bounds__(128) void doc_mega(
    const float* __restrict__ enc0, const float* __restrict__ E0q,
    const float* __restrict__ E0o, const unsigned char* __restrict__ mask,
    const float* __restrict__ emb,
    const u16* __restrict__ WpH, const u16* __restrict__ WpL,
    const float* __restrict__ biasd, const float* __restrict__ wo_d,
    float* __restrict__ dx, float* __restrict__ dhA, float* __restrict__ dhB,
    float* __restrict__ dc, float* __restrict__ dsc, float* __restrict__ whoh,
    float* __restrict__ dsent, float* __restrict__ out_last, int* bar)
{
    __shared__ u16 xhH[16 * 1032];
    __shared__ u16 xhL[16 * 1032];
    __shared__ float tileC[16 * 17];
    __shared__ float aux2[1024];

    const int blk = blockIdx.x, tid = threadIdx.x;
    const int w = tid >> 6, lane = tid & 63;
    const int b_ = blk >> 4, s = blk & 15;
    const int lane15 = lane & 15, q8 = (lane >> 4) << 3;

    for (int q = tid; q < 8 * 1032; q += 128) { xhH[8 * 1032 + q] = 0; xhL[8 * 1032 + q] = 0; }

    {
        int dd = tid & 31, part = tid >> 5;
        const float* p0 = enc0 + ((long)b_ * 400 + part * 100) * 512 + s * 32 + dd;
        float sm = 0.f;
        for (int j = 0; j < 100; ++j) { sm += *p0; p0 += 512; }
        aux2[part * 32 + dd] = sm;
        __syncthreads();
        if (tid < 32) {
            float m = (aux2[tid] + aux2[32 + tid] + aux2[64 + tid] + aux2[96 + tid]) * (1.f / 400.f);
            int e = s * 32 + tid;
            dhA[b_ * 512 + e] = m;
            dc[b_ * 512 + e] = m;
            dx[b_ * 512 + e] = emb[1024 + e];
        }
    }
    grid_barrier(bar, 128);

    const u16* bh_base = WpH + ((long)blk * 16 + lane15) * 1024 + q8;
    const u16* bl_base = WpL + ((long)blk * 16 + lane15) * 1024 + q8;
    const u16* ah_base = xhH + lane15 * 1032 + q8;
    const u16* al_base = xhL + lane15 * 1032 + q8;

    for (int t = 0; t < 16; ++t) {
        const float* hin = (t & 1) ? dhB : dhA;
        float* hout = (t & 1) ? dhA : dhB;

        // ---- A: stage xh (split bf16), MFMA gates, LSTM elementwise ----
        for (int q = tid; q < 2048; q += 128) {
            int b = q >> 8, c4 = q & 255;
            float4 v = (c4 < 128) ? ((const float4*)dx)[b * 128 + c4]
                                  : ((const float4*)hin)[b * 128 + c4 - 128];
            int o = b * 1032 + c4 * 4;
            u16 h0 = f2bf(v.x), h1 = f2bf(v.y), h2 = f2bf(v.z), h3 = f2bf(v.w);
            *(us4*)&xhH[o] = {h0, h1, h2, h3};
            *(us4*)&xhL[o] = {f2bf(v.x - bf2f(h0)), f2bf(v.y - bf2f(h1)),
                              f2bf(v.z - bf2f(h2)), f2bf(v.w - bf2f(h3))};
        }
        __syncthreads();

        f32x4 acc = {};
        for (int k0 = w * 512; k0 < w * 512 + 512; k0 += 32) {
            bf16x8 aH = *(const bf16x8*)&ah_base[k0];
            bf16x8 aL = *(const bf16x8*)&al_base[k0];
            bf16x8 bH = *(const bf16x8*)&bh_base[k0];
            bf16x8 bL = *(const bf16x8*)&bl_base[k0];
            acc = __builtin_amdgcn_mfma_f32_16x16x32_bf16(aH, bH, acc, 0, 0, 0);
            acc = __builtin_amdgcn_mfma_f32_16x16x32_bf16(aH, bL, acc, 0, 0, 0);
            acc = __builtin_amdgcn_mfma_f32_16x16x32_bf16(aL, bH, acc, 0, 0, 0);
        }
        if (w == 1) {
#pragma unroll
            for (int i = 0; i < 4; ++i)
                tileC[((lane >> 4) * 4 + i) * 17 + lane15] = acc[i];
        }
        __syncthreads();
        if (w == 0) {
#pragma unroll
            for (int i = 0; i < 4; ++i)
                tileC[((lane >> 4) * 4 + i) * 17 + lane15] += acc[i];
        }
        __syncthreads();
        if (tid < 32) {
            int b = tid & 7, u4 = tid >> 3;
            int u = blk * 4 + u4;
            float gi = tileC[b * 17 + u4 * 4 + 0] + biasd[u];
            float gf = tileC[b * 17 + u4 * 4 + 1] + biasd[512 + u];
            float gg = tileC[b * 17 + u4 * 4 + 2] + biasd[1024 + u];
            float go = tileC[b * 17 + u4 * 4 + 3] + biasd[1536 + u];
            float cc = dc[b * 512 + u];
            cc = sigm(gf) * cc + sigm(gi) * tanhf(gg);
            dc[b * 512 + u] = cc;
            hout[b * 512 + u] = sigm(go) * tanhf(cc);
        }
        grid_barrier(bar, 128);

        // ---- B: scores for j-slice + whoh for d-slice ----
        {
            ((float4*)aux2)[tid] = ((const float4*)hout)[b_ * 128 + tid];
            __syncthreads();
            for (int jj = w; jj < 25; jj += 2) {
                int j = s * 25 + jj;
                const float4* er = (const float4*)(E0q + ((long)b_ * 400 + j) * 512) + lane * 2;
                const float4* hv = (const float4*)aux2 + lane * 2;
                float sv = dot4(er[0], hv[0]) + dot4(er[1], hv[1]);
                sv = wave_sum(sv);
                if (lane == 0) dsc[b_ * 400 + j] = mask[b_ * 400 + j] ? -1e9f : sv;
            }
            for (int di = w; di < 32; di += 2) {
                int d = s * 32 + di;
                const float4* wr = (const float4*)(wo_d + (long)d * 1024 + 512) + lane * 2;
                const float4* hv = (const float4*)aux2 + lane * 2;
                float sv = dot4(wr[0], hv[0]) + dot4(wr[1], hv[1]);
                sv = wave_sum(sv);
                if (lane == 0) whoh[b_ * 512 + d] = sv;
            }
        }
        grid_barrier(bar, 128);

        // ---- C: softmax (redundant per block) + out via E0o ----
        {
            float v0 = dsc[b_ * 400 + tid];
            float v1 = dsc[b_ * 400 + tid + 128];
            float v2 = dsc[b_ * 400 + tid + 256];
            bool h3 = (tid + 384) < 400;
            float v3 = h3 ? dsc[b_ * 400 + tid + 384] : -1e30f;
            float mx = wave_max(fmaxf(fmaxf(v0, v1), fmaxf(v2, v3)));
            if (lane == 0) aux2[960 + w] = mx;
            __syncthreads();
            float M = fmaxf(aux2[960], aux2[961]);
            float e0 = expf(v0 - M), e1 = expf(v1 - M), e2 = expf(v2 - M);
            float e3 = h3 ? expf(v3 - M) : 0.f;
            float sv = wave_sum(e0 + e1 + e2 + e3);
            if (lane == 0) aux2[962 + w] = sv;
            __syncthreads();
            float inv = 1.f / (aux2[962] + aux2[963]);
            aux2[tid] = e0 * inv;
            aux2[tid + 128] = e1 * inv;
            aux2[tid + 256] = e2 * inv;
            if (h3) aux2[tid + 384] = e3 * inv;
            __syncthreads();
            int dd = tid & 31, part = tid >> 5;
            const float* eo = E0o + ((long)b_ * 400 + part * 100) * 512 + s * 32 + dd;
            float acc2 = 0.f;
            for (int j = 0; j < 100; ++j) { acc2 += aux2[part * 100 + j] * (*eo); eo += 512; }
            aux2[512 + part * 32 + dd] = acc2;
            __syncthreads();
            if (tid < 32) {
                int d = s * 32 + tid;
                float o = aux2[512 + tid] + aux2[544 + tid] + aux2[576 + tid] + aux2[608 + tid]
                        + whoh[b_ * 512 + d];
                float val = tanhf(o);
                dx[b_ * 512 + d] = val;
                dsent[((b_ << 4) + t) * 512 + d] = val;
                if (t == 15) out_last[b_ * 512 + d] = val;
            }
        }
        grid_barrier(bar, 128);
    }
}

// ---------------------------------------------------------------------------
// Word-level loop v2: 256 blocks x 512 threads, K-split 8 across waves.
// Block = one (16 b2 x 16 u x 4 gates) tile; wave w covers K in [w*64,w*64+64).
// Partials reduced via LDS; 8 waves/CU hides L2 latency.
// ---------------------------------------------------------------------------
__global__ __launch_bounds__(512) void word_mega(
    const float* __restrict__ sentS,
    u16* __restrict__ hAllH, u16* __restrict__ hAllL,
    const u16* __restrict__ WhhH, const u16* __restrict__ WhhL,
    const float* __restrict__ xW, float* __restrict__ wc,
    u16* __restrict__ catB, int* bar)
{
    __shared__ float red[8][4][256];   // 32 KB
    const int tid = threadIdx.x, blk = blockIdx.x;

    // init: hAll[0] (hi/lo) + wc from sentS (16384 float4 over blocks 0..31)
    {
        int q = blk * 512 + tid;
        if (q < 16384) {
            float4 v = ((const float4*)sentS)[q];
            float vv[4] = {v.x, v.y, v.z, v.w};
#pragma unroll
            for (int j = 0; j < 4; ++j) {
                int i = q * 4 + j;
                u16 hh = f2bf(vv[j]);
                hAllH[i] = hh;
                hAllL[i] = f2bf(vv[j] - bf2f(hh));
                wc[i] = vv[j];
            }
        }
    }
    grid_barrier(bar, 256);

    const int w = tid >> 6, lane = tid & 63;          // w = K-split index
    const int b2t = blk >> 5;                         // 8 batch-row tiles
    const int u0 = (blk & 31) << 4;                   // 32 unit tiles
    const int lane15 = lane & 15, q8 = (lane >> 4) << 3;
    const long arow = (long)(b2t * 16 + lane15) * 512 + w * 64 + q8;
    long brow[4];
#pragma unroll
    for (int g = 0; g < 4; ++g)
        brow[g] = (long)(g * 512 + u0 + lane15) * 512 + w * 64 + q8;

    for (int t = 0; t < 40; ++t) {
        const u16* hH = hAllH + (long)t * 65536;
        const u16* hL = hAllL + (long)t * 65536;
        f32x4 acc[4] = {};
#pragma unroll
        for (int k0 = 0; k0 < 64; k0 += 32) {
            bf16x8 aH = *(const bf16x8*)&hH[arow + k0];
            bf16x8 aL = *(const bf16x8*)&hL[arow + k0];
#pragma unroll
            for (int g = 0; g < 4; ++g) {
                bf16x8 bH = *(const bf16x8*)&WhhH[brow[g] + k0];
                bf16x8 bL = *(const bf16x8*)&WhhL[brow[g] + k0];
                acc[g] = __builtin_amdgcn_mfma_f32_16x16x32_bf16(aH, bH, acc[g], 0, 0, 0);
                acc[g] = __builtin_amdgcn_mfma_f32_16x16x32_bf16(aH, bL, acc[g], 0, 0, 0);
                acc[g] = __builtin_amdgcn_mfma_f32_16x16x32_bf16(aL, bH, acc[g], 0, 0, 0);
            }
        }
#pragma unroll
        for (int g = 0; g < 4; ++g)
#pragma unroll
            for (int i = 0; i < 4; ++i)
                red[w][g][((lane >> 4) * 4 + i) * 16 + lane15] = acc[g][i];
        __syncthreads();

        if (tid < 256) {
            const int rc = tid;
            float g4[4] = {0.f, 0.f, 0.f, 0.f};
#pragma unroll
            for (int ks = 0; ks < 8; ++ks)
#pragma unroll
                for (int g = 0; g < 4; ++g)
                    g4[g] += red[ks][g][rc];
            int b2 = b2t * 16 + (rc >> 4);
            int u = u0 + (rc & 15);
            const float* xr = xW + (long)t * 262144 + (long)b2 * 2048;
            float gi = g4[0] + xr[u];
            float gf = g4[1] + xr[512 + u];
            float gg = g4[2] + xr[1024 + u];
            float go = g4[3] + xr[1536 + u];
            long cidx = (long)b2 * 512 + u;
            float cc = wc[cidx];
            cc = sigm(gf) * cc + sigm(gi) * tanhf(gg);
            wc[cidx] = cc;
            float hv = sigm(go) * tanhf(cc);
            u16 hh = f2bf(hv);
            hAllH[(long)(t + 1) * 65536 + cidx] = hh;
            hAllL[(long)(t + 1) * 65536 + cidx] = f2bf(hv - bf2f(hh));
            catB[((long)b2 * 40 + t) * 1024 + 512 + u] = hh;
        }
        // grid_barrier's entry __syncthreads orders red reads vs next writes
        grid_barrier(bar, 256);
    }
}

// ---------------------------------------------------------------------------
// All prep work in one region-dispatched kernel (also zeroes out_attn & bars).
// ---------------------------------------------------------------------------
__device__ __forceinline__ void split1(const float* __restrict__ src,
                                       u16* __restrict__ H, u16* __restrict__ L, long i)
{
    float4 v = ((const float4*)src)[i];
    u16 h0 = f2bf(v.x), h1 = f2bf(v.y), h2 = f2bf(v.z), h3 = f2bf(v.w);
    ((us4*)H)[i] = {h0, h1, h2, h3};
    ((us4*)L)[i] = {f2bf(v.x - bf2f(h0)), f2bf(v.y - bf2f(h1)),
                    f2bf(v.z - bf2f(h2)), f2bf(v.w - bf2f(h3))};
}
__device__ __forceinline__ void wqT1(const float* __restrict__ wq,
                                     u16* __restrict__ H, u16* __restrict__ L, int idx)
{
    int e = idx >> 9, d = idx & 511;
    float v = wq[(long)d * 512 + e];
    u16 h = f2bf(v);
    H[idx] = h;
    L[idx] = f2bf(v - bf2f(h));
}

__global__ __launch_bounds__(256) void prep_all(
    const float* __restrict__ wih_w, const float* __restrict__ whh_w,
    const float* __restrict__ enc1, const float* __restrict__ enc0,
    const float* __restrict__ wq_w, const float* __restrict__ wq_d,
    const float* __restrict__ wo_w, const float* __restrict__ fcw,
    const int* __restrict__ toks, const float* __restrict__ emb,
    const float* __restrict__ spe,
    const float* __restrict__ bih_w, const float* __restrict__ bhh_w,
    const float* __restrict__ bih_d, const float* __restrict__ bhh_d,
    const float* __restrict__ wih_d, const float* __restrict__ whh_d,
    const float* __restrict__ wo_d,
    u16* __restrict__ WihH, u16* __restrict__ WihL,
    u16* __restrict__ WhhH, u16* __restrict__ WhhL,
    u16* __restrict__ enc1H, u16* __restrict__ enc1L,
    u16* __restrict__ enc0H, u16* __restrict__ enc0L,
    u16* __restrict__ wqTH, u16* __restrict__ wqTL,
    u16* __restrict__ wqdTH, u16* __restrict__ wqdTL,
    u16* __restrict__ woB, u16* __restrict__ fcwB, u16* __restrict__ enc1T,
    u16* __restrict__ xinH, u16* __restrict__ xinL,
    u16* __restrict__ woCH, u16* __restrict__ woCL,
    u16* __restrict__ WpH, u16* __restrict__ WpL,
    float* __restrict__ biasc, float* __restrict__ biasd,
    float* __restrict__ out_attn, int* __restrict__ bar)
{
    int b = blockIdx.x;
    const int tid = threadIdx.x;

    if (b < 1024) { split1(wih_w, WihH, WihL, (long)b * 256 + tid); return; }
    b -= 1024;
    if (b < 1024) { split1(whh_w, WhhH, WhhL, (long)b * 256 + tid); return; }
    b -= 1024;
    if (b < 1600) { split1(enc1, enc1H, enc1L, (long)b * 256 + tid); return; }
    b -= 1600;
    if (b < 1600) { split1(enc0, enc0H, enc0L, (long)b * 256 + tid); return; }
    b -= 1600;
    if (b < 1024) { wqT1(wq_w, wqTH, wqTL, b * 256 + tid); return; }
    b -= 1024;
    if (b < 1024) { wqT1(wq_d, wqdTH, wqdTL, b * 256 + tid); return; }
    b -= 1024;
    if (b < 512) {
        long i = (long)b * 256 + tid;
        float4 v = ((const float4*)wo_w)[i];
        ((us4*)woB)[i] = {f2bf(v.x), f2bf(v.y), f2bf(v.z), f2bf(v.w)};
        return;
    }
    b -= 512;
    if (b < 16000) {
        long i = (long)b * 256 + tid;
        float4 v = ((const float4*)fcw)[i];
        ((us4*)fcwB)[i] = {f2bf(v.x), f2bf(v.y), f2bf(v.z), f2bf(v.w)};
        return;
    }
    b -= 16000;
    if (b < 6656) {
        long idx = (long)b * 256 + tid;
        int j = (int)(idx % 416);
        long be = idx / 416;
        int e = (int)(be % 512);
        int bb = (int)(be / 512);
        float v = (j < 400) ? enc1[((long)bb * 400 + j) * 512 + e] : 0.f;
        enc1T[idx] = f2bf(v);
        return;
    }
    b -= 6656;
    if (b < 1280) {
        int g = b * 256 + tid;
        int m = g >> 6, e0 = (g & 63) << 3;
        int t = m >> 7, b2 = m & 127;
        int ne = 0;
        for (int s = 0; s < 40; ++s) ne |= (toks[b2 * 40 + s] != 1);
        int pos = ne ? (2 + (b2 & 15)) : 1;
        const float* ep = emb + (long)toks[b2 * 40 + t] * 512 + e0;
        const float* sp = spe + (long)pos * 512 + e0;
        long o = (long)m * 512 + e0;
#pragma unroll
        for (int j = 0; j < 8; ++j) {
            float v = ep[j] + sp[j];
            u16 h = f2bf(v);
            xinH[o + j] = h;
            xinL[o + j] = f2bf(v - bf2f(h));
        }
        return;
    }
    b -= 1280;
    if (b < 1) {
        for (int i = tid; i < 2048; i += 256) {
            biasc[i] = bih_w[i] + bhh_w[i];
            biasd[i] = bih_d[i] + bhh_d[i];
        }
        return;
    }
    b -= 1;
    if (b < 200) {
        out_attn[b * 256 + tid] = 0.f;
        return;
    }
    b -= 200;
    if (b < 1024) {
        int i = b * 256 + tid;
        int d = i >> 9, e = i & 511;
        float v = wo_d[(long)d * 1024 + e];
        u16 h = f2bf(v);
        woCH[i] = h;
        woCL[i] = f2bf(v - bf2f(h));
        return;
    }
    b -= 1024;
    if (b < 1024) {
        long gidx = (long)b * 256 + tid;
        int r = (int)(gidx >> 7);
        int k8 = ((int)gidx & 127) * 8;
        int u = r >> 2, g = r & 3;
        long orow = (long)(g * 512 + u);
#pragma unroll
        for (int j = 0; j < 8; ++j) {
            int k = k8 + j;
            float v = (k < 512) ? wih_d[orow * 512 + k] : whh_d[orow * 512 + k - 512];
            u16 h = f2bf(v);
            WpH[(long)r * 1024 + k] = h;
            WpL[(long)r * 1024 + k] = f2bf(v - bf2f(h));
        }
        return;
    }
    b -= 1024;
    if (tid < 8) bar[tid] = 0;
}

__global__ __launch_bounds__(256) void word_softmax(
    const float* __restrict__ sc, const unsigned char* __restrict__ mask,
    float* __restrict__ pout, u16* __restrict__ pbf)
{
    const int r = blockIdx.x, tid = threadIdx.x;
    const int b = r / 640;
    const int wv = tid >> 6, lane = tid & 63;
    __shared__ float red[4];
    const int j1 = tid + 256;
    float v0 = sc[(long)r * 512 + tid];
    if (mask[b * 400 + tid]) v0 = -1e9f;
    float v1 = -1e30f;
    if (j1 < 400) {
        v1 = sc[(long)r * 512 + j1];
        if (mask[b * 400 + j1]) v1 = -1e9f;
    }
    float mv = wave_max(fmaxf(v0, v1));
    if (lane == 0) red[wv] = mv;
    __syncthreads();
    if (tid == 0) red[0] = fmaxf(fmaxf(red[0], red[1]), fmaxf(red[2], red[3]));
    __syncthreads();
    const float M = red[0];
    float e0 = expf(v0 - M);
    float e1 = (j1 < 400) ? expf(v1 - M) : 0.f;
    __syncthreads();
    float sv = wave_sum(e0 + e1);
    if (lane == 0) red[wv] = sv;
    __syncthreads();
    if (tid == 0) red[0] = red[0] + red[1] + red[2] + red[3];
    __syncthreads();
    const float inv = 1.f / red[0];
    float p0 = e0 * inv;
    pout[(long)r * 400 + tid] = p0;
    pbf[(long)r * 416 + tid] = f2bf(p0);
    if (j1 < 400) {
        float p1 = e1 * inv;
        pout[(long)r * 400 + j1] = p1;
        pbf[(long)r * 416 + j1] = f2bf(p1);
    } else if (j1 < 416) {
        pbf[(long)r * 416 + j1] = 0;
    }
}

// ---------------------------------------------------------------------------
extern "C" void kernel_launch(void* const* d_in, const int* in_sizes, int n_in,
                              void* d_out, int out_size, void* d_ws, size_t ws_size,
                              hipStream_t stream)
{
    (void)in_sizes; (void)n_in; (void)out_size; (void)ws_size;

    const int*   toks  = (const int*)  d_in[0];
    const float* enc0  = (const float*)d_in[1];
    const float* enc1  = (const float*)d_in[2];
    const unsigned char* mask = (const unsigned char*)d_in[3];
    const float* emb   = (const float*)d_in[4];
    const float* spe   = (const float*)d_in[5];
    const float* wih_d = (const float*)d_in[6];
    const float* whh_d = (const float*)d_in[7];
    const float* bih_d = (const float*)d_in[8];
    const float* bhh_d = (const float*)d_in[9];
    const float* wq_d  = (const float*)d_in[10];
    const float* wo_d  = (const float*)d_in[11];
    const float* wih_w = (const float*)d_in[12];
    const float* whh_w = (const float*)d_in[13];
    const float* bih_w = (const float*)d_in[14];
    const float* bhh_w = (const float*)d_in[15];
    const float* wq_w  = (const float*)d_in[16];
    const float* wo_w  = (const float*)d_in[17];
    const float* fcw   = (const float*)d_in[18];
    const float* fcb   = (const float*)d_in[19];

    float* out_dec  = (float*)d_out;                  // [8,640,32000]
    float* out_attn = out_dec + 163840000L;           // [8,16,400] zeros
    float* out_watt = out_attn + 51200;               // [128,40,400]
    float* out_last = out_watt + 2048000;             // [8,512]

    char* wsp = (char*)d_ws;
    auto alloc = [&](size_t bytes) -> void* {
        void* p = wsp;
        wsp += (bytes + 255) & ~(size_t)255;
        return p;
    };

    float* xW    = (float*)alloc(40L * 128 * 2048 * 4);
    u16* hAllH   = (u16*)alloc(41L * 128 * 512 * 2);
    u16* hAllL   = (u16*)alloc(41L * 128 * 512 * 2);
    float* wc    = (float*)alloc(128L * 512 * 4);
    u16* xinH    = (u16*)alloc(5120L * 512 * 2);
    u16* xinL    = (u16*)alloc(5120L * 512 * 2);
    u16* WihH    = (u16*)alloc(2048L * 512 * 2);
    u16* WihL    = (u16*)alloc(2048L * 512 * 2);
    u16* WhhH    = (u16*)alloc(2048L * 512 * 2);
    u16* WhhL    = (u16*)alloc(2048L * 512 * 2);
    u16* wqTH    = (u16*)alloc(512L * 512 * 2);
    u16* wqTL    = (u16*)alloc(512L * 512 * 2);
    u16* wqdTH   = (u16*)alloc(512L * 512 * 2);
    u16* wqdTL   = (u16*)alloc(512L * 512 * 2);
    u16* enc1H   = (u16*)alloc(3200L * 512 * 2);
    u16* enc1L   = (u16*)alloc(3200L * 512 * 2);
    u16* enc0H   = (u16*)alloc(3200L * 512 * 2);
    u16* enc0L   = (u16*)alloc(3200L * 512 * 2);
    u16* sq1H    = (u16*)alloc(3328L * 512 * 2);
    u16* sq1L    = (u16*)alloc(3328L * 512 * 2);
    float* E0q   = (float*)alloc(3200L * 512 * 4);
    float* E0o   = (float*)alloc(3200L * 512 * 4);
    u16* woCH    = (u16*)alloc(512L * 512 * 2);
    u16* woCL    = (u16*)alloc(512L * 512 * 2);
    u16* WpH     = (u16*)alloc(2048L * 1024 * 2);
    u16* WpL     = (u16*)alloc(2048L * 1024 * 2);
    float* wsS   = (float*)alloc(5120L * 512 * 4);
    u16* Pbf     = (u16*)alloc(5120L * 416 * 2);
    u16* enc1T   = (u16*)alloc(8L * 512 * 416 * 2);
    u16* catB    = (u16*)alloc(5120L * 1024 * 2);
    u16* woB     = (u16*)alloc(512L * 1024 * 2);
    u16* Alog    = (u16*)alloc(5120L * 512 * 2);
    u16* fcwB    = (u16*)alloc(32000L * 512 * 2);
    float* biasc = (float*)alloc(2048 * 4);
    float* biasd = (float*)alloc(2048 * 4);
    float* dhA   = (float*)alloc(8L * 512 * 4);
    float* dhB   = (float*)alloc(8L * 512 * 4);
    float* dc    = (float*)alloc(8L * 512 * 4);
    float* dx    = (float*)alloc(8L * 512 * 4);
    float* dsc   = (float*)alloc(8L * 400 * 4);
    float* whoh  = (float*)alloc(8L * 512 * 4);
    float* dsent = (float*)alloc(128L * 512 * 4);
    int* bar     = (int*)alloc(64);

    // ---- 1: all prep ----
    prep_all<<<dim3(33994), 256, 0, stream>>>(
        wih_w, whh_w, enc1, enc0, wq_w, wq_d, wo_w, fcw, toks, emb, spe,
        bih_w, bhh_w, bih_d, bhh_d, wih_d, whh_d, wo_d,
        WihH, WihL, WhhH, WhhL, enc1H, enc1L, enc0H, enc0L,
        wqTH, wqTL, wqdTH, wqdTL, woB, fcwB, enc1T, xinH, xinL,
        woCH, woCL, WpH, WpL, biasc, biasd, out_attn, bar);

    // ---- 2-5: input-side GEMMs (split-accurate) ----
    gemm_bt<true, 0, 2><<<dim3(4, 25, 1), 256, 0, stream>>>(
        enc1H, enc1L, 512, 0, wqTH, wqTL, 512, 0,
        nullptr, sq1H, sq1L, 512, 0, nullptr, 512);

    gemm_bt<true, 0, 0><<<dim3(4, 25, 1), 256, 0, stream>>>(
        enc0H, enc0L, 512, 0, wqdTH, wqdTL, 512, 0,
        E0q, nullptr, nullptr, 512, 0, nullptr, 512);

    gemm_bt<true, 0, 0><<<dim3(4, 25, 1), 256, 0, stream>>>(
        enc0H, enc0L, 512, 0, woCH, woCL, 512, 0,
        E0o, nullptr, nullptr, 512, 0, nullptr, 512);

    gemm_bt<true, 0, 1><<<dim3(16, 40, 1), 256, 0, stream>>>(
        xinH, xinL, 512, 0, WihH, WihL, 512, 0,
        xW, nullptr, nullptr, 2048, 0, biasc, 512);

    // ---- 6: document-level loop (single kernel) ----
    doc_mega<<<dim3(128), 128, 0, stream>>>(
        enc0, E0q, E0o, mask, emb, WpH, WpL, biasd, wo_d,
        dx, dhA, dhB, dc, dsc, whoh, dsent, out_last, bar);

    // ---- 7: word-level LSTM recurrence (single kernel, K-split 8) ----
    word_mega<<<dim3(256), 512, 0, stream>>>(
        dsent, hAllH, hAllL, WhhH, WhhL, xW, wc, catB, bar + 2);

    // ---- 8: batched word attention scores ----
    gemm_bt<true, 1, 0><<<dim3(4, 5, 8), 256, 0, stream>>>(
        hAllH, hAllL, 0, 0, sq1H, sq1L, 512, 204800L,
        wsS, nullptr, nullptr, 512, 327680L, nullptr, 512);

    // ---- 9: softmax -> out_watt + Pbf ----
    word_softmax<<<dim3(5120), 256, 0, stream>>>(wsS, mask, out_watt, Pbf);

    // ---- 10: ctx = P @ enc1 -> catB[:, 0:512] ----
    gemm_bt<false, 0, 4><<<dim3(4, 5, 8), 256, 0, stream>>>(
        Pbf, nullptr, 416, 266240L, enc1T, nullptr, 416, 212992L,
        nullptr, catB, nullptr, 1024, 655360L, nullptr, 416);

    // ---- 11: out = tanh(cat @ wo^T) ----
    gemm_bt<false, 0, 3><<<dim3(4, 40, 1), 256, 0, stream>>>(
        catB, nullptr, 1024, 0, woB, nullptr, 1024, 0,
        nullptr, Alog, nullptr, 512, 0, nullptr, 1024);

    // ---- 12: logits (XMAJ grid: consecutive bids share B-tile in L2) ----
    gemm_bt<false, 0, 1, 1><<<dim3(40, 250, 1), 256, 0, stream>>>(
        Alog, nullptr, 512, 0, fcwB, nullptr, 512, 0,
        out_dec, nullptr, nullptr, 32000, 0, fcb, 512);
}

// Round 6
// 2295.086 us; speedup vs baseline: 2.7528x; 1.1155x over previous
//
#include <hip/hip_runtime.h>
#include <cstdint>

typedef unsigned short u16;
typedef __attribute__((ext_vector_type(8))) short bf16x8;
typedef __attribute__((ext_vector_type(8))) unsigned short u16x8;
typedef __attribute__((ext_vector_type(4))) float f32x4;

struct us4 { u16 a, b, c, d; };

__device__ __forceinline__ u16 f2bf(float f) {
    uint32_t u = __float_as_uint(f);
    uint32_t r = (u + 0x7FFFu + ((u >> 16) & 1u)) >> 16;
    return (u16)r;
}
__device__ __forceinline__ float bf2f(u16 h) { return __uint_as_float(((uint32_t)h) << 16); }
__device__ __forceinline__ float sigm(float x) { return 1.f / (1.f + expf(-x)); }
__device__ __forceinline__ float dot4(float4 a, float4 b) {
    return a.x * b.x + a.y * b.y + a.z * b.z + a.w * b.w;
}
__device__ __forceinline__ float wave_sum(float v) {
#pragma unroll
    for (int o = 32; o; o >>= 1) v += __shfl_down(v, o);
    return v;
}
__device__ __forceinline__ float wave_max(float v) {
#pragma unroll
    for (int o = 32; o; o >>= 1) v = fmaxf(v, __shfl_down(v, o));
    return v;
}

// ---------------------------------------------------------------------------
// Sharded device-scope barrier over NBLK blocks. Region layout (32-int lines):
// lines 0..NSHARD-1 = shard arrival counters, line NSHARD = root counter,
// line NSHARD+1 = generation. Arrivals spread over NSHARD cachelines in
// parallel -> ~NBLK/NSHARD serialized atomics instead of NBLK.
// ---------------------------------------------------------------------------
template <int NBLK, int NSHARD>
__device__ __forceinline__ void sbar(int* base, int idx) {
    __syncthreads();
    if (threadIdx.x == 0) {
        __threadfence();
        int* genp = base + (NSHARD + 1) * 32;
        int g = __hip_atomic_load(genp, __ATOMIC_RELAXED, __HIP_MEMORY_SCOPE_AGENT);
        constexpr int SSIZE = NBLK / NSHARD;
        int* sc = base + (idx % NSHARD) * 32;
        bool released = false;
        if (__hip_atomic_fetch_add(sc, 1, __ATOMIC_ACQ_REL, __HIP_MEMORY_SCOPE_AGENT) == SSIZE - 1) {
            __hip_atomic_store(sc, 0, __ATOMIC_RELAXED, __HIP_MEMORY_SCOPE_AGENT);
            int* rc = base + NSHARD * 32;
            if (__hip_atomic_fetch_add(rc, 1, __ATOMIC_ACQ_REL, __HIP_MEMORY_SCOPE_AGENT) == NSHARD - 1) {
                __hip_atomic_store(rc, 0, __ATOMIC_RELAXED, __HIP_MEMORY_SCOPE_AGENT);
                __hip_atomic_store(genp, g + 1, __ATOMIC_RELEASE, __HIP_MEMORY_SCOPE_AGENT);
                released = true;
            }
        }
        if (!released) {
            while (__hip_atomic_load(genp, __ATOMIC_RELAXED, __HIP_MEMORY_SCOPE_AGENT) == g)
                __builtin_amdgcn_s_sleep(1);
        }
        __threadfence();
    }
    __syncthreads();
}

// ---------------------------------------------------------------------------
// Generic 128x128-tile BT GEMM: C[M,N] = A[M,K] * B[N,K]^T
// XMAJ=1: m-tile on blockIdx.x (consecutive bids share the B-tile -> L2 reuse)
// ---------------------------------------------------------------------------
template <bool SPLIT, int AMODE, int EPI, int XMAJ = 0>
__global__ __launch_bounds__(256) void gemm_bt(
    const u16* __restrict__ AH, const u16* __restrict__ AL, int lda, long strideA,
    const u16* __restrict__ BH, const u16* __restrict__ BL, int ldb, long strideB,
    float* __restrict__ C, u16* __restrict__ CH, u16* __restrict__ CL,
    int ldc, long strideC, const float* __restrict__ bias, int K)
{
    constexpr int TL = 40;
    constexpr int CHK = 128 * TL;
    __shared__ u16 sm[(SPLIT ? 4 : 2) * CHK];
    u16* sAH = sm;
    u16* sBH = sm + CHK;
    u16* sAL = SPLIT ? sm + 2 * CHK : sm;
    u16* sBL = SPLIT ? sm + 3 * CHK : sm;

    const int tid = threadIdx.x;
    const int lane = tid & 63, w = tid >> 6;
    const int wm = w >> 1, wn = w & 1;
    const int lane15 = lane & 15, q8 = (lane >> 4) << 3;
    const int n0 = (XMAJ ? blockIdx.y : blockIdx.x) * 128;
    const int m0 = (XMAJ ? blockIdx.x : blockIdx.y) * 128;
    const int z = blockIdx.z;

    const int r = tid >> 2, c8 = (tid & 3) * 8;

    long aoff[2], boff[2];
#pragma unroll
    for (int h2 = 0; h2 < 2; ++h2) {
        int row = r + (h2 << 6);
        if (AMODE == 0) {
            aoff[h2] = strideA * z + (long)(m0 + row) * lda + c8;
        } else {
            int m = m0 + row;
            int t = m % 40, dd = m / 40;
            aoff[h2] = ((long)(t + 1) * 128 + (z * 16 + dd)) * 512 + c8;
        }
        boff[h2] = strideB * z + (long)(n0 + row) * ldb + c8;
    }

    f32x4 acc[4][4] = {};

    for (int k0 = 0; k0 < K; k0 += 32) {
#pragma unroll
        for (int h2 = 0; h2 < 2; ++h2) {
            int row = r + (h2 << 6);
            int sidx = row * TL + c8;
            *(u16x8*)&sAH[sidx] = *(const u16x8*)&AH[aoff[h2] + k0];
            *(u16x8*)&sBH[sidx] = *(const u16x8*)&BH[boff[h2] + k0];
            if constexpr (SPLIT) {
                *(u16x8*)&sAL[sidx] = *(const u16x8*)&AL[aoff[h2] + k0];
                *(u16x8*)&sBL[sidx] = *(const u16x8*)&BL[boff[h2] + k0];
            }
        }
        __syncthreads();

        bf16x8 a[4], b[4], al[4], bl[4];
#pragma unroll
        for (int i = 0; i < 4; ++i) {
            a[i] = *(const bf16x8*)&sAH[(wm * 64 + i * 16 + lane15) * TL + q8];
            b[i] = *(const bf16x8*)&sBH[(wn * 64 + i * 16 + lane15) * TL + q8];
            if constexpr (SPLIT) {
                al[i] = *(const bf16x8*)&sAL[(wm * 64 + i * 16 + lane15) * TL + q8];
                bl[i] = *(const bf16x8*)&sBL[(wn * 64 + i * 16 + lane15) * TL + q8];
            }
        }
#pragma unroll
        for (int mt = 0; mt < 4; ++mt)
#pragma unroll
            for (int nt = 0; nt < 4; ++nt) {
                acc[mt][nt] = __builtin_amdgcn_mfma_f32_16x16x32_bf16(a[mt], b[nt], acc[mt][nt], 0, 0, 0);
                if constexpr (SPLIT) {
                    acc[mt][nt] = __builtin_amdgcn_mfma_f32_16x16x32_bf16(a[mt], bl[nt], acc[mt][nt], 0, 0, 0);
                    acc[mt][nt] = __builtin_amdgcn_mfma_f32_16x16x32_bf16(al[mt], b[nt], acc[mt][nt], 0, 0, 0);
                }
            }
        __syncthreads();
    }

#pragma unroll
    for (int mt = 0; mt < 4; ++mt)
#pragma unroll
        for (int nt = 0; nt < 4; ++nt)
#pragma unroll
            for (int i = 0; i < 4; ++i) {
                int row = m0 + wm * 64 + mt * 16 + ((lane >> 4) << 2) + i;
                int col = n0 + wn * 64 + nt * 16 + lane15;
                long off = strideC * z + (long)row * ldc + col;
                float v = acc[mt][nt][i];
                if constexpr (EPI == 0) {
                    C[off] = v;
                } else if constexpr (EPI == 1) {
                    C[off] = v + bias[col];
                } else if constexpr (EPI == 2) {
                    u16 h_ = f2bf(v);
                    CH[off] = h_;
                    CL[off] = f2bf(v - bf2f(h_));
                } else if constexpr (EPI == 3) {
                    CH[off] = f2bf(tanhf(v));
                } else {
                    CH[off] = f2bf(v);
                }
            }
}

// ---------------------------------------------------------------------------
// Doc-level loop: 128 blocks x 128 threads. Per step: full barrier after A,
// GROUP (batch) barrier after B, full barrier after C. Sharded barriers.
// bar layout: [0..319] full(128,8); [512+b*192] doc group (16,4).
// ---------------------------------------------------------------------------
__global__ __launch_bounds__(128) void doc_mega(
    const float* __restrict__ enc0, const float* __restrict__ E0q,
    const float* __restrict__ E0o, const unsigned char* __restrict__ mask,
    const float* __restrict__ emb,
    const u16* __restrict__ WpH, const u16* __restrict__ WpL,
    const float* __restrict__ biasd, const float* __restrict__ wo_d,
    float* __restrict__ dx, float* __restrict__ dhA, float* __restrict__ dhB,
    float* __restrict__ dc, float* __restrict__ dsc, float* __restrict__ whoh,
    float* __restrict__ dsent, float* __restrict__ out_last, int* bar)
{
    __shared__ u16 xhH[16 * 1032];
    __shared__ u16 xhL[16 * 1032];
    __shared__ float tileC[16 * 17];
    __shared__ float aux2[1024];

    const int blk = blockIdx.x, tid = threadIdx.x;
    const int w = tid >> 6, lane = tid & 63;
    const int b_ = blk >> 4, s = blk & 15;
    const int lane15 = lane & 15, q8 = (lane >> 4) << 3;
    int* gbar = bar + 512 + b_ * 192;

    for (int q = tid; q < 8 * 1032; q += 128) { xhH[8 * 1032 + q] = 0; xhL[8 * 1032 + q] = 0; }

    {
        int dd = tid & 31, part = tid >> 5;
        const float* p0 = enc0 + ((long)b_ * 400 + part * 100) * 512 + s * 32 + dd;
        float sm = 0.f;
        for (int j = 0; j < 100; ++j) { sm += *p0; p0 += 512; }
        aux2[part * 32 + dd] = sm;
        __syncthreads();
        if (tid < 32) {
            float m = (aux2[tid] + aux2[32 + tid] + aux2[64 + tid] + aux2[96 + tid]) * (1.f / 400.f);
            int e = s * 32 + tid;
            dhA[b_ * 512 + e] = m;
            dc[b_ * 512 + e] = m;
            dx[b_ * 512 + e] = emb[1024 + e];
        }
    }
    sbar<128, 8>(bar, blk);

    const u16* bh_base = WpH + ((long)blk * 16 + lane15) * 1024 + q8;
    const u16* bl_base = WpL + ((long)blk * 16 + lane15) * 1024 + q8;
    const u16* ah_base = xhH + lane15 * 1032 + q8;
    const u16* al_base = xhL + lane15 * 1032 + q8;

    for (int t = 0; t < 16; ++t) {
        const float* hin = (t & 1) ? dhB : dhA;
        float* hout = (t & 1) ? dhA : dhB;

        // ---- A: stage xh (split bf16), MFMA gates, LSTM elementwise ----
        for (int q = tid; q < 2048; q += 128) {
            int b = q >> 8, c4 = q & 255;
            float4 v = (c4 < 128) ? ((const float4*)dx)[b * 128 + c4]
                                  : ((const float4*)hin)[b * 128 + c4 - 128];
            int o = b * 1032 + c4 * 4;
            u16 h0 = f2bf(v.x), h1 = f2bf(v.y), h2 = f2bf(v.z), h3 = f2bf(v.w);
            *(us4*)&xhH[o] = {h0, h1, h2, h3};
            *(us4*)&xhL[o] = {f2bf(v.x - bf2f(h0)), f2bf(v.y - bf2f(h1)),
                              f2bf(v.z - bf2f(h2)), f2bf(v.w - bf2f(h3))};
        }
        __syncthreads();

        f32x4 acc = {};
        for (int k0 = w * 512; k0 < w * 512 + 512; k0 += 32) {
            bf16x8 aH = *(const bf16x8*)&ah_base[k0];
            bf16x8 aL = *(const bf16x8*)&al_base[k0];
            bf16x8 bH = *(const bf16x8*)&bh_base[k0];
            bf16x8 bL = *(const bf16x8*)&bl_base[k0];
            acc = __builtin_amdgcn_mfma_f32_16x16x32_bf16(aH, bH, acc, 0, 0, 0);
            acc = __builtin_amdgcn_mfma_f32_16x16x32_bf16(aH, bL, acc, 0, 0, 0);
            acc = __builtin_amdgcn_mfma_f32_16x16x32_bf16(aL, bH, acc, 0, 0, 0);
        }
        if (w == 1) {
#pragma unroll
            for (int i = 0; i < 4; ++i)
                tileC[((lane >> 4) * 4 + i) * 17 + lane15] = acc[i];
        }
        __syncthreads();
        if (w == 0) {
#pragma unroll
            for (int i = 0; i < 4; ++i)
                tileC[((lane >> 4) * 4 + i) * 17 + lane15] += acc[i];
        }
        __syncthreads();
        if (tid < 32) {
            int b = tid & 7, u4 = tid >> 3;
            int u = blk * 4 + u4;
            float gi = tileC[b * 17 + u4 * 4 + 0] + biasd[u];
            float gf = tileC[b * 17 + u4 * 4 + 1] + biasd[512 + u];
            float gg = tileC[b * 17 + u4 * 4 + 2] + biasd[1024 + u];
            float go = tileC[b * 17 + u4 * 4 + 3] + biasd[1536 + u];
            float cc = dc[b * 512 + u];
            cc = sigm(gf) * cc + sigm(gi) * tanhf(gg);
            dc[b * 512 + u] = cc;
            hout[b * 512 + u] = sigm(go) * tanhf(cc);
        }
        sbar<128, 8>(bar, blk);

        // ---- B: scores for j-slice + whoh for d-slice (batch-group data) ----
        {
            ((float4*)aux2)[tid] = ((const float4*)hout)[b_ * 128 + tid];
            __syncthreads();
            for (int jj = w; jj < 25; jj += 2) {
                int j = s * 25 + jj;
                const float4* er = (const float4*)(E0q + ((long)b_ * 400 + j) * 512) + lane * 2;
                const float4* hv = (const float4*)aux2 + lane * 2;
                float sv = dot4(er[0], hv[0]) + dot4(er[1], hv[1]);
                sv = wave_sum(sv);
                if (lane == 0) dsc[b_ * 400 + j] = mask[b_ * 400 + j] ? -1e9f : sv;
            }
            for (int di = w; di < 32; di += 2) {
                int d = s * 32 + di;
                const float4* wr = (const float4*)(wo_d + (long)d * 1024 + 512) + lane * 2;
                const float4* hv = (const float4*)aux2 + lane * 2;
                float sv = dot4(wr[0], hv[0]) + dot4(wr[1], hv[1]);
                sv = wave_sum(sv);
                if (lane == 0) whoh[b_ * 512 + d] = sv;
            }
        }
        sbar<16, 4>(gbar, s);   // B->C is batch-group-local

        // ---- C: softmax (redundant per block) + out via E0o ----
        {
            float v0 = dsc[b_ * 400 + tid];
            float v1 = dsc[b_ * 400 + tid + 128];
            float v2 = dsc[b_ * 400 + tid + 256];
            bool h3 = (tid + 384) < 400;
            float v3 = h3 ? dsc[b_ * 400 + tid + 384] : -1e30f;
            float mx = wave_max(fmaxf(fmaxf(v0, v1), fmaxf(v2, v3)));
            if (lane == 0) aux2[960 + w] = mx;
            __syncthreads();
            float M = fmaxf(aux2[960], aux2[961]);
            float e0 = expf(v0 - M), e1 = expf(v1 - M), e2 = expf(v2 - M);
            float e3 = h3 ? expf(v3 - M) : 0.f;
            float sv = wave_sum(e0 + e1 + e2 + e3);
            if (lane == 0) aux2[962 + w] = sv;
            __syncthreads();
            float inv = 1.f / (aux2[962] + aux2[963]);
            aux2[tid] = e0 * inv;
            aux2[tid + 128] = e1 * inv;
            aux2[tid + 256] = e2 * inv;
            if (h3) aux2[tid + 384] = e3 * inv;
            __syncthreads();
            int dd = tid & 31, part = tid >> 5;
            const float* eo = E0o + ((long)b_ * 400 + part * 100) * 512 + s * 32 + dd;
            float acc2 = 0.f;
            for (int j = 0; j < 100; ++j) { acc2 += aux2[part * 100 + j] * (*eo); eo += 512; }
            aux2[512 + part * 32 + dd] = acc2;
            __syncthreads();
            if (tid < 32) {
                int d = s * 32 + tid;
                float o = aux2[512 + tid] + aux2[544 + tid] + aux2[576 + tid] + aux2[608 + tid]
                        + whoh[b_ * 512 + d];
                float val = tanhf(o);
                dx[b_ * 512 + d] = val;
                dsent[((b_ << 4) + t) * 512 + d] = val;
                if (t == 15) out_last[b_ * 512 + d] = val;
            }
        }
        sbar<128, 8>(bar, blk);
    }
}

// ---------------------------------------------------------------------------
// Word-level loop: 256 blocks x 512 threads, K-split 8, GROUP-local barriers:
// block (b2t,u0) only depends on the 32 blocks sharing b2t.
// bar layout: [2048 + (blk>>5)*192] word group (32,4).
// ---------------------------------------------------------------------------
__global__ __launch_bounds__(512) void word_mega(
    const float* __restrict__ sentS,
    u16* __restrict__ hAllH, u16* __restrict__ hAllL,
    const u16* __restrict__ WhhH, const u16* __restrict__ WhhL,
    const float* __restrict__ xW, float* __restrict__ wc,
    u16* __restrict__ catB, int* bar)
{
    __shared__ float red[8][4][256];   // 32 KB
    const int tid = threadIdx.x, blk = blockIdx.x;
    const int b2t = blk >> 5;
    const int u0 = (blk & 31) << 4;
    int* gbar = bar + 2048 + b2t * 192;

    // init: each block writes exactly its own (16 b2 x 16 u) tile
    if (tid < 256) {
        int b2 = b2t * 16 + (tid >> 4), u = u0 + (tid & 15);
        long cidx = (long)b2 * 512 + u;
        float v = sentS[cidx];
        u16 hh = f2bf(v);
        hAllH[cidx] = hh;
        hAllL[cidx] = f2bf(v - bf2f(hh));
        wc[cidx] = v;
    }
    sbar<32, 4>(gbar, blk & 31);

    const int w = tid >> 6, lane = tid & 63;          // w = K-split index
    const int lane15 = lane & 15, q8 = (lane >> 4) << 3;
    const long arow = (long)(b2t * 16 + lane15) * 512 + w * 64 + q8;
    long brow[4];
#pragma unroll
    for (int g = 0; g < 4; ++g)
        brow[g] = (long)(g * 512 + u0 + lane15) * 512 + w * 64 + q8;

    for (int t = 0; t < 40; ++t) {
        const u16* hH = hAllH + (long)t * 65536;
        const u16* hL = hAllL + (long)t * 65536;
        f32x4 acc[4] = {};
#pragma unroll
        for (int k0 = 0; k0 < 64; k0 += 32) {
            bf16x8 aH = *(const bf16x8*)&hH[arow + k0];
            bf16x8 aL = *(const bf16x8*)&hL[arow + k0];
#pragma unroll
            for (int g = 0; g < 4; ++g) {
                bf16x8 bH = *(const bf16x8*)&WhhH[brow[g] + k0];
                bf16x8 bL = *(const bf16x8*)&WhhL[brow[g] + k0];
                acc[g] = __builtin_amdgcn_mfma_f32_16x16x32_bf16(aH, bH, acc[g], 0, 0, 0);
                acc[g] = __builtin_amdgcn_mfma_f32_16x16x32_bf16(aH, bL, acc[g], 0, 0, 0);
                acc[g] = __builtin_amdgcn_mfma_f32_16x16x32_bf16(aL, bH, acc[g], 0, 0, 0);
            }
        }
#pragma unroll
        for (int g = 0; g < 4; ++g)
#pragma unroll
            for (int i = 0; i < 4; ++i)
                red[w][g][((lane >> 4) * 4 + i) * 16 + lane15] = acc[g][i];
        __syncthreads();

        if (tid < 256) {
            const int rc = tid;
            float g4[4] = {0.f, 0.f, 0.f, 0.f};
#pragma unroll
            for (int ks = 0; ks < 8; ++ks)
#pragma unroll
                for (int g = 0; g < 4; ++g)
                    g4[g] += red[ks][g][rc];
            int b2 = b2t * 16 + (rc >> 4);
            int u = u0 + (rc & 15);
            const float* xr = xW + (long)t * 262144 + (long)b2 * 2048;
            float gi = g4[0] + xr[u];
            float gf = g4[1] + xr[512 + u];
            float gg = g4[2] + xr[1024 + u];
            float go = g4[3] + xr[1536 + u];
            long cidx = (long)b2 * 512 + u;
            float cc = wc[cidx];
            cc = sigm(gf) * cc + sigm(gi) * tanhf(gg);
            wc[cidx] = cc;
            float hv = sigm(go) * tanhf(cc);
            u16 hh = f2bf(hv);
            hAllH[(long)(t + 1) * 65536 + cidx] = hh;
            hAllL[(long)(t + 1) * 65536 + cidx] = f2bf(hv - bf2f(hh));
            catB[((long)b2 * 40 + t) * 1024 + 512 + u] = hh;
        }
        sbar<32, 4>(gbar, blk & 31);
    }
}

// ---------------------------------------------------------------------------
// All prep work in one region-dispatched kernel (also zeroes out_attn & bars).
// ---------------------------------------------------------------------------
__device__ __forceinline__ void split1(const float* __restrict__ src,
                                       u16* __restrict__ H, u16* __restrict__ L, long i)
{
    float4 v = ((const float4*)src)[i];
    u16 h0 = f2bf(v.x), h1 = f2bf(v.y), h2 = f2bf(v.z), h3 = f2bf(v.w);
    ((us4*)H)[i] = {h0, h1, h2, h3};
    ((us4*)L)[i] = {f2bf(v.x - bf2f(h0)), f2bf(v.y - bf2f(h1)),
                    f2bf(v.z - bf2f(h2)), f2bf(v.w - bf2f(h3))};
}
__device__ __forceinline__ void wqT1(const float* __restrict__ wq,
                                     u16* __restrict__ H, u16* __restrict__ L, int idx)
{
    int e = idx >> 9, d = idx & 511;
    float v = wq[(long)d * 512 + e];
    u16 h = f2bf(v);
    H[idx] = h;
    L[idx] = f2bf(v - bf2f(h));
}

__global__ __launch_bounds__(256) void prep_all(
    const float* __restrict__ wih_w, const float* __restrict__ whh_w,
    const float* __restrict__ enc1, const float* __restrict__ enc0,
    const float* __restrict__ wq_w, const float* __restrict__ wq_d,
    const float* __restrict__ wo_w, const float* __restrict__ fcw,
    const int* __restrict__ toks, const float* __restrict__ emb,
    const float* __restrict__ spe,
    const float* __restrict__ bih_w, const float* __restrict__ bhh_w,
    const float* __restrict__ bih_d, const float* __restrict__ bhh_d,
    const float* __restrict__ wih_d, const float* __restrict__ whh_d,
    const float* __restrict__ wo_d,
    u16* __restrict__ WihH, u16* __restrict__ WihL,
    u16* __restrict__ WhhH, u16* __restrict__ WhhL,
    u16* __restrict__ enc1H, u16* __restrict__ enc1L,
    u16* __restrict__ enc0H, u16* __restrict__ enc0L,
    u16* __restrict__ wqTH, u16* __restrict__ wqTL,
    u16* __restrict__ wqdTH, u16* __restrict__ wqdTL,
    u16* __restrict__ woB, u16* __restrict__ fcwB, u16* __restrict__ enc1T,
    u16* __restrict__ xinH, u16* __restrict__ xinL,
    u16* __restrict__ woCH, u16* __restrict__ woCL,
    u16* __restrict__ WpH, u16* __restrict__ WpL,
    float* __restrict__ biasc, float* __restrict__ biasd,
    float* __restrict__ out_attn, int* __restrict__ bar)
{
    int b = blockIdx.x;
    const int tid = threadIdx.x;

    if (b < 1024) { split1(wih_w, WihH, WihL, (long)b * 256 + tid); return; }
    b -= 1024;
    if (b < 1024) { split1(whh_w, WhhH, WhhL, (long)b * 256 + tid); return; }
    b -= 1024;
    if (b < 1600) { split1(enc1, enc1H, enc1L, (long)b * 256 + tid); return; }
    b -= 1600;
    if (b < 1600) { split1(enc0, enc0H, enc0L, (long)b * 256 + tid); return; }
    b -= 1600;
    if (b < 1024) { wqT1(wq_w, wqTH, wqTL, b * 256 + tid); return; }
    b -= 1024;
    if (b < 1024) { wqT1(wq_d, wqdTH, wqdTL, b * 256 + tid); return; }
    b -= 1024;
    if (b < 512) {
        long i = (long)b * 256 + tid;
        float4 v = ((const float4*)wo_w)[i];
        ((us4*)woB)[i] = {f2bf(v.x), f2bf(v.y), f2bf(v.z), f2bf(v.w)};
        return;
    }
    b -= 512;
    if (b < 16000) {
        long i = (long)b * 256 + tid;
        float4 v = ((const float4*)fcw)[i];
        ((us4*)fcwB)[i] = {f2bf(v.x), f2bf(v.y), f2bf(v.z), f2bf(v.w)};
        return;
    }
    b -= 16000;
    if (b < 6656) {
        long idx = (long)b * 256 + tid;
        int j = (int)(idx % 416);
        long be = idx / 416;
        int e = (int)(be % 512);
        int bb = (int)(be / 512);
        float v = (j < 400) ? enc1[((long)bb * 400 + j) * 512 + e] : 0.f;
        enc1T[idx] = f2bf(v);
        return;
    }
    b -= 6656;
    if (b < 1280) {
        int g = b * 256 + tid;
        int m = g >> 6, e0 = (g & 63) << 3;
        int t = m >> 7, b2 = m & 127;
        int ne = 0;
        for (int s = 0; s < 40; ++s) ne |= (toks[b2 * 40 + s] != 1);
        int pos = ne ? (2 + (b2 & 15)) : 1;
        const float* ep = emb + (long)toks[b2 * 40 + t] * 512 + e0;
        const float* sp = spe + (long)pos * 512 + e0;
        long o = (long)m * 512 + e0;
#pragma unroll
        for (int j = 0; j < 8; ++j) {
            float v = ep[j] + sp[j];
            u16 h = f2bf(v);
            xinH[o + j] = h;
            xinL[o + j] = f2bf(v - bf2f(h));
        }
        return;
    }
    b -= 1280;
    if (b < 1) {
        for (int i = tid; i < 2048; i += 256) {
            biasc[i] = bih_w[i] + bhh_w[i];
            biasd[i] = bih_d[i] + bhh_d[i];
        }
        return;
    }
    b -= 1;
    if (b < 200) {
        out_attn[b * 256 + tid] = 0.f;
        return;
    }
    b -= 200;
    if (b < 1024) {
        int i = b * 256 + tid;
        int d = i >> 9, e = i & 511;
        float v = wo_d[(long)d * 1024 + e];
        u16 h = f2bf(v);
        woCH[i] = h;
        woCL[i] = f2bf(v - bf2f(h));
        return;
    }
    b -= 1024;
    if (b < 1024) {
        long gidx = (long)b * 256 + tid;
        int r = (int)(gidx >> 7);
        int k8 = ((int)gidx & 127) * 8;
        int u = r >> 2, g = r & 3;
        long orow = (long)(g * 512 + u);
#pragma unroll
        for (int j = 0; j < 8; ++j) {
            int k = k8 + j;
            float v = (k < 512) ? wih_d[orow * 512 + k] : whh_d[orow * 512 + k - 512];
            u16 h = f2bf(v);
            WpH[(long)r * 1024 + k] = h;
            WpL[(long)r * 1024 + k] = f2bf(v - bf2f(h));
        }
        return;
    }
    b -= 1024;
    // zero the full barrier area: 16 blocks x 256 = 4096 ints
    bar[b * 256 + tid] = 0;
}

__global__ __launch_bounds__(256) void word_softmax(
    const float* __restrict__ sc, const unsigned char* __restrict__ mask,
    float* __restrict__ pout, u16* __restrict__ pbf)
{
    const int r = blockIdx.x, tid = threadIdx.x;
    const int b = r / 640;
    const int wv = tid >> 6, lane = tid & 63;
    __shared__ float red[4];
    const int j1 = tid + 256;
    float v0 = sc[(long)r * 512 + tid];
    if (mask[b * 400 + tid]) v0 = -1e9f;
    float v1 = -1e30f;
    if (j1 < 400) {
        v1 = sc[(long)r * 512 + j1];
        if (mask[b * 400 + j1]) v1 = -1e9f;
    }
    float mv = wave_max(fmaxf(v0, v1));
    if (lane == 0) red[wv] = mv;
    __syncthreads();
    if (tid == 0) red[0] = fmaxf(fmaxf(red[0], red[1]), fmaxf(red[2], red[3]));
    __syncthreads();
    const float M = red[0];
    float e0 = expf(v0 - M);
    float e1 = (j1 < 400) ? expf(v1 - M) : 0.f;
    __syncthreads();
    float sv = wave_sum(e0 + e1);
    if (lane == 0) red[wv] = sv;
    __syncthreads();
    if (tid == 0) red[0] = red[0] + red[1] + red[2] + red[3];
    __syncthreads();
    const float inv = 1.f / red[0];
    float p0 = e0 * inv;
    pout[(long)r * 400 + tid] = p0;
    pbf[(long)r * 416 + tid] = f2bf(p0);
    if (j1 < 400) {
        float p1 = e1 * inv;
        pout[(long)r * 400 + j1] = p1;
        pbf[(long)r * 416 + j1] = f2bf(p1);
    } else if (j1 < 416) {
        pbf[(long)r * 416 + j1] = 0;
    }
}

// ---------------------------------------------------------------------------
extern "C" void kernel_launch(void* const* d_in, const int* in_sizes, int n_in,
                              void* d_out, int out_size, void* d_ws, size_t ws_size,
                              hipStream_t stream)
{
    (void)in_sizes; (void)n_in; (void)out_size; (void)ws_size;

    const int*   toks  = (const int*)  d_in[0];
    const float* enc0  = (const float*)d_in[1];
    const float* enc1  = (const float*)d_in[2];
    const unsigned char* mask = (const unsigned char*)d_in[3];
    const float* emb   = (const float*)d_in[4];
    const float* spe   = (const float*)d_in[5];
    const float* wih_d = (const float*)d_in[6];
    const float* whh_d = (const float*)d_in[7];
    const float* bih_d = (const float*)d_in[8];
    const float* bhh_d = (const float*)d_in[9];
    const float* wq_d  = (const float*)d_in[10];
    const float* wo_d  = (const float*)d_in[11];
    const float* wih_w = (const float*)d_in[12];
    const float* whh_w = (const float*)d_in[13];
    const float* bih_w = (const float*)d_in[14];
    const float* bhh_w = (const float*)d_in[15];
    const float* wq_w  = (const float*)d_in[16];
    const float* wo_w  = (const float*)d_in[17];
    const float* fcw   = (const float*)d_in[18];
    const float* fcb   = (const float*)d_in[19];

    float* out_dec  = (float*)d_out;                  // [8,640,32000]
    float* out_attn = out_dec + 163840000L;           // [8,16,400] zeros
    float* out_watt = out_attn + 51200;               // [128,40,400]
    float* out_last = out_watt + 2048000;             // [8,512]

    char* wsp = (char*)d_ws;
    auto alloc = [&](size_t bytes) -> void* {
        void* p = wsp;
        wsp += (bytes + 255) & ~(size_t)255;
        return p;
    };

    float* xW    = (float*)alloc(40L * 128 * 2048 * 4);
    u16* hAllH   = (u16*)alloc(41L * 128 * 512 * 2);
    u16* hAllL   = (u16*)alloc(41L * 128 * 512 * 2);
    float* wc    = (float*)alloc(128L * 512 * 4);
    u16* xinH    = (u16*)alloc(5120L * 512 * 2);
    u16* xinL    = (u16*)alloc(5120L * 512 * 2);
    u16* WihH    = (u16*)alloc(2048L * 512 * 2);
    u16* WihL    = (u16*)alloc(2048L * 512 * 2);
    u16* WhhH    = (u16*)alloc(2048L * 512 * 2);
    u16* WhhL    = (u16*)alloc(2048L * 512 * 2);
    u16* wqTH    = (u16*)alloc(512L * 512 * 2);
    u16* wqTL    = (u16*)alloc(512L * 512 * 2);
    u16* wqdTH   = (u16*)alloc(512L * 512 * 2);
    u16* wqdTL   = (u16*)alloc(512L * 512 * 2);
    u16* enc1H   = (u16*)alloc(3200L * 512 * 2);
    u16* enc1L   = (u16*)alloc(3200L * 512 * 2);
    u16* enc0H   = (u16*)alloc(3200L * 512 * 2);
    u16* enc0L   = (u16*)alloc(3200L * 512 * 2);
    u16* sq1H    = (u16*)alloc(3328L * 512 * 2);
    u16* sq1L    = (u16*)alloc(3328L * 512 * 2);
    float* E0q   = (float*)alloc(3200L * 512 * 4);
    float* E0o   = (float*)alloc(3200L * 512 * 4);
    u16* woCH    = (u16*)alloc(512L * 512 * 2);
    u16* woCL    = (u16*)alloc(512L * 512 * 2);
    u16* WpH     = (u16*)alloc(2048L * 1024 * 2);
    u16* WpL     = (u16*)alloc(2048L * 1024 * 2);
    float* wsS   = (float*)alloc(5120L * 512 * 4);
    u16* Pbf     = (u16*)alloc(5120L * 416 * 2);
    u16* enc1T   = (u16*)alloc(8L * 512 * 416 * 2);
    u16* catB    = (u16*)alloc(5120L * 1024 * 2);
    u16* woB     = (u16*)alloc(512L * 1024 * 2);
    u16* Alog    = (u16*)alloc(5120L * 512 * 2);
    u16* fcwB    = (u16*)alloc(32000L * 512 * 2);
    float* biasc = (float*)alloc(2048 * 4);
    float* biasd = (float*)alloc(2048 * 4);
    float* dhA   = (float*)alloc(8L * 512 * 4);
    float* dhB   = (float*)alloc(8L * 512 * 4);
    float* dc    = (float*)alloc(8L * 512 * 4);
    float* dx    = (float*)alloc(8L * 512 * 4);
    float* dsc   = (float*)alloc(8L * 400 * 4);
    float* whoh  = (float*)alloc(8L * 512 * 4);
    float* dsent = (float*)alloc(128L * 512 * 4);
    int* bar     = (int*)alloc(4096 * 4);   // sharded barrier regions

    // ---- 1: all prep (also zeroes out_attn and all barrier lines) ----
    prep_all<<<dim3(34009), 256, 0, stream>>>(
        wih_w, whh_w, enc1, enc0, wq_w, wq_d, wo_w, fcw, toks, emb, spe,
        bih_w, bhh_w, bih_d, bhh_d, wih_d, whh_d, wo_d,
        WihH, WihL, WhhH, WhhL, enc1H, enc1L, enc0H, enc0L,
        wqTH, wqTL, wqdTH, wqdTL, woB, fcwB, enc1T, xinH, xinL,
        woCH, woCL, WpH, WpL, biasc, biasd, out_attn, bar);

    // ---- 2-5: input-side GEMMs (split-accurate) ----
    gemm_bt<true, 0, 2><<<dim3(4, 25, 1), 256, 0, stream>>>(
        enc1H, enc1L, 512, 0, wqTH, wqTL, 512, 0,
        nullptr, sq1H, sq1L, 512, 0, nullptr, 512);

    gemm_bt<true, 0, 0><<<dim3(4, 25, 1), 256, 0, stream>>>(
        enc0H, enc0L, 512, 0, wqdTH, wqdTL, 512, 0,
        E0q, nullptr, nullptr, 512, 0, nullptr, 512);

    gemm_bt<true, 0, 0><<<dim3(4, 25, 1), 256, 0, stream>>>(
        enc0H, enc0L, 512, 0, woCH, woCL, 512, 0,
        E0o, nullptr, nullptr, 512, 0, nullptr, 512);

    gemm_bt<true, 0, 1><<<dim3(16, 40, 1), 256, 0, stream>>>(
        xinH, xinL, 512, 0, WihH, WihL, 512, 0,
        xW, nullptr, nullptr, 2048, 0, biasc, 512);

    // ---- 6: document-level loop (single kernel, sharded barriers) ----
    doc_mega<<<dim3(128), 128, 0, stream>>>(
        enc0, E0q, E0o, mask, emb, WpH, WpL, biasd, wo_d,
        dx, dhA, dhB, dc, dsc, whoh, dsent, out_last, bar);

    // ---- 7: word-level LSTM recurrence (group-local barriers) ----
    word_mega<<<dim3(256), 512, 0, stream>>>(
        dsent, hAllH, hAllL, WhhH, WhhL, xW, wc, catB, bar);

    // ---- 8: batched word attention scores ----
    gemm_bt<true, 1, 0><<<dim3(4, 5, 8), 256, 0, stream>>>(
        hAllH, hAllL, 0, 0, sq1H, sq1L, 512, 204800L,
        wsS, nullptr, nullptr, 512, 327680L, nullptr, 512);

    // ---- 9: softmax -> out_watt + Pbf ----
    word_softmax<<<dim3(5120), 256, 0, stream>>>(wsS, mask, out_watt, Pbf);

    // ---- 10: ctx = P @ enc1 -> catB[:, 0:512] ----
    gemm_bt<false, 0, 4><<<dim3(4, 5, 8), 256, 0, stream>>>(
        Pbf, nullptr, 416, 266240L, enc1T, nullptr, 416, 212992L,
        nullptr, catB, nullptr, 1024, 655360L, nullptr, 416);

    // ---- 11: out = tanh(cat @ wo^T) ----
    gemm_bt<false, 0, 3><<<dim3(4, 40, 1), 256, 0, stream>>>(
        catB, nullptr, 1024, 0, woB, nullptr, 1024, 0,
        nullptr, Alog, nullptr, 512, 0, nullptr, 1024);

    // ---- 12: logits (XMAJ grid: consecutive bids share B-tile in L2) ----
    gemm_bt<false, 0, 1, 1><<<dim3(40, 250, 1), 256, 0, stream>>>(
        Alog, nullptr, 512, 0, fcwB, nullptr, 512, 0,
        out_dec, nullptr, nullptr, 32000, 0, fcb, 512);
}

// Round 7
// 1499.074 us; speedup vs baseline: 4.2145x; 1.5310x over previous
//
#include <hip/hip_runtime.h>
#include <cstdint>

typedef unsigned short u16;
typedef unsigned int u32;
typedef __attribute__((ext_vector_type(8))) short bf16x8;
typedef __attribute__((ext_vector_type(8))) unsigned short u16x8;
typedef __attribute__((ext_vector_type(4))) float f32x4;

struct us4 { u16 a, b, c, d; };

__device__ __forceinline__ u16 f2bf(float f) {
    uint32_t u = __float_as_uint(f);
    uint32_t r = (u + 0x7FFFu + ((u >> 16) & 1u)) >> 16;
    return (u16)r;
}
__device__ __forceinline__ float bf2f(u16 h) { return __uint_as_float(((uint32_t)h) << 16); }
__device__ __forceinline__ float sigm(float x) { return 1.f / (1.f + expf(-x)); }
__device__ __forceinline__ float dot4(float4 a, float4 b) {
    return a.x * b.x + a.y * b.y + a.z * b.z + a.w * b.w;
}
__device__ __forceinline__ float wave_sum(float v) {
#pragma unroll
    for (int o = 32; o; o >>= 1) v += __shfl_down(v, o);
    return v;
}
__device__ __forceinline__ float wave_max(float v) {
#pragma unroll
    for (int o = 32; o; o >>= 1) v = fmaxf(v, __shfl_down(v, o));
    return v;
}

// Coherent (device-scope, relaxed) u32 access: sc-flagged, bypasses the
// non-coherent L1/L2 path, NO cache-maintenance instructions.
__device__ __forceinline__ void ast(u32* p, u32 v) {
    __hip_atomic_store(p, v, __ATOMIC_RELAXED, __HIP_MEMORY_SCOPE_AGENT);
}
__device__ __forceinline__ u32 ald(const u32* p) {
    return __hip_atomic_load(p, __ATOMIC_RELAXED, __HIP_MEMORY_SCOPE_AGENT);
}
__device__ __forceinline__ u32 packsplit(float v) {
    u16 h = f2bf(v);
    u16 l = f2bf(v - bf2f(h));
    return (u32)h | ((u32)l << 16);
}

// ---------------------------------------------------------------------------
// Fence-free sharded barrier. All atomics RELAXED agent-scope (coherent by
// construction); data moved via ast/ald is already at the coherence point, so
// no buffer_wbl2/buffer_inv is ever needed. vmcnt(0) drains data stores
// before arrival (each wave already drains at __syncthreads).
// ---------------------------------------------------------------------------
template <int NBLK, int NSHARD>
__device__ __forceinline__ void sbar(int* base, int idx) {
    __syncthreads();
    if (threadIdx.x == 0) {
        asm volatile("s_waitcnt vmcnt(0)" ::: "memory");
        int* genp = base + (NSHARD + 1) * 32;
        int g = __hip_atomic_load(genp, __ATOMIC_RELAXED, __HIP_MEMORY_SCOPE_AGENT);
        constexpr int SSIZE = NBLK / NSHARD;
        int* sc = base + (idx % NSHARD) * 32;
        bool released = false;
        if (__hip_atomic_fetch_add(sc, 1, __ATOMIC_RELAXED, __HIP_MEMORY_SCOPE_AGENT) == SSIZE - 1) {
            __hip_atomic_store(sc, 0, __ATOMIC_RELAXED, __HIP_MEMORY_SCOPE_AGENT);
            int* rc = base + NSHARD * 32;
            if (__hip_atomic_fetch_add(rc, 1, __ATOMIC_RELAXED, __HIP_MEMORY_SCOPE_AGENT) == NSHARD - 1) {
                __hip_atomic_store(rc, 0, __ATOMIC_RELAXED, __HIP_MEMORY_SCOPE_AGENT);
                __hip_atomic_store(genp, g + 1, __ATOMIC_RELAXED, __HIP_MEMORY_SCOPE_AGENT);
                released = true;
            }
        }
        if (!released) {
            while (__hip_atomic_load(genp, __ATOMIC_RELAXED, __HIP_MEMORY_SCOPE_AGENT) == g)
                __builtin_amdgcn_s_sleep(1);
        }
    }
    __syncthreads();
    asm volatile("" ::: "memory");
}

// ---------------------------------------------------------------------------
// Generic 128x128-tile BT GEMM: C[M,N] = A[M,K] * B[N,K]^T   (unchanged)
// ---------------------------------------------------------------------------
template <bool SPLIT, int AMODE, int EPI, int XMAJ = 0>
__global__ __launch_bounds__(256) void gemm_bt(
    const u16* __restrict__ AH, const u16* __restrict__ AL, int lda, long strideA,
    const u16* __restrict__ BH, const u16* __restrict__ BL, int ldb, long strideB,
    float* __restrict__ C, u16* __restrict__ CH, u16* __restrict__ CL,
    int ldc, long strideC, const float* __restrict__ bias, int K)
{
    constexpr int TL = 40;
    constexpr int CHK = 128 * TL;
    __shared__ u16 sm[(SPLIT ? 4 : 2) * CHK];
    u16* sAH = sm;
    u16* sBH = sm + CHK;
    u16* sAL = SPLIT ? sm + 2 * CHK : sm;
    u16* sBL = SPLIT ? sm + 3 * CHK : sm;

    const int tid = threadIdx.x;
    const int lane = tid & 63, w = tid >> 6;
    const int wm = w >> 1, wn = w & 1;
    const int lane15 = lane & 15, q8 = (lane >> 4) << 3;
    const int n0 = (XMAJ ? blockIdx.y : blockIdx.x) * 128;
    const int m0 = (XMAJ ? blockIdx.x : blockIdx.y) * 128;
    const int z = blockIdx.z;

    const int r = tid >> 2, c8 = (tid & 3) * 8;

    long aoff[2], boff[2];
#pragma unroll
    for (int h2 = 0; h2 < 2; ++h2) {
        int row = r + (h2 << 6);
        if (AMODE == 0) {
            aoff[h2] = strideA * z + (long)(m0 + row) * lda + c8;
        } else {
            int m = m0 + row;
            int t = m % 40, dd = m / 40;
            aoff[h2] = ((long)(t + 1) * 128 + (z * 16 + dd)) * 512 + c8;
        }
        boff[h2] = strideB * z + (long)(n0 + row) * ldb + c8;
    }

    f32x4 acc[4][4] = {};

    for (int k0 = 0; k0 < K; k0 += 32) {
#pragma unroll
        for (int h2 = 0; h2 < 2; ++h2) {
            int row = r + (h2 << 6);
            int sidx = row * TL + c8;
            *(u16x8*)&sAH[sidx] = *(const u16x8*)&AH[aoff[h2] + k0];
            *(u16x8*)&sBH[sidx] = *(const u16x8*)&BH[boff[h2] + k0];
            if constexpr (SPLIT) {
                *(u16x8*)&sAL[sidx] = *(const u16x8*)&AL[aoff[h2] + k0];
                *(u16x8*)&sBL[sidx] = *(const u16x8*)&BL[boff[h2] + k0];
            }
        }
        __syncthreads();

        bf16x8 a[4], b[4], al[4], bl[4];
#pragma unroll
        for (int i = 0; i < 4; ++i) {
            a[i] = *(const bf16x8*)&sAH[(wm * 64 + i * 16 + lane15) * TL + q8];
            b[i] = *(const bf16x8*)&sBH[(wn * 64 + i * 16 + lane15) * TL + q8];
            if constexpr (SPLIT) {
                al[i] = *(const bf16x8*)&sAL[(wm * 64 + i * 16 + lane15) * TL + q8];
                bl[i] = *(const bf16x8*)&sBL[(wn * 64 + i * 16 + lane15) * TL + q8];
            }
        }
#pragma unroll
        for (int mt = 0; mt < 4; ++mt)
#pragma unroll
            for (int nt = 0; nt < 4; ++nt) {
                acc[mt][nt] = __builtin_amdgcn_mfma_f32_16x16x32_bf16(a[mt], b[nt], acc[mt][nt], 0, 0, 0);
                if constexpr (SPLIT) {
                    acc[mt][nt] = __builtin_amdgcn_mfma_f32_16x16x32_bf16(a[mt], bl[nt], acc[mt][nt], 0, 0, 0);
                    acc[mt][nt] = __builtin_amdgcn_mfma_f32_16x16x32_bf16(al[mt], b[nt], acc[mt][nt], 0, 0, 0);
                }
            }
        __syncthreads();
    }

#pragma unroll
    for (int mt = 0; mt < 4; ++mt)
#pragma unroll
        for (int nt = 0; nt < 4; ++nt)
#pragma unroll
            for (int i = 0; i < 4; ++i) {
                int row = m0 + wm * 64 + mt * 16 + ((lane >> 4) << 2) + i;
                int col = n0 + wn * 64 + nt * 16 + lane15;
                long off = strideC * z + (long)row * ldc + col;
                float v = acc[mt][nt][i];
                if constexpr (EPI == 0) {
                    C[off] = v;
                } else if constexpr (EPI == 1) {
                    C[off] = v + bias[col];
                } else if constexpr (EPI == 2) {
                    u16 h_ = f2bf(v);
                    CH[off] = h_;
                    CL[off] = f2bf(v - bf2f(h_));
                } else if constexpr (EPI == 3) {
                    CH[off] = f2bf(tanhf(v));
                } else {
                    CH[off] = f2bf(v);
                }
            }
}

// ---------------------------------------------------------------------------
// Doc-level loop: 128 blocks x 128 threads. Cross-block data via packed-u32
// agent atomics (hP ping-pong, dxP, dscP, dcP handoff); dc in registers;
// whoh in LDS. No fences anywhere; weights stay L2-resident.
// ---------------------------------------------------------------------------
__global__ __launch_bounds__(128) void doc_mega(
    const float* __restrict__ enc0, const float* __restrict__ E0q,
    const float* __restrict__ E0o, const unsigned char* __restrict__ mask,
    const float* __restrict__ emb,
    const u16* __restrict__ WpH, const u16* __restrict__ WpL,
    const float* __restrict__ biasd, const float* __restrict__ wo_d,
    u32* __restrict__ dxP, u32* __restrict__ hP0, u32* __restrict__ hP1,
    u32* __restrict__ dcP, u32* __restrict__ dscP,
    float* __restrict__ dsent, float* __restrict__ out_last, int* bar)
{
    __shared__ u16 xhH[16 * 1032];
    __shared__ u16 xhL[16 * 1032];
    __shared__ float tileC[16 * 17];
    __shared__ float aux2[1024];
    __shared__ float whoh_s[32];

    const int blk = blockIdx.x, tid = threadIdx.x;
    const int w = tid >> 6, lane = tid & 63;
    const int b_ = blk >> 4, s = blk & 15;
    const int lane15 = lane & 15, q8 = (lane >> 4) << 3;
    int* gbar = bar + 512 + b_ * 192;

    for (int q = tid; q < 8 * 1032; q += 128) { xhH[8 * 1032 + q] = 0; xhL[8 * 1032 + q] = 0; }

    {   // init: dh = dc = mean_j enc0[b,j,:], dx = emb[SOD]
        int dd = tid & 31, part = tid >> 5;
        const float* p0 = enc0 + ((long)b_ * 400 + part * 100) * 512 + s * 32 + dd;
        float sm = 0.f;
        for (int j = 0; j < 100; ++j) { sm += *p0; p0 += 512; }
        aux2[part * 32 + dd] = sm;
        __syncthreads();
        if (tid < 32) {
            float m = (aux2[tid] + aux2[32 + tid] + aux2[64 + tid] + aux2[96 + tid]) * (1.f / 400.f);
            int e = s * 32 + tid;
            ast(&hP0[b_ * 512 + e], packsplit(m));
            ast(&dcP[b_ * 512 + e], __float_as_uint(m));
            ast(&dxP[b_ * 512 + e], packsplit(emb[1024 + e]));
        }
    }
    sbar<128, 8>(bar, blk);

    // dc handoff into registers (block-exclusive thereafter)
    const int eb_b = tid & 7, eb_u4 = tid >> 3, eb_u = blk * 4 + eb_u4;
    float dcr = 0.f;
    if (tid < 32) dcr = __uint_as_float(ald(&dcP[eb_b * 512 + eb_u]));

    const u16* bh_base = WpH + ((long)blk * 16 + lane15) * 1024 + q8;
    const u16* bl_base = WpL + ((long)blk * 16 + lane15) * 1024 + q8;
    const u16* ah_base = xhH + lane15 * 1032 + q8;
    const u16* al_base = xhL + lane15 * 1032 + q8;

    for (int t = 0; t < 16; ++t) {
        u32* hinP = (t & 1) ? hP1 : hP0;
        u32* houtP = (t & 1) ? hP0 : hP1;

        // ---- A: stage packed x|h into LDS, MFMA gates, LSTM elementwise ----
        for (int q = tid; q < 4096; q += 128) {
            u32 px = ald(&dxP[q]);
            u32 ph = ald(&hinP[q]);
            int o = (q >> 9) * 1032 + (q & 511);
            xhH[o] = (u16)px;        xhL[o] = (u16)(px >> 16);
            xhH[o + 512] = (u16)ph;  xhL[o + 512] = (u16)(ph >> 16);
        }
        __syncthreads();

        f32x4 acc = {};
        for (int k0 = w * 512; k0 < w * 512 + 512; k0 += 32) {
            bf16x8 aH = *(const bf16x8*)&ah_base[k0];
            bf16x8 aL = *(const bf16x8*)&al_base[k0];
            bf16x8 bH = *(const bf16x8*)&bh_base[k0];
            bf16x8 bL = *(const bf16x8*)&bl_base[k0];
            acc = __builtin_amdgcn_mfma_f32_16x16x32_bf16(aH, bH, acc, 0, 0, 0);
            acc = __builtin_amdgcn_mfma_f32_16x16x32_bf16(aH, bL, acc, 0, 0, 0);
            acc = __builtin_amdgcn_mfma_f32_16x16x32_bf16(aL, bH, acc, 0, 0, 0);
        }
        if (w == 1) {
#pragma unroll
            for (int i = 0; i < 4; ++i)
                tileC[((lane >> 4) * 4 + i) * 17 + lane15] = acc[i];
        }
        __syncthreads();
        if (w == 0) {
#pragma unroll
            for (int i = 0; i < 4; ++i)
                tileC[((lane >> 4) * 4 + i) * 17 + lane15] += acc[i];
        }
        __syncthreads();
        if (tid < 32) {
            float gi = tileC[eb_b * 17 + eb_u4 * 4 + 0] + biasd[eb_u];
            float gf = tileC[eb_b * 17 + eb_u4 * 4 + 1] + biasd[512 + eb_u];
            float gg = tileC[eb_b * 17 + eb_u4 * 4 + 2] + biasd[1024 + eb_u];
            float go = tileC[eb_b * 17 + eb_u4 * 4 + 3] + biasd[1536 + eb_u];
            dcr = sigm(gf) * dcr + sigm(gi) * tanhf(gg);
            float hv = sigm(go) * tanhf(dcr);
            ast(&houtP[eb_b * 512 + eb_u], packsplit(hv));
        }
        sbar<128, 8>(bar, blk);

        // ---- B: scores (j-slice) + whoh (d-slice, LDS-local) ----
        {
            for (int e = tid; e < 512; e += 128) {
                u32 p = ald(&houtP[b_ * 512 + e]);
                aux2[e] = bf2f((u16)p) + bf2f((u16)(p >> 16));
            }
            __syncthreads();
            for (int jj = w; jj < 25; jj += 2) {
                int j = s * 25 + jj;
                const float4* er = (const float4*)(E0q + ((long)b_ * 400 + j) * 512) + lane * 2;
                const float4* hv = (const float4*)aux2 + lane * 2;
                float sv = dot4(er[0], hv[0]) + dot4(er[1], hv[1]);
                sv = wave_sum(sv);
                if (lane == 0)
                    ast(&dscP[b_ * 400 + j], __float_as_uint(mask[b_ * 400 + j] ? -1e9f : sv));
            }
            for (int di = w; di < 32; di += 2) {
                int d = s * 32 + di;
                const float4* wr = (const float4*)(wo_d + (long)d * 1024 + 512) + lane * 2;
                const float4* hv = (const float4*)aux2 + lane * 2;
                float sv = dot4(wr[0], hv[0]) + dot4(wr[1], hv[1]);
                sv = wave_sum(sv);
                if (lane == 0) whoh_s[di] = sv;
            }
        }
        sbar<16, 4>(gbar, s);   // B->C is batch-group-local

        // ---- C: softmax (redundant per block) + out via E0o ----
        {
            float v0 = __uint_as_float(ald(&dscP[b_ * 400 + tid]));
            float v1 = __uint_as_float(ald(&dscP[b_ * 400 + tid + 128]));
            float v2 = __uint_as_float(ald(&dscP[b_ * 400 + tid + 256]));
            bool h3 = (tid + 384) < 400;
            float v3 = h3 ? __uint_as_float(ald(&dscP[b_ * 400 + tid + 384])) : -1e30f;
            float mx = wave_max(fmaxf(fmaxf(v0, v1), fmaxf(v2, v3)));
            if (lane == 0) aux2[960 + w] = mx;
            __syncthreads();
            float M = fmaxf(aux2[960], aux2[961]);
            float e0 = expf(v0 - M), e1 = expf(v1 - M), e2 = expf(v2 - M);
            float e3 = h3 ? expf(v3 - M) : 0.f;
            float sv = wave_sum(e0 + e1 + e2 + e3);
            if (lane == 0) aux2[962 + w] = sv;
            __syncthreads();
            float inv = 1.f / (aux2[962] + aux2[963]);
            aux2[tid] = e0 * inv;
            aux2[tid + 128] = e1 * inv;
            aux2[tid + 256] = e2 * inv;
            if (h3) aux2[tid + 384] = e3 * inv;
            __syncthreads();
            int dd = tid & 31, part = tid >> 5;
            const float* eo = E0o + ((long)b_ * 400 + part * 100) * 512 + s * 32 + dd;
            float acc2 = 0.f;
            for (int j = 0; j < 100; ++j) { acc2 += aux2[part * 100 + j] * (*eo); eo += 512; }
            aux2[512 + part * 32 + dd] = acc2;
            __syncthreads();
            if (tid < 32) {
                int d = s * 32 + tid;
                float o = aux2[512 + tid] + aux2[544 + tid] + aux2[576 + tid] + aux2[608 + tid]
                        + whoh_s[tid];
                float val = tanhf(o);
                ast(&dxP[b_ * 512 + d], packsplit(val));
                dsent[((b_ << 4) + t) * 512 + d] = val;
                if (t == 15) out_last[b_ * 512 + d] = val;
            }
        }
        sbar<128, 8>(bar, blk);
    }
}

// ---------------------------------------------------------------------------
// Word-level loop: 256 blocks x 512 threads, K-split 8, group-local fence-free
// barriers. h exchanged as packed u32 atomics (hAllP); wc in registers;
// hAllH/L + catB written normal for downstream kernels.
// ---------------------------------------------------------------------------
__global__ __launch_bounds__(512) void word_mega(
    const float* __restrict__ sentS,
    u32* __restrict__ hAllP,
    u16* __restrict__ hAllH, u16* __restrict__ hAllL,
    const u16* __restrict__ WhhH, const u16* __restrict__ WhhL,
    const float* __restrict__ xW,
    u16* __restrict__ catB, int* bar)
{
    __shared__ float red[8][4][256];   // 32 KB
    const int tid = threadIdx.x, blk = blockIdx.x;
    const int b2t = blk >> 5;
    const int u0 = (blk & 31) << 4;
    int* gbar = bar + 2048 + b2t * 192;

    // init: each block seeds its own (16 b2 x 16 u) tile; wc lives in wcr
    float wcr = 0.f;
    long cidx = 0;
    int my_b2 = 0, my_u = 0;
    if (tid < 256) {
        my_b2 = b2t * 16 + (tid >> 4);
        my_u = u0 + (tid & 15);
        cidx = (long)my_b2 * 512 + my_u;
        wcr = sentS[cidx];
        ast(&hAllP[cidx], packsplit(wcr));
    }
    sbar<32, 4>(gbar, blk & 31);

    const int w = tid >> 6, lane = tid & 63;          // w = K-split index
    const int lane15 = lane & 15, q8 = (lane >> 4) << 3;
    const long arowE = (long)(b2t * 16 + lane15) * 512 + w * 64 + q8;
    long brow[4];
#pragma unroll
    for (int g = 0; g < 4; ++g)
        brow[g] = (long)(g * 512 + u0 + lane15) * 512 + w * 64 + q8;

    for (int t = 0; t < 40; ++t) {
        const u32* hP = hAllP + (long)t * 65536;

        // prefetch xW early (read-only, L2-warm)
        float xw0 = 0.f, xw1 = 0.f, xw2 = 0.f, xw3 = 0.f;
        if (tid < 256) {
            const float* xr = xW + (long)t * 262144 + (long)my_b2 * 2048;
            xw0 = xr[my_u]; xw1 = xr[512 + my_u]; xw2 = xr[1024 + my_u]; xw3 = xr[1536 + my_u];
        }

        f32x4 acc[4] = {};
#pragma unroll
        for (int k0 = 0; k0 < 64; k0 += 32) {
            u32 ph[8];
#pragma unroll
            for (int j = 0; j < 8; ++j) ph[j] = ald(&hP[arowE + k0 + j]);
            bf16x8 aH, aL;
#pragma unroll
            for (int j = 0; j < 8; ++j) {
                aH[j] = (short)(ph[j] & 0xffffu);
                aL[j] = (short)(ph[j] >> 16);
            }
#pragma unroll
            for (int g = 0; g < 4; ++g) {
                bf16x8 bH = *(const bf16x8*)&WhhH[brow[g] + k0];
                bf16x8 bL = *(const bf16x8*)&WhhL[brow[g] + k0];
                acc[g] = __builtin_amdgcn_mfma_f32_16x16x32_bf16(aH, bH, acc[g], 0, 0, 0);
                acc[g] = __builtin_amdgcn_mfma_f32_16x16x32_bf16(aH, bL, acc[g], 0, 0, 0);
                acc[g] = __builtin_amdgcn_mfma_f32_16x16x32_bf16(aL, bH, acc[g], 0, 0, 0);
            }
        }
#pragma unroll
        for (int g = 0; g < 4; ++g)
#pragma unroll
            for (int i = 0; i < 4; ++i)
                red[w][g][((lane >> 4) * 4 + i) * 16 + lane15] = acc[g][i];
        __syncthreads();

        if (tid < 256) {
            float g4[4] = {0.f, 0.f, 0.f, 0.f};
#pragma unroll
            for (int ks = 0; ks < 8; ++ks)
#pragma unroll
                for (int g = 0; g < 4; ++g)
                    g4[g] += red[ks][g][tid];
            float gi = g4[0] + xw0;
            float gf = g4[1] + xw1;
            float gg = g4[2] + xw2;
            float go = g4[3] + xw3;
            wcr = sigm(gf) * wcr + sigm(gi) * tanhf(gg);
            float hv = sigm(go) * tanhf(wcr);
            u16 hh = f2bf(hv);
            u16 ll = f2bf(hv - bf2f(hh));
            long o = (long)(t + 1) * 65536 + cidx;
            ast(&hAllP[o], (u32)hh | ((u32)ll << 16));
            hAllH[o] = hh;                      // for downstream GEMMs (normal)
            hAllL[o] = ll;
            catB[((long)my_b2 * 40 + t) * 1024 + 512 + my_u] = hh;
        }
        sbar<32, 4>(gbar, blk & 31);
    }
}

// ---------------------------------------------------------------------------
// All prep work in one region-dispatched kernel (also zeroes out_attn & bars).
// ---------------------------------------------------------------------------
__device__ __forceinline__ void split1(const float* __restrict__ src,
                                       u16* __restrict__ H, u16* __restrict__ L, long i)
{
    float4 v = ((const float4*)src)[i];
    u16 h0 = f2bf(v.x), h1 = f2bf(v.y), h2 = f2bf(v.z), h3 = f2bf(v.w);
    ((us4*)H)[i] = {h0, h1, h2, h3};
    ((us4*)L)[i] = {f2bf(v.x - bf2f(h0)), f2bf(v.y - bf2f(h1)),
                    f2bf(v.z - bf2f(h2)), f2bf(v.w - bf2f(h3))};
}
__device__ __forceinline__ void wqT1(const float* __restrict__ wq,
                                     u16* __restrict__ H, u16* __restrict__ L, int idx)
{
    int e = idx >> 9, d = idx & 511;
    float v = wq[(long)d * 512 + e];
    u16 h = f2bf(v);
    H[idx] = h;
    L[idx] = f2bf(v - bf2f(h));
}

__global__ __launch_bounds__(256) void prep_all(
    const float* __restrict__ wih_w, const float* __restrict__ whh_w,
    const float* __restrict__ enc1, const float* __restrict__ enc0,
    const float* __restrict__ wq_w, const float* __restrict__ wq_d,
    const float* __restrict__ wo_w, const float* __restrict__ fcw,
    const int* __restrict__ toks, const float* __restrict__ emb,
    const float* __restrict__ spe,
    const float* __restrict__ bih_w, const float* __restrict__ bhh_w,
    const float* __restrict__ bih_d, const float* __restrict__ bhh_d,
    const float* __restrict__ wih_d, const float* __restrict__ whh_d,
    const float* __restrict__ wo_d,
    u16* __restrict__ WihH, u16* __restrict__ WihL,
    u16* __restrict__ WhhH, u16* __restrict__ WhhL,
    u16* __restrict__ enc1H, u16* __restrict__ enc1L,
    u16* __restrict__ enc0H, u16* __restrict__ enc0L,
    u16* __restrict__ wqTH, u16* __restrict__ wqTL,
    u16* __restrict__ wqdTH, u16* __restrict__ wqdTL,
    u16* __restrict__ woB, u16* __restrict__ fcwB, u16* __restrict__ enc1T,
    u16* __restrict__ xinH, u16* __restrict__ xinL,
    u16* __restrict__ woCH, u16* __restrict__ woCL,
    u16* __restrict__ WpH, u16* __restrict__ WpL,
    float* __restrict__ biasc, float* __restrict__ biasd,
    float* __restrict__ out_attn, int* __restrict__ bar)
{
    int b = blockIdx.x;
    const int tid = threadIdx.x;

    if (b < 1024) { split1(wih_w, WihH, WihL, (long)b * 256 + tid); return; }
    b -= 1024;
    if (b < 1024) { split1(whh_w, WhhH, WhhL, (long)b * 256 + tid); return; }
    b -= 1024;
    if (b < 1600) { split1(enc1, enc1H, enc1L, (long)b * 256 + tid); return; }
    b -= 1600;
    if (b < 1600) { split1(enc0, enc0H, enc0L, (long)b * 256 + tid); return; }
    b -= 1600;
    if (b < 1024) { wqT1(wq_w, wqTH, wqTL, b * 256 + tid); return; }
    b -= 1024;
    if (b < 1024) { wqT1(wq_d, wqdTH, wqdTL, b * 256 + tid); return; }
    b -= 1024;
    if (b < 512) {
        long i = (long)b * 256 + tid;
        float4 v = ((const float4*)wo_w)[i];
        ((us4*)woB)[i] = {f2bf(v.x), f2bf(v.y), f2bf(v.z), f2bf(v.w)};
        return;
    }
    b -= 512;
    if (b < 16000) {
        long i = (long)b * 256 + tid;
        float4 v = ((const float4*)fcw)[i];
        ((us4*)fcwB)[i] = {f2bf(v.x), f2bf(v.y), f2bf(v.z), f2bf(v.w)};
        return;
    }
    b -= 16000;
    if (b < 6656) {
        long idx = (long)b * 256 + tid;
        int j = (int)(idx % 416);
        long be = idx / 416;
        int e = (int)(be % 512);
        int bb = (int)(be / 512);
        float v = (j < 400) ? enc1[((long)bb * 400 + j) * 512 + e] : 0.f;
        enc1T[idx] = f2bf(v);
        return;
    }
    b -= 6656;
    if (b < 1280) {
        int g = b * 256 + tid;
        int m = g >> 6, e0 = (g & 63) << 3;
        int t = m >> 7, b2 = m & 127;
        int ne = 0;
        for (int s = 0; s < 40; ++s) ne |= (toks[b2 * 40 + s] != 1);
        int pos = ne ? (2 + (b2 & 15)) : 1;
        const float* ep = emb + (long)toks[b2 * 40 + t] * 512 + e0;
        const float* sp = spe + (long)pos * 512 + e0;
        long o = (long)m * 512 + e0;
#pragma unroll
        for (int j = 0; j < 8; ++j) {
            float v = ep[j] + sp[j];
            u16 h = f2bf(v);
            xinH[o + j] = h;
            xinL[o + j] = f2bf(v - bf2f(h));
        }
        return;
    }
    b -= 1280;
    if (b < 1) {
        for (int i = tid; i < 2048; i += 256) {
            biasc[i] = bih_w[i] + bhh_w[i];
            biasd[i] = bih_d[i] + bhh_d[i];
        }
        return;
    }
    b -= 1;
    if (b < 200) {
        out_attn[b * 256 + tid] = 0.f;
        return;
    }
    b -= 200;
    if (b < 1024) {
        int i = b * 256 + tid;
        int d = i >> 9, e = i & 511;
        float v = wo_d[(long)d * 1024 + e];
        u16 h = f2bf(v);
        woCH[i] = h;
        woCL[i] = f2bf(v - bf2f(h));
        return;
    }
    b -= 1024;
    if (b < 1024) {
        long gidx = (long)b * 256 + tid;
        int r = (int)(gidx >> 7);
        int k8 = ((int)gidx & 127) * 8;
        int u = r >> 2, g = r & 3;
        long orow = (long)(g * 512 + u);
#pragma unroll
        for (int j = 0; j < 8; ++j) {
            int k = k8 + j;
            float v = (k < 512) ? wih_d[orow * 512 + k] : whh_d[orow * 512 + k - 512];
            u16 h = f2bf(v);
            WpH[(long)r * 1024 + k] = h;
            WpL[(long)r * 1024 + k] = f2bf(v - bf2f(h));
        }
        return;
    }
    b -= 1024;
    // zero the barrier area: 16 blocks x 256 = 4096 ints
    bar[b * 256 + tid] = 0;
}

__global__ __launch_bounds__(256) void word_softmax(
    const float* __restrict__ sc, const unsigned char* __restrict__ mask,
    float* __restrict__ pout, u16* __restrict__ pbf)
{
    const int r = blockIdx.x, tid = threadIdx.x;
    const int b = r / 640;
    const int wv = tid >> 6, lane = tid & 63;
    __shared__ float red[4];
    const int j1 = tid + 256;
    float v0 = sc[(long)r * 512 + tid];
    if (mask[b * 400 + tid]) v0 = -1e9f;
    float v1 = -1e30f;
    if (j1 < 400) {
        v1 = sc[(long)r * 512 + j1];
        if (mask[b * 400 + j1]) v1 = -1e9f;
    }
    float mv = wave_max(fmaxf(v0, v1));
    if (lane == 0) red[wv] = mv;
    __syncthreads();
    if (tid == 0) red[0] = fmaxf(fmaxf(red[0], red[1]), fmaxf(red[2], red[3]));
    __syncthreads();
    const float M = red[0];
    float e0 = expf(v0 - M);
    float e1 = (j1 < 400) ? expf(v1 - M) : 0.f;
    __syncthreads();
    float sv = wave_sum(e0 + e1);
    if (lane == 0) red[wv] = sv;
    __syncthreads();
    if (tid == 0) red[0] = red[0] + red[1] + red[2] + red[3];
    __syncthreads();
    const float inv = 1.f / red[0];
    float p0 = e0 * inv;
    pout[(long)r * 400 + tid] = p0;
    pbf[(long)r * 416 + tid] = f2bf(p0);
    if (j1 < 400) {
        float p1 = e1 * inv;
        pout[(long)r * 400 + j1] = p1;
        pbf[(long)r * 416 + j1] = f2bf(p1);
    } else if (j1 < 416) {
        pbf[(long)r * 416 + j1] = 0;
    }
}

// ---------------------------------------------------------------------------
extern "C" void kernel_launch(void* const* d_in, const int* in_sizes, int n_in,
                              void* d_out, int out_size, void* d_ws, size_t ws_size,
                              hipStream_t stream)
{
    (void)in_sizes; (void)n_in; (void)out_size; (void)ws_size;

    const int*   toks  = (const int*)  d_in[0];
    const float* enc0  = (const float*)d_in[1];
    const float* enc1  = (const float*)d_in[2];
    const unsigned char* mask = (const unsigned char*)d_in[3];
    const float* emb   = (const float*)d_in[4];
    const float* spe   = (const float*)d_in[5];
    const float* wih_d = (const float*)d_in[6];
    const float* whh_d = (const float*)d_in[7];
    const float* bih_d = (const float*)d_in[8];
    const float* bhh_d = (const float*)d_in[9];
    const float* wq_d  = (const float*)d_in[10];
    const float* wo_d  = (const float*)d_in[11];
    const float* wih_w = (const float*)d_in[12];
    const float* whh_w = (const float*)d_in[13];
    const float* bih_w = (const float*)d_in[14];
    const float* bhh_w = (const float*)d_in[15];
    const float* wq_w  = (const float*)d_in[16];
    const float* wo_w  = (const float*)d_in[17];
    const float* fcw   = (const float*)d_in[18];
    const float* fcb   = (const float*)d_in[19];

    float* out_dec  = (float*)d_out;                  // [8,640,32000]
    float* out_attn = out_dec + 163840000L;           // [8,16,400] zeros
    float* out_watt = out_attn + 51200;               // [128,40,400]
    float* out_last = out_watt + 2048000;             // [8,512]

    char* wsp = (char*)d_ws;
    auto alloc = [&](size_t bytes) -> void* {
        void* p = wsp;
        wsp += (bytes + 255) & ~(size_t)255;
        return p;
    };

    float* xW    = (float*)alloc(40L * 128 * 2048 * 4);
    u32* hAllP   = (u32*)alloc(41L * 128 * 512 * 4);
    u16* hAllH   = (u16*)alloc(41L * 128 * 512 * 2);
    u16* hAllL   = (u16*)alloc(41L * 128 * 512 * 2);
    u16* xinH    = (u16*)alloc(5120L * 512 * 2);
    u16* xinL    = (u16*)alloc(5120L * 512 * 2);
    u16* WihH    = (u16*)alloc(2048L * 512 * 2);
    u16* WihL    = (u16*)alloc(2048L * 512 * 2);
    u16* WhhH    = (u16*)alloc(2048L * 512 * 2);
    u16* WhhL    = (u16*)alloc(2048L * 512 * 2);
    u16* wqTH    = (u16*)alloc(512L * 512 * 2);
    u16* wqTL    = (u16*)alloc(512L * 512 * 2);
    u16* wqdTH   = (u16*)alloc(512L * 512 * 2);
    u16* wqdTL   = (u16*)alloc(512L * 512 * 2);
    u16* enc1H   = (u16*)alloc(3200L * 512 * 2);
    u16* enc1L   = (u16*)alloc(3200L * 512 * 2);
    u16* enc0H   = (u16*)alloc(3200L * 512 * 2);
    u16* enc0L   = (u16*)alloc(3200L * 512 * 2);
    u16* sq1H    = (u16*)alloc(3328L * 512 * 2);
    u16* sq1L    = (u16*)alloc(3328L * 512 * 2);
    float* E0q   = (float*)alloc(3200L * 512 * 4);
    float* E0o   = (float*)alloc(3200L * 512 * 4);
    u16* woCH    = (u16*)alloc(512L * 512 * 2);
    u16* woCL    = (u16*)alloc(512L * 512 * 2);
    u16* WpH     = (u16*)alloc(2048L * 1024 * 2);
    u16* WpL     = (u16*)alloc(2048L * 1024 * 2);
    float* wsS   = (float*)alloc(5120L * 512 * 4);
    u16* Pbf     = (u16*)alloc(5120L * 416 * 2);
    u16* enc1T   = (u16*)alloc(8L * 512 * 416 * 2);
    u16* catB    = (u16*)alloc(5120L * 1024 * 2);
    u16* woB     = (u16*)alloc(512L * 1024 * 2);
    u16* Alog    = (u16*)alloc(5120L * 512 * 2);
    u16* fcwB    = (u16*)alloc(32000L * 512 * 2);
    float* biasc = (float*)alloc(2048 * 4);
    float* biasd = (float*)alloc(2048 * 4);
    u32* dxP     = (u32*)alloc(4096 * 4);
    u32* hP0     = (u32*)alloc(4096 * 4);
    u32* hP1     = (u32*)alloc(4096 * 4);
    u32* dcP     = (u32*)alloc(4096 * 4);
    u32* dscP    = (u32*)alloc(3200 * 4);
    float* dsent = (float*)alloc(128L * 512 * 4);
    int* bar     = (int*)alloc(4096 * 4);   // sharded barrier regions

    // ---- 1: all prep (also zeroes out_attn and all barrier lines) ----
    prep_all<<<dim3(34009), 256, 0, stream>>>(
        wih_w, whh_w, enc1, enc0, wq_w, wq_d, wo_w, fcw, toks, emb, spe,
        bih_w, bhh_w, bih_d, bhh_d, wih_d, whh_d, wo_d,
        WihH, WihL, WhhH, WhhL, enc1H, enc1L, enc0H, enc0L,
        wqTH, wqTL, wqdTH, wqdTL, woB, fcwB, enc1T, xinH, xinL,
        woCH, woCL, WpH, WpL, biasc, biasd, out_attn, bar);

    // ---- 2-5: input-side GEMMs (split-accurate) ----
    gemm_bt<true, 0, 2><<<dim3(4, 25, 1), 256, 0, stream>>>(
        enc1H, enc1L, 512, 0, wqTH, wqTL, 512, 0,
        nullptr, sq1H, sq1L, 512, 0, nullptr, 512);

    gemm_bt<true, 0, 0><<<dim3(4, 25, 1), 256, 0, stream>>>(
        enc0H, enc0L, 512, 0, wqdTH, wqdTL, 512, 0,
        E0q, nullptr, nullptr, 512, 0, nullptr, 512);

    gemm_bt<true, 0, 0><<<dim3(4, 25, 1), 256, 0, stream>>>(
        enc0H, enc0L, 512, 0, woCH, woCL, 512, 0,
        E0o, nullptr, nullptr, 512, 0, nullptr, 512);

    gemm_bt<true, 0, 1><<<dim3(16, 40, 1), 256, 0, stream>>>(
        xinH, xinL, 512, 0, WihH, WihL, 512, 0,
        xW, nullptr, nullptr, 2048, 0, biasc, 512);

    // ---- 6: document-level loop (fence-free coherent comm) ----
    doc_mega<<<dim3(128), 128, 0, stream>>>(
        enc0, E0q, E0o, mask, emb, WpH, WpL, biasd, wo_d,
        dxP, hP0, hP1, dcP, dscP, dsent, out_last, bar);

    // ---- 7: word-level LSTM recurrence (fence-free coherent comm) ----
    word_mega<<<dim3(256), 512, 0, stream>>>(
        dsent, hAllP, hAllH, hAllL, WhhH, WhhL, xW, catB, bar);

    // ---- 8: batched word attention scores ----
    gemm_bt<true, 1, 0><<<dim3(4, 5, 8), 256, 0, stream>>>(
        hAllH, hAllL, 0, 0, sq1H, sq1L, 512, 204800L,
        wsS, nullptr, nullptr, 512, 327680L, nullptr, 512);

    // ---- 9: softmax -> out_watt + Pbf ----
    word_softmax<<<dim3(5120), 256, 0, stream>>>(wsS, mask, out_watt, Pbf);

    // ---- 10: ctx = P @ enc1 -> catB[:, 0:512] ----
    gemm_bt<false, 0, 4><<<dim3(4, 5, 8), 256, 0, stream>>>(
        Pbf, nullptr, 416, 266240L, enc1T, nullptr, 416, 212992L,
        nullptr, catB, nullptr, 1024, 655360L, nullptr, 416);

    // ---- 11: out = tanh(cat @ wo^T) ----
    gemm_bt<false, 0, 3><<<dim3(4, 40, 1), 256, 0, stream>>>(
        catB, nullptr, 1024, 0, woB, nullptr, 1024, 0,
        nullptr, Alog, nullptr, 512, 0, nullptr, 1024);

    // ---- 12: logits (XMAJ grid: consecutive bids share B-tile in L2) ----
    gemm_bt<false, 0, 1, 1><<<dim3(40, 250, 1), 256, 0, stream>>>(
        Alog, nullptr, 512, 0, fcwB, nullptr, 512, 0,
        out_dec, nullptr, nullptr, 32000, 0, fcb, 512);
}

// Round 8
// 1328.675 us; speedup vs baseline: 4.7550x; 1.1282x over previous
//
#include <hip/hip_runtime.h>
#include <cstdint>

typedef unsigned short u16;
typedef unsigned int u32;
typedef __attribute__((ext_vector_type(8))) short bf16x8;
typedef __attribute__((ext_vector_type(8))) unsigned short u16x8;
typedef __attribute__((ext_vector_type(4))) float f32x4;

struct us4 { u16 a, b, c, d; };

__device__ __forceinline__ u16 f2bf(float f) {
    uint32_t u = __float_as_uint(f);
    uint32_t r = (u + 0x7FFFu + ((u >> 16) & 1u)) >> 16;
    return (u16)r;
}
__device__ __forceinline__ float bf2f(u16 h) { return __uint_as_float(((uint32_t)h) << 16); }
__device__ __forceinline__ float sigm(float x) { return 1.f / (1.f + expf(-x)); }
__device__ __forceinline__ float dot4(float4 a, float4 b) {
    return a.x * b.x + a.y * b.y + a.z * b.z + a.w * b.w;
}
__device__ __forceinline__ float wave_sum(float v) {
#pragma unroll
    for (int o = 32; o; o >>= 1) v += __shfl_down(v, o);
    return v;
}
__device__ __forceinline__ float wave_max(float v) {
#pragma unroll
    for (int o = 32; o; o >>= 1) v = fmaxf(v, __shfl_down(v, o));
    return v;
}

// Coherent (device-scope, relaxed) u32 access: sc-flagged, bypasses the
// non-coherent L1/L2 path, NO cache-maintenance instructions.
__device__ __forceinline__ void ast(u32* p, u32 v) {
    __hip_atomic_store(p, v, __ATOMIC_RELAXED, __HIP_MEMORY_SCOPE_AGENT);
}
__device__ __forceinline__ u32 ald(const u32* p) {
    return __hip_atomic_load(p, __ATOMIC_RELAXED, __HIP_MEMORY_SCOPE_AGENT);
}
__device__ __forceinline__ u32 packsplit(float v) {
    u16 h = f2bf(v);
    u16 l = f2bf(v - bf2f(h));
    return (u32)h | ((u32)l << 16);
}

// ---------------------------------------------------------------------------
// Fence-free sharded barrier (unchanged from round 7).
// ---------------------------------------------------------------------------
template <int NBLK, int NSHARD>
__device__ __forceinline__ void sbar(int* base, int idx) {
    __syncthreads();
    if (threadIdx.x == 0) {
        asm volatile("s_waitcnt vmcnt(0)" ::: "memory");
        int* genp = base + (NSHARD + 1) * 32;
        int g = __hip_atomic_load(genp, __ATOMIC_RELAXED, __HIP_MEMORY_SCOPE_AGENT);
        constexpr int SSIZE = NBLK / NSHARD;
        int* sc = base + (idx % NSHARD) * 32;
        bool released = false;
        if (__hip_atomic_fetch_add(sc, 1, __ATOMIC_RELAXED, __HIP_MEMORY_SCOPE_AGENT) == SSIZE - 1) {
            __hip_atomic_store(sc, 0, __ATOMIC_RELAXED, __HIP_MEMORY_SCOPE_AGENT);
            int* rc = base + NSHARD * 32;
            if (__hip_atomic_fetch_add(rc, 1, __ATOMIC_RELAXED, __HIP_MEMORY_SCOPE_AGENT) == NSHARD - 1) {
                __hip_atomic_store(rc, 0, __ATOMIC_RELAXED, __HIP_MEMORY_SCOPE_AGENT);
                __hip_atomic_store(genp, g + 1, __ATOMIC_RELAXED, __HIP_MEMORY_SCOPE_AGENT);
                released = true;
            }
        }
        if (!released) {
            while (__hip_atomic_load(genp, __ATOMIC_RELAXED, __HIP_MEMORY_SCOPE_AGENT) == g)
                __builtin_amdgcn_s_sleep(1);
        }
    }
    __syncthreads();
    asm volatile("" ::: "memory");
}

// ---------------------------------------------------------------------------
// Generic 128x128-tile BT GEMM: C[M,N] = A[M,K] * B[N,K]^T   (unchanged)
// ---------------------------------------------------------------------------
template <bool SPLIT, int AMODE, int EPI, int XMAJ = 0>
__global__ __launch_bounds__(256) void gemm_bt(
    const u16* __restrict__ AH, const u16* __restrict__ AL, int lda, long strideA,
    const u16* __restrict__ BH, const u16* __restrict__ BL, int ldb, long strideB,
    float* __restrict__ C, u16* __restrict__ CH, u16* __restrict__ CL,
    int ldc, long strideC, const float* __restrict__ bias, int K)
{
    constexpr int TL = 40;
    constexpr int CHK = 128 * TL;
    __shared__ u16 sm[(SPLIT ? 4 : 2) * CHK];
    u16* sAH = sm;
    u16* sBH = sm + CHK;
    u16* sAL = SPLIT ? sm + 2 * CHK : sm;
    u16* sBL = SPLIT ? sm + 3 * CHK : sm;

    const int tid = threadIdx.x;
    const int lane = tid & 63, w = tid >> 6;
    const int wm = w >> 1, wn = w & 1;
    const int lane15 = lane & 15, q8 = (lane >> 4) << 3;
    const int n0 = (XMAJ ? blockIdx.y : blockIdx.x) * 128;
    const int m0 = (XMAJ ? blockIdx.x : blockIdx.y) * 128;
    const int z = blockIdx.z;

    const int r = tid >> 2, c8 = (tid & 3) * 8;

    long aoff[2], boff[2];
#pragma unroll
    for (int h2 = 0; h2 < 2; ++h2) {
        int row = r + (h2 << 6);
        if (AMODE == 0) {
            aoff[h2] = strideA * z + (long)(m0 + row) * lda + c8;
        } else {
            int m = m0 + row;
            int t = m % 40, dd = m / 40;
            aoff[h2] = ((long)(t + 1) * 128 + (z * 16 + dd)) * 512 + c8;
        }
        boff[h2] = strideB * z + (long)(n0 + row) * ldb + c8;
    }

    f32x4 acc[4][4] = {};

    for (int k0 = 0; k0 < K; k0 += 32) {
#pragma unroll
        for (int h2 = 0; h2 < 2; ++h2) {
            int row = r + (h2 << 6);
            int sidx = row * TL + c8;
            *(u16x8*)&sAH[sidx] = *(const u16x8*)&AH[aoff[h2] + k0];
            *(u16x8*)&sBH[sidx] = *(const u16x8*)&BH[boff[h2] + k0];
            if constexpr (SPLIT) {
                *(u16x8*)&sAL[sidx] = *(const u16x8*)&AL[aoff[h2] + k0];
                *(u16x8*)&sBL[sidx] = *(const u16x8*)&BL[boff[h2] + k0];
            }
        }
        __syncthreads();

        bf16x8 a[4], b[4], al[4], bl[4];
#pragma unroll
        for (int i = 0; i < 4; ++i) {
            a[i] = *(const bf16x8*)&sAH[(wm * 64 + i * 16 + lane15) * TL + q8];
            b[i] = *(const bf16x8*)&sBH[(wn * 64 + i * 16 + lane15) * TL + q8];
            if constexpr (SPLIT) {
                al[i] = *(const bf16x8*)&sAL[(wm * 64 + i * 16 + lane15) * TL + q8];
                bl[i] = *(const bf16x8*)&sBL[(wn * 64 + i * 16 + lane15) * TL + q8];
            }
        }
#pragma unroll
        for (int mt = 0; mt < 4; ++mt)
#pragma unroll
            for (int nt = 0; nt < 4; ++nt) {
                acc[mt][nt] = __builtin_amdgcn_mfma_f32_16x16x32_bf16(a[mt], b[nt], acc[mt][nt], 0, 0, 0);
                if constexpr (SPLIT) {
                    acc[mt][nt] = __builtin_amdgcn_mfma_f32_16x16x32_bf16(a[mt], bl[nt], acc[mt][nt], 0, 0, 0);
                    acc[mt][nt] = __builtin_amdgcn_mfma_f32_16x16x32_bf16(al[mt], b[nt], acc[mt][nt], 0, 0, 0);
                }
            }
        __syncthreads();
    }

#pragma unroll
    for (int mt = 0; mt < 4; ++mt)
#pragma unroll
        for (int nt = 0; nt < 4; ++nt)
#pragma unroll
            for (int i = 0; i < 4; ++i) {
                int row = m0 + wm * 64 + mt * 16 + ((lane >> 4) << 2) + i;
                int col = n0 + wn * 64 + nt * 16 + lane15;
                long off = strideC * z + (long)row * ldc + col;
                float v = acc[mt][nt][i];
                if constexpr (EPI == 0) {
                    C[off] = v;
                } else if constexpr (EPI == 1) {
                    C[off] = v + bias[col];
                } else if constexpr (EPI == 2) {
                    u16 h_ = f2bf(v);
                    CH[off] = h_;
                    CL[off] = f2bf(v - bf2f(h_));
                } else if constexpr (EPI == 3) {
                    CH[off] = f2bf(tanhf(v));
                } else {
                    CH[off] = f2bf(v);
                }
            }
}

// ---------------------------------------------------------------------------
// Doc-level loop: 128 blocks x 128 threads. Coherent loads batched
// (issue-16 -> use-16) so round-trips pipeline instead of serializing.
// ---------------------------------------------------------------------------
__global__ __launch_bounds__(128) void doc_mega(
    const float* __restrict__ enc0, const float* __restrict__ E0q,
    const float* __restrict__ E0o, const unsigned char* __restrict__ mask,
    const float* __restrict__ emb,
    const u16* __restrict__ WpH, const u16* __restrict__ WpL,
    const float* __restrict__ biasd, const float* __restrict__ wo_d,
    u32* __restrict__ dxP, u32* __restrict__ hP0, u32* __restrict__ hP1,
    u32* __restrict__ dcP, u32* __restrict__ dscP,
    float* __restrict__ dsent, float* __restrict__ out_last, int* bar)
{
    __shared__ u16 xhH[16 * 1032];
    __shared__ u16 xhL[16 * 1032];
    __shared__ float tileC[16 * 17];
    __shared__ float aux2[1024];
    __shared__ float whoh_s[32];

    const int blk = blockIdx.x, tid = threadIdx.x;
    const int w = tid >> 6, lane = tid & 63;
    const int b_ = blk >> 4, s = blk & 15;
    const int lane15 = lane & 15, q8 = (lane >> 4) << 3;
    int* gbar = bar + 512 + b_ * 192;

    for (int q = tid; q < 8 * 1032; q += 128) { xhH[8 * 1032 + q] = 0; xhL[8 * 1032 + q] = 0; }

    {   // init: dh = dc = mean_j enc0[b,j,:], dx = emb[SOD]
        int dd = tid & 31, part = tid >> 5;
        const float* p0 = enc0 + ((long)b_ * 400 + part * 100) * 512 + s * 32 + dd;
        float sm = 0.f;
#pragma unroll 4
        for (int j = 0; j < 100; ++j) { sm += *p0; p0 += 512; }
        aux2[part * 32 + dd] = sm;
        __syncthreads();
        if (tid < 32) {
            float m = (aux2[tid] + aux2[32 + tid] + aux2[64 + tid] + aux2[96 + tid]) * (1.f / 400.f);
            int e = s * 32 + tid;
            ast(&hP0[b_ * 512 + e], packsplit(m));
            ast(&dcP[b_ * 512 + e], __float_as_uint(m));
            ast(&dxP[b_ * 512 + e], packsplit(emb[1024 + e]));
        }
    }
    sbar<128, 8>(bar, blk);

    // dc handoff into registers (block-exclusive thereafter)
    const int eb_b = tid & 7, eb_u4 = tid >> 3, eb_u = blk * 4 + eb_u4;
    float dcr = 0.f;
    if (tid < 32) dcr = __uint_as_float(ald(&dcP[eb_b * 512 + eb_u]));

    const u16* bh_base = WpH + ((long)blk * 16 + lane15) * 1024 + q8;
    const u16* bl_base = WpL + ((long)blk * 16 + lane15) * 1024 + q8;
    const u16* ah_base = xhH + lane15 * 1032 + q8;
    const u16* al_base = xhL + lane15 * 1032 + q8;

    for (int t = 0; t < 16; ++t) {
        u32* hinP = (t & 1) ? hP1 : hP0;
        u32* houtP = (t & 1) ? hP0 : hP1;

        // ---- A: stage packed x|h into LDS (batched coherent loads) ----
#pragma unroll
        for (int base = 0; base < 4096; base += 1024) {
            u32 px[8], ph[8];
#pragma unroll
            for (int j = 0; j < 8; ++j) {
                int q = base + j * 128 + tid;
                px[j] = ald(&dxP[q]);
                ph[j] = ald(&hinP[q]);
            }
#pragma unroll
            for (int j = 0; j < 8; ++j) {
                int q = base + j * 128 + tid;
                int o = (q >> 9) * 1032 + (q & 511);
                xhH[o] = (u16)px[j];           xhL[o] = (u16)(px[j] >> 16);
                xhH[o + 512] = (u16)ph[j];     xhL[o + 512] = (u16)(ph[j] >> 16);
            }
        }
        __syncthreads();

        f32x4 acc = {};
#pragma unroll 4
        for (int k0 = w * 512; k0 < w * 512 + 512; k0 += 32) {
            bf16x8 aH = *(const bf16x8*)&ah_base[k0];
            bf16x8 aL = *(const bf16x8*)&al_base[k0];
            bf16x8 bH = *(const bf16x8*)&bh_base[k0];
            bf16x8 bL = *(const bf16x8*)&bl_base[k0];
            acc = __builtin_amdgcn_mfma_f32_16x16x32_bf16(aH, bH, acc, 0, 0, 0);
            acc = __builtin_amdgcn_mfma_f32_16x16x32_bf16(aH, bL, acc, 0, 0, 0);
            acc = __builtin_amdgcn_mfma_f32_16x16x32_bf16(aL, bH, acc, 0, 0, 0);
        }
        if (w == 1) {
#pragma unroll
            for (int i = 0; i < 4; ++i)
                tileC[((lane >> 4) * 4 + i) * 17 + lane15] = acc[i];
        }
        __syncthreads();
        if (w == 0) {
#pragma unroll
            for (int i = 0; i < 4; ++i)
                tileC[((lane >> 4) * 4 + i) * 17 + lane15] += acc[i];
        }
        __syncthreads();
        if (tid < 32) {
            float gi = tileC[eb_b * 17 + eb_u4 * 4 + 0] + biasd[eb_u];
            float gf = tileC[eb_b * 17 + eb_u4 * 4 + 1] + biasd[512 + eb_u];
            float gg = tileC[eb_b * 17 + eb_u4 * 4 + 2] + biasd[1024 + eb_u];
            float go = tileC[eb_b * 17 + eb_u4 * 4 + 3] + biasd[1536 + eb_u];
            dcr = sigm(gf) * dcr + sigm(gi) * tanhf(gg);
            float hv = sigm(go) * tanhf(dcr);
            ast(&houtP[eb_b * 512 + eb_u], packsplit(hv));
        }
        sbar<128, 8>(bar, blk);

        // ---- B: scores (j-slice) + whoh (d-slice, LDS-local) ----
        {
            u32 pp[4];
#pragma unroll
            for (int j = 0; j < 4; ++j) pp[j] = ald(&houtP[b_ * 512 + j * 128 + tid]);
#pragma unroll
            for (int j = 0; j < 4; ++j)
                aux2[j * 128 + tid] = bf2f((u16)pp[j]) + bf2f((u16)(pp[j] >> 16));
            __syncthreads();
            for (int jj = w; jj < 25; jj += 2) {
                int j = s * 25 + jj;
                const float4* er = (const float4*)(E0q + ((long)b_ * 400 + j) * 512) + lane * 2;
                const float4* hv = (const float4*)aux2 + lane * 2;
                float sv = dot4(er[0], hv[0]) + dot4(er[1], hv[1]);
                sv = wave_sum(sv);
                if (lane == 0)
                    ast(&dscP[b_ * 400 + j], __float_as_uint(mask[b_ * 400 + j] ? -1e9f : sv));
            }
            for (int di = w; di < 32; di += 2) {
                int d = s * 32 + di;
                const float4* wr = (const float4*)(wo_d + (long)d * 1024 + 512) + lane * 2;
                const float4* hv = (const float4*)aux2 + lane * 2;
                float sv = dot4(wr[0], hv[0]) + dot4(wr[1], hv[1]);
                sv = wave_sum(sv);
                if (lane == 0) whoh_s[di] = sv;
            }
        }
        sbar<16, 4>(gbar, s);   // B->C is batch-group-local

        // ---- C: softmax (redundant per block) + out via E0o ----
        {
            float v0 = __uint_as_float(ald(&dscP[b_ * 400 + tid]));
            float v1 = __uint_as_float(ald(&dscP[b_ * 400 + tid + 128]));
            float v2 = __uint_as_float(ald(&dscP[b_ * 400 + tid + 256]));
            bool h3 = (tid + 384) < 400;
            float v3 = h3 ? __uint_as_float(ald(&dscP[b_ * 400 + tid + 384])) : -1e30f;
            float mx = wave_max(fmaxf(fmaxf(v0, v1), fmaxf(v2, v3)));
            if (lane == 0) aux2[960 + w] = mx;
            __syncthreads();
            float M = fmaxf(aux2[960], aux2[961]);
            float e0 = expf(v0 - M), e1 = expf(v1 - M), e2 = expf(v2 - M);
            float e3 = h3 ? expf(v3 - M) : 0.f;
            float sv = wave_sum(e0 + e1 + e2 + e3);
            if (lane == 0) aux2[962 + w] = sv;
            __syncthreads();
            float inv = 1.f / (aux2[962] + aux2[963]);
            aux2[tid] = e0 * inv;
            aux2[tid + 128] = e1 * inv;
            aux2[tid + 256] = e2 * inv;
            if (h3) aux2[tid + 384] = e3 * inv;
            __syncthreads();
            int dd = tid & 31, part = tid >> 5;
            const float* eo = E0o + ((long)b_ * 400 + part * 100) * 512 + s * 32 + dd;
            float acc2 = 0.f;
#pragma unroll 4
            for (int j = 0; j < 100; ++j) { acc2 += aux2[part * 100 + j] * (*eo); eo += 512; }
            aux2[512 + part * 32 + dd] = acc2;
            __syncthreads();
            if (tid < 32) {
                int d = s * 32 + tid;
                float o = aux2[512 + tid] + aux2[544 + tid] + aux2[576 + tid] + aux2[608 + tid]
                        + whoh_s[tid];
                float val = tanhf(o);
                ast(&dxP[b_ * 512 + d], packsplit(val));
                dsent[((b_ << 4) + t) * 512 + d] = val;
                if (t == 15) out_last[b_ * 512 + d] = val;
            }
        }
        sbar<128, 8>(bar, blk);
    }
}

// ---------------------------------------------------------------------------
// Word-level loop: 256 blocks x 512 threads, K-split 8, group-local fence-free
// barriers. All 16 coherent h-loads of a step issued up-front.
// ---------------------------------------------------------------------------
__global__ __launch_bounds__(512) void word_mega(
    const float* __restrict__ sentS,
    u32* __restrict__ hAllP,
    u16* __restrict__ hAllH, u16* __restrict__ hAllL,
    const u16* __restrict__ WhhH, const u16* __restrict__ WhhL,
    const float* __restrict__ xW,
    u16* __restrict__ catB, int* bar)
{
    __shared__ float red[8][4][256];   // 32 KB
    const int tid = threadIdx.x, blk = blockIdx.x;
    const int b2t = blk >> 5;
    const int u0 = (blk & 31) << 4;
    int* gbar = bar + 2048 + b2t * 192;

    float wcr = 0.f;
    long cidx = 0;
    int my_b2 = 0, my_u = 0;
    if (tid < 256) {
        my_b2 = b2t * 16 + (tid >> 4);
        my_u = u0 + (tid & 15);
        cidx = (long)my_b2 * 512 + my_u;
        wcr = sentS[cidx];
        ast(&hAllP[cidx], packsplit(wcr));
    }
    sbar<32, 4>(gbar, blk & 31);

    const int w = tid >> 6, lane = tid & 63;          // w = K-split index
    const int lane15 = lane & 15, q8 = (lane >> 4) << 3;
    const long arowE = (long)(b2t * 16 + lane15) * 512 + w * 64 + q8;
    long brow[4];
#pragma unroll
    for (int g = 0; g < 4; ++g)
        brow[g] = (long)(g * 512 + u0 + lane15) * 512 + w * 64 + q8;

    for (int t = 0; t < 40; ++t) {
        const u32* hP = hAllP + (long)t * 65536;

        // issue ALL coherent h-loads for this step up-front (pipelined)
        u32 ph[16];
#pragma unroll
        for (int j = 0; j < 16; ++j)
            ph[j] = ald(&hP[arowE + (j >> 3) * 32 + (j & 7)]);

        // prefetch xW early (read-only, L2-warm)
        float xw0 = 0.f, xw1 = 0.f, xw2 = 0.f, xw3 = 0.f;
        if (tid < 256) {
            const float* xr = xW + (long)t * 262144 + (long)my_b2 * 2048;
            xw0 = xr[my_u]; xw1 = xr[512 + my_u]; xw2 = xr[1024 + my_u]; xw3 = xr[1536 + my_u];
        }

        f32x4 acc[4] = {};
#pragma unroll
        for (int half = 0; half < 2; ++half) {
            int k0 = half * 32;
            bf16x8 aH, aL;
#pragma unroll
            for (int j = 0; j < 8; ++j) {
                u32 p = ph[half * 8 + j];
                aH[j] = (short)(p & 0xffffu);
                aL[j] = (short)(p >> 16);
            }
#pragma unroll
            for (int g = 0; g < 4; ++g) {
                bf16x8 bH = *(const bf16x8*)&WhhH[brow[g] + k0];
                bf16x8 bL = *(const bf16x8*)&WhhL[brow[g] + k0];
                acc[g] = __builtin_amdgcn_mfma_f32_16x16x32_bf16(aH, bH, acc[g], 0, 0, 0);
                acc[g] = __builtin_amdgcn_mfma_f32_16x16x32_bf16(aH, bL, acc[g], 0, 0, 0);
                acc[g] = __builtin_amdgcn_mfma_f32_16x16x32_bf16(aL, bH, acc[g], 0, 0, 0);
            }
        }
#pragma unroll
        for (int g = 0; g < 4; ++g)
#pragma unroll
            for (int i = 0; i < 4; ++i)
                red[w][g][((lane >> 4) * 4 + i) * 16 + lane15] = acc[g][i];
        __syncthreads();

        if (tid < 256) {
            float g4[4] = {0.f, 0.f, 0.f, 0.f};
#pragma unroll
            for (int ks = 0; ks < 8; ++ks)
#pragma unroll
                for (int g = 0; g < 4; ++g)
                    g4[g] += red[ks][g][tid];
            float gi = g4[0] + xw0;
            float gf = g4[1] + xw1;
            float gg = g4[2] + xw2;
            float go = g4[3] + xw3;
            wcr = sigm(gf) * wcr + sigm(gi) * tanhf(gg);
            float hv = sigm(go) * tanhf(wcr);
            u16 hh = f2bf(hv);
            u16 ll = f2bf(hv - bf2f(hh));
            long o = (long)(t + 1) * 65536 + cidx;
            ast(&hAllP[o], (u32)hh | ((u32)ll << 16));
            hAllH[o] = hh;                      // for downstream GEMMs (normal)
            hAllL[o] = ll;
            catB[((long)my_b2 * 40 + t) * 1024 + 512 + my_u] = hh;
        }
        sbar<32, 4>(gbar, blk & 31);
    }
}

// ---------------------------------------------------------------------------
// All prep work in one region-dispatched kernel (also zeroes out_attn & bars).
// ---------------------------------------------------------------------------
__device__ __forceinline__ void split1(const float* __restrict__ src,
                                       u16* __restrict__ H, u16* __restrict__ L, long i)
{
    float4 v = ((const float4*)src)[i];
    u16 h0 = f2bf(v.x), h1 = f2bf(v.y), h2 = f2bf(v.z), h3 = f2bf(v.w);
    ((us4*)H)[i] = {h0, h1, h2, h3};
    ((us4*)L)[i] = {f2bf(v.x - bf2f(h0)), f2bf(v.y - bf2f(h1)),
                    f2bf(v.z - bf2f(h2)), f2bf(v.w - bf2f(h3))};
}
__device__ __forceinline__ void wqT1(const float* __restrict__ wq,
                                     u16* __restrict__ H, u16* __restrict__ L, int idx)
{
    int e = idx >> 9, d = idx & 511;
    float v = wq[(long)d * 512 + e];
    u16 h = f2bf(v);
    H[idx] = h;
    L[idx] = f2bf(v - bf2f(h));
}

__global__ __launch_bounds__(256) void prep_all(
    const float* __restrict__ wih_w, const float* __restrict__ whh_w,
    const float* __restrict__ enc1, const float* __restrict__ enc0,
    const float* __restrict__ wq_w, const float* __restrict__ wq_d,
    const float* __restrict__ wo_w, const float* __restrict__ fcw,
    const int* __restrict__ toks, const float* __restrict__ emb,
    const float* __restrict__ spe,
    const float* __restrict__ bih_w, const float* __restrict__ bhh_w,
    const float* __restrict__ bih_d, const float* __restrict__ bhh_d,
    const float* __restrict__ wih_d, const float* __restrict__ whh_d,
    const float* __restrict__ wo_d,
    u16* __restrict__ WihH, u16* __restrict__ WihL,
    u16* __restrict__ WhhH, u16* __restrict__ WhhL,
    u16* __restrict__ enc1H, u16* __restrict__ enc1L,
    u16* __restrict__ enc0H, u16* __restrict__ enc0L,
    u16* __restrict__ wqTH, u16* __restrict__ wqTL,
    u16* __restrict__ wqdTH, u16* __restrict__ wqdTL,
    u16* __restrict__ woB, u16* __restrict__ fcwB, u16* __restrict__ enc1T,
    u16* __restrict__ xinH, u16* __restrict__ xinL,
    u16* __restrict__ woCH, u16* __restrict__ woCL,
    u16* __restrict__ WpH, u16* __restrict__ WpL,
    float* __restrict__ biasc, float* __restrict__ biasd,
    float* __restrict__ out_attn, int* __restrict__ bar)
{
    int b = blockIdx.x;
    const int tid = threadIdx.x;

    if (b < 1024) { split1(wih_w, WihH, WihL, (long)b * 256 + tid); return; }
    b -= 1024;
    if (b < 1024) { split1(whh_w, WhhH, WhhL, (long)b * 256 + tid); return; }
    b -= 1024;
    if (b < 1600) { split1(enc1, enc1H, enc1L, (long)b * 256 + tid); return; }
    b -= 1600;
    if (b < 1600) { split1(enc0, enc0H, enc0L, (long)b * 256 + tid); return; }
    b -= 1600;
    if (b < 1024) { wqT1(wq_w, wqTH, wqTL, b * 256 + tid); return; }
    b -= 1024;
    if (b < 1024) { wqT1(wq_d, wqdTH, wqdTL, b * 256 + tid); return; }
    b -= 1024;
    if (b < 512) {
        long i = (long)b * 256 + tid;
        float4 v = ((const float4*)wo_w)[i];
        ((us4*)woB)[i] = {f2bf(v.x), f2bf(v.y), f2bf(v.z), f2bf(v.w)};
        return;
    }
    b -= 512;
    if (b < 16000) {
        long i = (long)b * 256 + tid;
        float4 v = ((const float4*)fcw)[i];
        ((us4*)fcwB)[i] = {f2bf(v.x), f2bf(v.y), f2bf(v.z), f2bf(v.w)};
        return;
    }
    b -= 16000;
    if (b < 6656) {
        long idx = (long)b * 256 + tid;
        int j = (int)(idx % 416);
        long be = idx / 416;
        int e = (int)(be % 512);
        int bb = (int)(be / 512);
        float v = (j < 400) ? enc1[((long)bb * 400 + j) * 512 + e] : 0.f;
        enc1T[idx] = f2bf(v);
        return;
    }
    b -= 6656;
    if (b < 1280) {
        int g = b * 256 + tid;
        int m = g >> 6, e0 = (g & 63) << 3;
        int t = m >> 7, b2 = m & 127;
        int ne = 0;
        for (int s = 0; s < 40; ++s) ne |= (toks[b2 * 40 + s] != 1);
        int pos = ne ? (2 + (b2 & 15)) : 1;
        const float* ep = emb + (long)toks[b2 * 40 + t] * 512 + e0;
        const float* sp = spe + (long)pos * 512 + e0;
        long o = (long)m * 512 + e0;
#pragma unroll
        for (int j = 0; j < 8; ++j) {
            float v = ep[j] + sp[j];
            u16 h = f2bf(v);
            xinH[o + j] = h;
            xinL[o + j] = f2bf(v - bf2f(h));
        }
        return;
    }
    b -= 1280;
    if (b < 1) {
        for (int i = tid; i < 2048; i += 256) {
            biasc[i] = bih_w[i] + bhh_w[i];
            biasd[i] = bih_d[i] + bhh_d[i];
        }
        return;
    }
    b -= 1;
    if (b < 200) {
        out_attn[b * 256 + tid] = 0.f;
        return;
    }
    b -= 200;
    if (b < 1024) {
        int i = b * 256 + tid;
        int d = i >> 9, e = i & 511;
        float v = wo_d[(long)d * 1024 + e];
        u16 h = f2bf(v);
        woCH[i] = h;
        woCL[i] = f2bf(v - bf2f(h));
        return;
    }
    b -= 1024;
    if (b < 1024) {
        long gidx = (long)b * 256 + tid;
        int r = (int)(gidx >> 7);
        int k8 = ((int)gidx & 127) * 8;
        int u = r >> 2, g = r & 3;
        long orow = (long)(g * 512 + u);
#pragma unroll
        for (int j = 0; j < 8; ++j) {
            int k = k8 + j;
            float v = (k < 512) ? wih_d[orow * 512 + k] : whh_d[orow * 512 + k - 512];
            u16 h = f2bf(v);
            WpH[(long)r * 1024 + k] = h;
            WpL[(long)r * 1024 + k] = f2bf(v - bf2f(h));
        }
        return;
    }
    b -= 1024;
    // zero the barrier area: 16 blocks x 256 = 4096 ints
    bar[b * 256 + tid] = 0;
}

__global__ __launch_bounds__(256) void word_softmax(
    const float* __restrict__ sc, const unsigned char* __restrict__ mask,
    float* __restrict__ pout, u16* __restrict__ pbf)
{
    const int r = blockIdx.x, tid = threadIdx.x;
    const int b = r / 640;
    const int wv = tid >> 6, lane = tid & 63;
    __shared__ float red[4];
    const int j1 = tid + 256;
    float v0 = sc[(long)r * 512 + tid];
    if (mask[b * 400 + tid]) v0 = -1e9f;
    float v1 = -1e30f;
    if (j1 < 400) {
        v1 = sc[(long)r * 512 + j1];
        if (mask[b * 400 + j1]) v1 = -1e9f;
    }
    float mv = wave_max(fmaxf(v0, v1));
    if (lane == 0) red[wv] = mv;
    __syncthreads();
    if (tid == 0) red[0] = fmaxf(fmaxf(red[0], red[1]), fmaxf(red[2], red[3]));
    __syncthreads();
    const float M = red[0];
    float e0 = expf(v0 - M);
    float e1 = (j1 < 400) ? expf(v1 - M) : 0.f;
    __syncthreads();
    float sv = wave_sum(e0 + e1);
    if (lane == 0) red[wv] = sv;
    __syncthreads();
    if (tid == 0) red[0] = red[0] + red[1] + red[2] + red[3];
    __syncthreads();
    const float inv = 1.f / red[0];
    float p0 = e0 * inv;
    pout[(long)r * 400 + tid] = p0;
    pbf[(long)r * 416 + tid] = f2bf(p0);
    if (j1 < 400) {
        float p1 = e1 * inv;
        pout[(long)r * 400 + j1] = p1;
        pbf[(long)r * 416 + j1] = f2bf(p1);
    } else if (j1 < 416) {
        pbf[(long)r * 416 + j1] = 0;
    }
}

// ---------------------------------------------------------------------------
extern "C" void kernel_launch(void* const* d_in, const int* in_sizes, int n_in,
                              void* d_out, int out_size, void* d_ws, size_t ws_size,
                              hipStream_t stream)
{
    (void)in_sizes; (void)n_in; (void)out_size; (void)ws_size;

    const int*   toks  = (const int*)  d_in[0];
    const float* enc0  = (const float*)d_in[1];
    const float* enc1  = (const float*)d_in[2];
    const unsigned char* mask = (const unsigned char*)d_in[3];
    const float* emb   = (const float*)d_in[4];
    const float* spe   = (const float*)d_in[5];
    const float* wih_d = (const float*)d_in[6];
    const float* whh_d = (const float*)d_in[7];
    const float* bih_d = (const float*)d_in[8];
    const float* bhh_d = (const float*)d_in[9];
    const float* wq_d  = (const float*)d_in[10];
    const float* wo_d  = (const float*)d_in[11];
    const float* wih_w = (const float*)d_in[12];
    const float* whh_w = (const float*)d_in[13];
    const float* bih_w = (const float*)d_in[14];
    const float* bhh_w = (const float*)d_in[15];
    const float* wq_w  = (const float*)d_in[16];
    const float* wo_w  = (const float*)d_in[17];
    const float* fcw   = (const float*)d_in[18];
    const float* fcb   = (const float*)d_in[19];

    float* out_dec  = (float*)d_out;                  // [8,640,32000]
    float* out_attn = out_dec + 163840000L;           // [8,16,400] zeros
    float* out_watt = out_attn + 51200;               // [128,40,400]
    float* out_last = out_watt + 2048000;             // [8,512]

    char* wsp = (char*)d_ws;
    auto alloc = [&](size_t bytes) -> void* {
        void* p = wsp;
        wsp += (bytes + 255) & ~(size_t)255;
        return p;
    };

    float* xW    = (float*)alloc(40L * 128 * 2048 * 4);
    u32* hAllP   = (u32*)alloc(41L * 128 * 512 * 4);
    u16* hAllH   = (u16*)alloc(41L * 128 * 512 * 2);
    u16* hAllL   = (u16*)alloc(41L * 128 * 512 * 2);
    u16* xinH    = (u16*)alloc(5120L * 512 * 2);
    u16* xinL    = (u16*)alloc(5120L * 512 * 2);
    u16* WihH    = (u16*)alloc(2048L * 512 * 2);
    u16* WihL    = (u16*)alloc(2048L * 512 * 2);
    u16* WhhH    = (u16*)alloc(2048L * 512 * 2);
    u16* WhhL    = (u16*)alloc(2048L * 512 * 2);
    u16* wqTH    = (u16*)alloc(512L * 512 * 2);
    u16* wqTL    = (u16*)alloc(512L * 512 * 2);
    u16* wqdTH   = (u16*)alloc(512L * 512 * 2);
    u16* wqdTL   = (u16*)alloc(512L * 512 * 2);
    u16* enc1H   = (u16*)alloc(3200L * 512 * 2);
    u16* enc1L   = (u16*)alloc(3200L * 512 * 2);
    u16* enc0H   = (u16*)alloc(3200L * 512 * 2);
    u16* enc0L   = (u16*)alloc(3200L * 512 * 2);
    u16* sq1H    = (u16*)alloc(3328L * 512 * 2);
    u16* sq1L    = (u16*)alloc(3328L * 512 * 2);
    float* E0q   = (float*)alloc(3200L * 512 * 4);
    float* E0o   = (float*)alloc(3200L * 512 * 4);
    u16* woCH    = (u16*)alloc(512L * 512 * 2);
    u16* woCL    = (u16*)alloc(512L * 512 * 2);
    u16* WpH     = (u16*)alloc(2048L * 1024 * 2);
    u16* WpL     = (u16*)alloc(2048L * 1024 * 2);
    float* wsS   = (float*)alloc(5120L * 512 * 4);
    u16* Pbf     = (u16*)alloc(5120L * 416 * 2);
    u16* enc1T   = (u16*)alloc(8L * 512 * 416 * 2);
    u16* catB    = (u16*)alloc(5120L * 1024 * 2);
    u16* woB     = (u16*)alloc(512L * 1024 * 2);
    u16* Alog    = (u16*)alloc(5120L * 512 * 2);
    u16* fcwB    = (u16*)alloc(32000L * 512 * 2);
    float* biasc = (float*)alloc(2048 * 4);
    float* biasd = (float*)alloc(2048 * 4);
    u32* dxP     = (u32*)alloc(4096 * 4);
    u32* hP0     = (u32*)alloc(4096 * 4);
    u32* hP1     = (u32*)alloc(4096 * 4);
    u32* dcP     = (u32*)alloc(4096 * 4);
    u32* dscP    = (u32*)alloc(3200 * 4);
    float* dsent = (float*)alloc(128L * 512 * 4);
    int* bar     = (int*)alloc(4096 * 4);   // sharded barrier regions

    // ---- 1: all prep (also zeroes out_attn and all barrier lines) ----
    prep_all<<<dim3(34009), 256, 0, stream>>>(
        wih_w, whh_w, enc1, enc0, wq_w, wq_d, wo_w, fcw, toks, emb, spe,
        bih_w, bhh_w, bih_d, bhh_d, wih_d, whh_d, wo_d,
        WihH, WihL, WhhH, WhhL, enc1H, enc1L, enc0H, enc0L,
        wqTH, wqTL, wqdTH, wqdTL, woB, fcwB, enc1T, xinH, xinL,
        woCH, woCL, WpH, WpL, biasc, biasd, out_attn, bar);

    // ---- 2-5: input-side GEMMs (split-accurate) ----
    gemm_bt<true, 0, 2><<<dim3(4, 25, 1), 256, 0, stream>>>(
        enc1H, enc1L, 512, 0, wqTH, wqTL, 512, 0,
        nullptr, sq1H, sq1L, 512, 0, nullptr, 512);

    gemm_bt<true, 0, 0><<<dim3(4, 25, 1), 256, 0, stream>>>(
        enc0H, enc0L, 512, 0, wqdTH, wqdTL, 512, 0,
        E0q, nullptr, nullptr, 512, 0, nullptr, 512);

    gemm_bt<true, 0, 0><<<dim3(4, 25, 1), 256, 0, stream>>>(
        enc0H, enc0L, 512, 0, woCH, woCL, 512, 0,
        E0o, nullptr, nullptr, 512, 0, nullptr, 512);

    gemm_bt<true, 0, 1><<<dim3(16, 40, 1), 256, 0, stream>>>(
        xinH, xinL, 512, 0, WihH, WihL, 512, 0,
        xW, nullptr, nullptr, 2048, 0, biasc, 512);

    // ---- 6: document-level loop (fence-free, batched coherent loads) ----
    doc_mega<<<dim3(128), 128, 0, stream>>>(
        enc0, E0q, E0o, mask, emb, WpH, WpL, biasd, wo_d,
        dxP, hP0, hP1, dcP, dscP, dsent, out_last, bar);

    // ---- 7: word-level LSTM recurrence (fence-free, batched loads) ----
    word_mega<<<dim3(256), 512, 0, stream>>>(
        dsent, hAllP, hAllH, hAllL, WhhH, WhhL, xW, catB, bar);

    // ---- 8: batched word attention scores ----
    gemm_bt<true, 1, 0><<<dim3(4, 5, 8), 256, 0, stream>>>(
        hAllH, hAllL, 0, 0, sq1H, sq1L, 512, 204800L,
        wsS, nullptr, nullptr, 512, 327680L, nullptr, 512);

    // ---- 9: softmax -> out_watt + Pbf ----
    word_softmax<<<dim3(5120), 256, 0, stream>>>(wsS, mask, out_watt, Pbf);

    // ---- 10: ctx = P @ enc1 -> catB[:, 0:512] ----
    gemm_bt<false, 0, 4><<<dim3(4, 5, 8), 256, 0, stream>>>(
        Pbf, nullptr, 416, 266240L, enc1T, nullptr, 416, 212992L,
        nullptr, catB, nullptr, 1024, 655360L, nullptr, 416);

    // ---- 11: out = tanh(cat @ wo^T) ----
    gemm_bt<false, 0, 3><<<dim3(4, 40, 1), 256, 0, stream>>>(
        catB, nullptr, 1024, 0, woB, nullptr, 1024, 0,
        nullptr, Alog, nullptr, 512, 0, nullptr, 1024);

    // ---- 12: logits (XMAJ grid: consecutive bids share B-tile in L2) ----
    gemm_bt<false, 0, 1, 1><<<dim3(40, 250, 1), 256, 0, stream>>>(
        Alog, nullptr, 512, 0, fcwB, nullptr, 512, 0,
        out_dec, nullptr, nullptr, 32000, 0, fcb, 512);
}

// Round 9
// 1111.256 us; speedup vs baseline: 5.6853x; 1.1957x over previous
//
#include <hip/hip_runtime.h>
#include <cstdint>

typedef unsigned short u16;
typedef unsigned int u32;
typedef __attribute__((ext_vector_type(8))) short bf16x8;
typedef __attribute__((ext_vector_type(8))) unsigned short u16x8;
typedef __attribute__((ext_vector_type(4))) float f32x4;

struct us4 { u16 a, b, c, d; };

__device__ __forceinline__ u16 f2bf(float f) {
    uint32_t u = __float_as_uint(f);
    uint32_t r = (u + 0x7FFFu + ((u >> 16) & 1u)) >> 16;
    return (u16)r;
}
__device__ __forceinline__ float bf2f(u16 h) { return __uint_as_float(((uint32_t)h) << 16); }
__device__ __forceinline__ float sigm(float x) { return 1.f / (1.f + expf(-x)); }
__device__ __forceinline__ float dot4(float4 a, float4 b) {
    return a.x * b.x + a.y * b.y + a.z * b.z + a.w * b.w;
}
__device__ __forceinline__ float wave_sum(float v) {
#pragma unroll
    for (int o = 32; o; o >>= 1) v += __shfl_down(v, o);
    return v;
}
__device__ __forceinline__ float wave_max(float v) {
#pragma unroll
    for (int o = 32; o; o >>= 1) v = fmaxf(v, __shfl_down(v, o));
    return v;
}

// Coherent (device-scope, relaxed) u32 access: no cache maintenance.
__device__ __forceinline__ void ast(u32* p, u32 v) {
    __hip_atomic_store(p, v, __ATOMIC_RELAXED, __HIP_MEMORY_SCOPE_AGENT);
}
__device__ __forceinline__ u32 ald(const u32* p) {
    return __hip_atomic_load(p, __ATOMIC_RELAXED, __HIP_MEMORY_SCOPE_AGENT);
}
__device__ __forceinline__ u32 packsplit(float v) {
    u16 h = f2bf(v);
    u16 l = f2bf(v - bf2f(h));
    return (u32)h | ((u32)l << 16);
}

// Fence-free sharded barrier (proven round 7/8).
template <int NBLK, int NSHARD>
__device__ __forceinline__ void sbar(int* base, int idx) {
    __syncthreads();
    if (threadIdx.x == 0) {
        asm volatile("s_waitcnt vmcnt(0)" ::: "memory");
        int* genp = base + (NSHARD + 1) * 32;
        int g = __hip_atomic_load(genp, __ATOMIC_RELAXED, __HIP_MEMORY_SCOPE_AGENT);
        constexpr int SSIZE = NBLK / NSHARD;
        int* sc = base + (idx % NSHARD) * 32;
        bool released = false;
        if (__hip_atomic_fetch_add(sc, 1, __ATOMIC_RELAXED, __HIP_MEMORY_SCOPE_AGENT) == SSIZE - 1) {
            __hip_atomic_store(sc, 0, __ATOMIC_RELAXED, __HIP_MEMORY_SCOPE_AGENT);
            int* rc = base + NSHARD * 32;
            if (__hip_atomic_fetch_add(rc, 1, __ATOMIC_RELAXED, __HIP_MEMORY_SCOPE_AGENT) == NSHARD - 1) {
                __hip_atomic_store(rc, 0, __ATOMIC_RELAXED, __HIP_MEMORY_SCOPE_AGENT);
                __hip_atomic_store(genp, g + 1, __ATOMIC_RELAXED, __HIP_MEMORY_SCOPE_AGENT);
                released = true;
            }
        }
        if (!released) {
            while (__hip_atomic_load(genp, __ATOMIC_RELAXED, __HIP_MEMORY_SCOPE_AGENT) == g)
                __builtin_amdgcn_s_sleep(1);
        }
    }
    __syncthreads();
    asm volatile("" ::: "memory");
}

// ---------------------------------------------------------------------------
// Generic 128x128-tile BT GEMM (register-staged) — kept for small GEMMs.
// ---------------------------------------------------------------------------
template <bool SPLIT, int AMODE, int EPI, int XMAJ = 0>
__global__ __launch_bounds__(256) void gemm_bt(
    const u16* __restrict__ AH, const u16* __restrict__ AL, int lda, long strideA,
    const u16* __restrict__ BH, const u16* __restrict__ BL, int ldb, long strideB,
    float* __restrict__ C, u16* __restrict__ CH, u16* __restrict__ CL,
    int ldc, long strideC, const float* __restrict__ bias, int K)
{
    constexpr int TL = 40;
    constexpr int CHK = 128 * TL;
    __shared__ u16 sm[(SPLIT ? 4 : 2) * CHK];
    u16* sAH = sm;
    u16* sBH = sm + CHK;
    u16* sAL = SPLIT ? sm + 2 * CHK : sm;
    u16* sBL = SPLIT ? sm + 3 * CHK : sm;

    const int tid = threadIdx.x;
    const int lane = tid & 63, w = tid >> 6;
    const int wm = w >> 1, wn = w & 1;
    const int lane15 = lane & 15, q8 = (lane >> 4) << 3;
    const int n0 = (XMAJ ? blockIdx.y : blockIdx.x) * 128;
    const int m0 = (XMAJ ? blockIdx.x : blockIdx.y) * 128;
    const int z = blockIdx.z;

    const int r = tid >> 2, c8 = (tid & 3) * 8;

    long aoff[2], boff[2];
#pragma unroll
    for (int h2 = 0; h2 < 2; ++h2) {
        int row = r + (h2 << 6);
        if (AMODE == 0) {
            aoff[h2] = strideA * z + (long)(m0 + row) * lda + c8;
        } else {
            int m = m0 + row;
            int t = m % 40, dd = m / 40;
            aoff[h2] = ((long)(t + 1) * 128 + (z * 16 + dd)) * 512 + c8;
        }
        boff[h2] = strideB * z + (long)(n0 + row) * ldb + c8;
    }

    f32x4 acc[4][4] = {};

    for (int k0 = 0; k0 < K; k0 += 32) {
#pragma unroll
        for (int h2 = 0; h2 < 2; ++h2) {
            int row = r + (h2 << 6);
            int sidx = row * TL + c8;
            *(u16x8*)&sAH[sidx] = *(const u16x8*)&AH[aoff[h2] + k0];
            *(u16x8*)&sBH[sidx] = *(const u16x8*)&BH[boff[h2] + k0];
            if constexpr (SPLIT) {
                *(u16x8*)&sAL[sidx] = *(const u16x8*)&AL[aoff[h2] + k0];
                *(u16x8*)&sBL[sidx] = *(const u16x8*)&BL[boff[h2] + k0];
            }
        }
        __syncthreads();

        bf16x8 a[4], b[4], al[4], bl[4];
#pragma unroll
        for (int i = 0; i < 4; ++i) {
            a[i] = *(const bf16x8*)&sAH[(wm * 64 + i * 16 + lane15) * TL + q8];
            b[i] = *(const bf16x8*)&sBH[(wn * 64 + i * 16 + lane15) * TL + q8];
            if constexpr (SPLIT) {
                al[i] = *(const bf16x8*)&sAL[(wm * 64 + i * 16 + lane15) * TL + q8];
                bl[i] = *(const bf16x8*)&sBL[(wn * 64 + i * 16 + lane15) * TL + q8];
            }
        }
#pragma unroll
        for (int mt = 0; mt < 4; ++mt)
#pragma unroll
            for (int nt = 0; nt < 4; ++nt) {
                acc[mt][nt] = __builtin_amdgcn_mfma_f32_16x16x32_bf16(a[mt], b[nt], acc[mt][nt], 0, 0, 0);
                if constexpr (SPLIT) {
                    acc[mt][nt] = __builtin_amdgcn_mfma_f32_16x16x32_bf16(a[mt], bl[nt], acc[mt][nt], 0, 0, 0);
                    acc[mt][nt] = __builtin_amdgcn_mfma_f32_16x16x32_bf16(al[mt], b[nt], acc[mt][nt], 0, 0, 0);
                }
            }
        __syncthreads();
    }

#pragma unroll
    for (int mt = 0; mt < 4; ++mt)
#pragma unroll
        for (int nt = 0; nt < 4; ++nt)
#pragma unroll
            for (int i = 0; i < 4; ++i) {
                int row = m0 + wm * 64 + mt * 16 + ((lane >> 4) << 2) + i;
                int col = n0 + wn * 64 + nt * 16 + lane15;
                long off = strideC * z + (long)row * ldc + col;
                float v = acc[mt][nt][i];
                if constexpr (EPI == 0) {
                    C[off] = v;
                } else if constexpr (EPI == 1) {
                    C[off] = v + bias[col];
                } else if constexpr (EPI == 2) {
                    u16 h_ = f2bf(v);
                    CH[off] = h_;
                    CL[off] = f2bf(v - bf2f(h_));
                } else if constexpr (EPI == 3) {
                    CH[off] = f2bf(tanhf(v));
                } else {
                    CH[off] = f2bf(v);
                }
            }
}

// ---------------------------------------------------------------------------
// Logits GEMM: m97-style global_load_lds staging (linear [128][32] LDS).
// C[M,N] = A[M,512] * B[N,512]^T + bias. Grid (M/128, N/128), m-tile fast.
// ---------------------------------------------------------------------------
#define GLOAD_LDS16(gsrc, ldst) \
    __builtin_amdgcn_global_load_lds((const __attribute__((address_space(1))) u32*)(gsrc), \
                                     (__attribute__((address_space(3))) u32*)(ldst), 16, 0, 0)

__global__ __launch_bounds__(256) void gemm_lds_bias(
    const u16* __restrict__ A, const u16* __restrict__ B,
    float* __restrict__ C, const float* __restrict__ bias, int ldc, int K)
{
    __shared__ u16 sA[128 * 32];
    __shared__ u16 sB[128 * 32];

    const int tid = threadIdx.x;
    const int lane = tid & 63, w = tid >> 6;
    const int wm = w >> 1, wn = w & 1;
    const int lane15 = lane & 15, q8 = (lane >> 4) << 3;
    const int m0 = blockIdx.x * 128;    // m fast: consecutive bids share B-tile
    const int n0 = blockIdx.y * 128;

    const int srow = lane >> 2, schunk = (lane & 3) * 8;

    f32x4 acc[4][4] = {};

    for (int k0 = 0; k0 < K; k0 += 32) {
#pragma unroll
        for (int c = 0; c < 2; ++c) {
            int base_r = (w * 2 + c) * 16;
            const u16* ga = A + (long)(m0 + base_r + srow) * 512 + k0 + schunk;
            const u16* gb = B + (long)(n0 + base_r + srow) * 512 + k0 + schunk;
            GLOAD_LDS16(ga, &sA[base_r * 32]);
            GLOAD_LDS16(gb, &sB[base_r * 32]);
        }
        __syncthreads();

        bf16x8 a[4], b[4];
#pragma unroll
        for (int i = 0; i < 4; ++i) {
            a[i] = *(const bf16x8*)&sA[(wm * 64 + i * 16 + lane15) * 32 + q8];
            b[i] = *(const bf16x8*)&sB[(wn * 64 + i * 16 + lane15) * 32 + q8];
        }
#pragma unroll
        for (int mt = 0; mt < 4; ++mt)
#pragma unroll
            for (int nt = 0; nt < 4; ++nt)
                acc[mt][nt] = __builtin_amdgcn_mfma_f32_16x16x32_bf16(a[mt], b[nt], acc[mt][nt], 0, 0, 0);
        __syncthreads();
    }

#pragma unroll
    for (int mt = 0; mt < 4; ++mt)
#pragma unroll
        for (int nt = 0; nt < 4; ++nt)
#pragma unroll
            for (int i = 0; i < 4; ++i) {
                int row = m0 + wm * 64 + mt * 16 + ((lane >> 4) << 2) + i;
                int col = n0 + wn * 64 + nt * 16 + lane15;
                C[(long)row * ldc + col] = acc[mt][nt][i] + bias[col];
            }
}

// ---------------------------------------------------------------------------
// Doc-level loop v3: 128 blocks x 256 threads (4 waves), 3 barriers/step.
// 4-way K-split MFMA; latency loops get 2-4x TLP vs v2.
// ---------------------------------------------------------------------------
__global__ __launch_bounds__(256) void doc_mega(
    const float* __restrict__ enc0, const float* __restrict__ E0q,
    const float* __restrict__ E0o, const unsigned char* __restrict__ mask,
    const float* __restrict__ emb,
    const u16* __restrict__ WpH, const u16* __restrict__ WpL,
    const float* __restrict__ biasd, const float* __restrict__ wo_d,
    u32* __restrict__ dxP, u32* __restrict__ hP0, u32* __restrict__ hP1,
    u32* __restrict__ dcP, u32* __restrict__ dscP,
    float* __restrict__ dsent, float* __restrict__ out_last, int* bar)
{
    __shared__ u16 xhH[16 * 1032];
    __shared__ u16 xhL[16 * 1032];
    __shared__ float red4[4][16 * 17];
    __shared__ float aux2[512];
    __shared__ float sc_s[512];
    __shared__ float whoh_s[32];
    __shared__ float ctxp[8][32];
    __shared__ float rtmp[8];

    const int blk = blockIdx.x, tid = threadIdx.x;
    const int w = tid >> 6, lane = tid & 63;
    const int b_ = blk >> 4, s = blk & 15;
    const int lane15 = lane & 15, q8 = (lane >> 4) << 3;
    int* gbar = bar + 512 + b_ * 192;

    for (int q = tid; q < 8 * 1032; q += 256) { xhH[8 * 1032 + q] = 0; xhL[8 * 1032 + q] = 0; }

    {   // init: dh = dc = mean_j enc0[b,j,:], dx = emb[SOD]
        int dd = tid & 31, part = tid >> 5;
        const float* p0 = enc0 + ((long)b_ * 400 + part * 50) * 512 + s * 32 + dd;
        float sm = 0.f;
#pragma unroll 10
        for (int j = 0; j < 50; ++j) { sm += *p0; p0 += 512; }
        ctxp[part][dd] = sm;
        __syncthreads();
        if (tid < 32) {
            float m = 0.f;
#pragma unroll
            for (int p = 0; p < 8; ++p) m += ctxp[p][tid];
            m *= (1.f / 400.f);
            int e = s * 32 + tid;
            ast(&hP0[b_ * 512 + e], packsplit(m));
            ast(&dcP[b_ * 512 + e], __float_as_uint(m));
            ast(&dxP[b_ * 512 + e], packsplit(emb[1024 + e]));
        }
    }
    sbar<128, 8>(bar, blk);

    // dc handoff into registers (block-exclusive thereafter)
    const int eb_b = tid & 7, eb_u4 = tid >> 3, eb_u = blk * 4 + eb_u4;
    float dcr = 0.f;
    if (tid < 32) dcr = __uint_as_float(ald(&dcP[eb_b * 512 + eb_u]));

    const u16* bh_base = WpH + ((long)blk * 16 + lane15) * 1024 + (w << 8) + q8;
    const u16* bl_base = WpL + ((long)blk * 16 + lane15) * 1024 + (w << 8) + q8;
    const u16* ah_base = xhH + lane15 * 1032 + (w << 8) + q8;
    const u16* al_base = xhL + lane15 * 1032 + (w << 8) + q8;

    for (int t = 0; t < 16; ++t) {
        u32* hinP = (t & 1) ? hP1 : hP0;
        u32* houtP = (t & 1) ? hP0 : hP1;

        // ---- A: stage packed x|h into LDS (2 batches of 16 coherent loads) ----
#pragma unroll
        for (int half = 0; half < 2; ++half) {
            u32 px[8], ph[8];
#pragma unroll
            for (int j = 0; j < 8; ++j) {
                int q = half * 2048 + j * 256 + tid;
                px[j] = ald(&dxP[q]);
                ph[j] = ald(&hinP[q]);
            }
#pragma unroll
            for (int j = 0; j < 8; ++j) {
                int q = half * 2048 + j * 256 + tid;
                int o = (q >> 9) * 1032 + (q & 511);
                xhH[o] = (u16)px[j];           xhL[o] = (u16)(px[j] >> 16);
                xhH[o + 512] = (u16)ph[j];     xhL[o + 512] = (u16)(ph[j] >> 16);
            }
        }
        __syncthreads();

        // 4-way K-split MFMA (each wave covers K range [w*256, w*256+256))
        f32x4 acc = {};
#pragma unroll
        for (int k0 = 0; k0 < 256; k0 += 32) {
            bf16x8 aH = *(const bf16x8*)&ah_base[k0];
            bf16x8 aL = *(const bf16x8*)&al_base[k0];
            bf16x8 bH = *(const bf16x8*)&bh_base[k0];
            bf16x8 bL = *(const bf16x8*)&bl_base[k0];
            acc = __builtin_amdgcn_mfma_f32_16x16x32_bf16(aH, bH, acc, 0, 0, 0);
            acc = __builtin_amdgcn_mfma_f32_16x16x32_bf16(aH, bL, acc, 0, 0, 0);
            acc = __builtin_amdgcn_mfma_f32_16x16x32_bf16(aL, bH, acc, 0, 0, 0);
        }
#pragma unroll
        for (int i = 0; i < 4; ++i)
            red4[w][((lane >> 4) * 4 + i) * 17 + lane15] = acc[i];
        __syncthreads();

        if (tid < 32) {
            float g4[4];
#pragma unroll
            for (int g = 0; g < 4; ++g)
                g4[g] = red4[0][eb_b * 17 + eb_u4 * 4 + g] + red4[1][eb_b * 17 + eb_u4 * 4 + g]
                      + red4[2][eb_b * 17 + eb_u4 * 4 + g] + red4[3][eb_b * 17 + eb_u4 * 4 + g];
            float gi = g4[0] + biasd[eb_u];
            float gf = g4[1] + biasd[512 + eb_u];
            float gg = g4[2] + biasd[1024 + eb_u];
            float go = g4[3] + biasd[1536 + eb_u];
            dcr = sigm(gf) * dcr + sigm(gi) * tanhf(gg);
            float hv = sigm(go) * tanhf(dcr);
            ast(&houtP[eb_b * 512 + eb_u], packsplit(hv));
        }
        sbar<128, 8>(bar, blk);

        // ---- B: scores (j-slice, ~6/wave) + whoh (8 rows/wave) ----
        {
            u32 p0 = ald(&houtP[b_ * 512 + tid]);
            u32 p1 = ald(&houtP[b_ * 512 + 256 + tid]);
            aux2[tid] = bf2f((u16)p0) + bf2f((u16)(p0 >> 16));
            aux2[256 + tid] = bf2f((u16)p1) + bf2f((u16)(p1 >> 16));
            __syncthreads();
            for (int jj = w; jj < 25; jj += 4) {
                int j = s * 25 + jj;
                const float4* er = (const float4*)(E0q + ((long)b_ * 400 + j) * 512) + lane * 2;
                const float4* hv = (const float4*)aux2 + lane * 2;
                float sv = dot4(er[0], hv[0]) + dot4(er[1], hv[1]);
                sv = wave_sum(sv);
                if (lane == 0)
                    ast(&dscP[b_ * 400 + j], __float_as_uint(mask[b_ * 400 + j] ? -1e9f : sv));
            }
#pragma unroll
            for (int r = 0; r < 8; ++r) {
                int d = s * 32 + w * 8 + r;
                const float4* wr = (const float4*)(wo_d + (long)d * 1024 + 512) + lane * 2;
                const float4* hv = (const float4*)aux2 + lane * 2;
                float sv = dot4(wr[0], hv[0]) + dot4(wr[1], hv[1]);
                sv = wave_sum(sv);
                if (lane == 0) whoh_s[w * 8 + r] = sv;
            }
        }
        sbar<16, 4>(gbar, s);   // B->C is batch-group-local

        // ---- C: softmax (block-local) + ctx (d-slice) + out ----
        {
            float v0 = __uint_as_float(ald(&dscP[b_ * 400 + tid]));
            bool h1 = (tid + 256) < 400;
            float v1 = h1 ? __uint_as_float(ald(&dscP[b_ * 400 + tid + 256])) : -1e30f;
            float mx = wave_max(fmaxf(v0, v1));
            if (lane == 0) rtmp[w] = mx;
            __syncthreads();
            float M = fmaxf(fmaxf(rtmp[0], rtmp[1]), fmaxf(rtmp[2], rtmp[3]));
            float e0 = expf(v0 - M);
            float e1 = h1 ? expf(v1 - M) : 0.f;
            float sv = wave_sum(e0 + e1);
            if (lane == 0) rtmp[4 + w] = sv;
            __syncthreads();
            float inv = 1.f / (rtmp[4] + rtmp[5] + rtmp[6] + rtmp[7]);
            sc_s[tid] = e0 * inv;
            if (h1) sc_s[tid + 256] = e1 * inv;
            __syncthreads();
            int dd = tid & 31, part = tid >> 5;
            const float* eo = E0o + ((long)b_ * 400 + part * 50) * 512 + s * 32 + dd;
            float acc2 = 0.f;
#pragma unroll 10
            for (int j = 0; j < 50; ++j) { acc2 += sc_s[part * 50 + j] * (*eo); eo += 512; }
            ctxp[part][dd] = acc2;
            __syncthreads();
            if (tid < 32) {
                int d = s * 32 + tid;
                float o = whoh_s[tid];
#pragma unroll
                for (int p = 0; p < 8; ++p) o += ctxp[p][tid];
                float val = tanhf(o);
                ast(&dxP[b_ * 512 + d], packsplit(val));
                dsent[((b_ << 4) + t) * 512 + d] = val;
                if (t == 15) out_last[b_ * 512 + d] = val;
            }
        }
        sbar<128, 8>(bar, blk);
    }
}

// ---------------------------------------------------------------------------
// Word-level loop (unchanged from round 8 — proven).
// ---------------------------------------------------------------------------
__global__ __launch_bounds__(512) void word_mega(
    const float* __restrict__ sentS,
    u32* __restrict__ hAllP,
    u16* __restrict__ hAllH, u16* __restrict__ hAllL,
    const u16* __restrict__ WhhH, const u16* __restrict__ WhhL,
    const float* __restrict__ xW,
    u16* __restrict__ catB, int* bar)
{
    __shared__ float red[8][4][256];   // 32 KB
    const int tid = threadIdx.x, blk = blockIdx.x;
    const int b2t = blk >> 5;
    const int u0 = (blk & 31) << 4;
    int* gbar = bar + 2048 + b2t * 192;

    float wcr = 0.f;
    long cidx = 0;
    int my_b2 = 0, my_u = 0;
    if (tid < 256) {
        my_b2 = b2t * 16 + (tid >> 4);
        my_u = u0 + (tid & 15);
        cidx = (long)my_b2 * 512 + my_u;
        wcr = sentS[cidx];
        ast(&hAllP[cidx], packsplit(wcr));
    }
    sbar<32, 4>(gbar, blk & 31);

    const int w = tid >> 6, lane = tid & 63;
    const int lane15 = lane & 15, q8 = (lane >> 4) << 3;
    const long arowE = (long)(b2t * 16 + lane15) * 512 + w * 64 + q8;
    long brow[4];
#pragma unroll
    for (int g = 0; g < 4; ++g)
        brow[g] = (long)(g * 512 + u0 + lane15) * 512 + w * 64 + q8;

    for (int t = 0; t < 40; ++t) {
        const u32* hP = hAllP + (long)t * 65536;

        u32 ph[16];
#pragma unroll
        for (int j = 0; j < 16; ++j)
            ph[j] = ald(&hP[arowE + (j >> 3) * 32 + (j & 7)]);

        float xw0 = 0.f, xw1 = 0.f, xw2 = 0.f, xw3 = 0.f;
        if (tid < 256) {
            const float* xr = xW + (long)t * 262144 + (long)my_b2 * 2048;
            xw0 = xr[my_u]; xw1 = xr[512 + my_u]; xw2 = xr[1024 + my_u]; xw3 = xr[1536 + my_u];
        }

        f32x4 acc[4] = {};
#pragma unroll
        for (int half = 0; half < 2; ++half) {
            int k0 = half * 32;
            bf16x8 aH, aL;
#pragma unroll
            for (int j = 0; j < 8; ++j) {
                u32 p = ph[half * 8 + j];
                aH[j] = (short)(p & 0xffffu);
                aL[j] = (short)(p >> 16);
            }
#pragma unroll
            for (int g = 0; g < 4; ++g) {
                bf16x8 bH = *(const bf16x8*)&WhhH[brow[g] + k0];
                bf16x8 bL = *(const bf16x8*)&WhhL[brow[g] + k0];
                acc[g] = __builtin_amdgcn_mfma_f32_16x16x32_bf16(aH, bH, acc[g], 0, 0, 0);
                acc[g] = __builtin_amdgcn_mfma_f32_16x16x32_bf16(aH, bL, acc[g], 0, 0, 0);
                acc[g] = __builtin_amdgcn_mfma_f32_16x16x32_bf16(aL, bH, acc[g], 0, 0, 0);
            }
        }
#pragma unroll
        for (int g = 0; g < 4; ++g)
#pragma unroll
            for (int i = 0; i < 4; ++i)
                red[w][g][((lane >> 4) * 4 + i) * 16 + lane15] = acc[g][i];
        __syncthreads();

        if (tid < 256) {
            float g4[4] = {0.f, 0.f, 0.f, 0.f};
#pragma unroll
            for (int ks = 0; ks < 8; ++ks)
#pragma unroll
                for (int g = 0; g < 4; ++g)
                    g4[g] += red[ks][g][tid];
            float gi = g4[0] + xw0;
            float gf = g4[1] + xw1;
            float gg = g4[2] + xw2;
            float go = g4[3] + xw3;
            wcr = sigm(gf) * wcr + sigm(gi) * tanhf(gg);
            float hv = sigm(go) * tanhf(wcr);
            u16 hh = f2bf(hv);
            u16 ll = f2bf(hv - bf2f(hh));
            long o = (long)(t + 1) * 65536 + cidx;
            ast(&hAllP[o], (u32)hh | ((u32)ll << 16));
            hAllH[o] = hh;
            hAllL[o] = ll;
            catB[((long)my_b2 * 40 + t) * 1024 + 512 + my_u] = hh;
        }
        sbar<32, 4>(gbar, blk & 31);
    }
}

// ---------------------------------------------------------------------------
// All prep work in one region-dispatched kernel (unchanged).
// ---------------------------------------------------------------------------
__device__ __forceinline__ void split1(const float* __restrict__ src,
                                       u16* __restrict__ H, u16* __restrict__ L, long i)
{
    float4 v = ((const float4*)src)[i];
    u16 h0 = f2bf(v.x), h1 = f2bf(v.y), h2 = f2bf(v.z), h3 = f2bf(v.w);
    ((us4*)H)[i] = {h0, h1, h2, h3};
    ((us4*)L)[i] = {f2bf(v.x - bf2f(h0)), f2bf(v.y - bf2f(h1)),
                    f2bf(v.z - bf2f(h2)), f2bf(v.w - bf2f(h3))};
}
__device__ __forceinline__ void wqT1(const float* __restrict__ wq,
                                     u16* __restrict__ H, u16* __restrict__ L, int idx)
{
    int e = idx >> 9, d = idx & 511;
    float v = wq[(long)d * 512 + e];
    u16 h = f2bf(v);
    H[idx] = h;
    L[idx] = f2bf(v - bf2f(h));
}

__global__ __launch_bounds__(256) void prep_all(
    const float* __restrict__ wih_w, const float* __restrict__ whh_w,
    const float* __restrict__ enc1, const float* __restrict__ enc0,
    const float* __restrict__ wq_w, const float* __restrict__ wq_d,
    const float* __restrict__ wo_w, const float* __restrict__ fcw,
    const int* __restrict__ toks, const float* __restrict__ emb,
    const float* __restrict__ spe,
    const float* __restrict__ bih_w, const float* __restrict__ bhh_w,
    const float* __restrict__ bih_d, const float* __restrict__ bhh_d,
    const float* __restrict__ wih_d, const float* __restrict__ whh_d,
    const float* __restrict__ wo_d,
    u16* __restrict__ WihH, u16* __restrict__ WihL,
    u16* __restrict__ WhhH, u16* __restrict__ WhhL,
    u16* __restrict__ enc1H, u16* __restrict__ enc1L,
    u16* __restrict__ enc0H, u16* __restrict__ enc0L,
    u16* __restrict__ wqTH, u16* __restrict__ wqTL,
    u16* __restrict__ wqdTH, u16* __restrict__ wqdTL,
    u16* __restrict__ woB, u16* __restrict__ fcwB, u16* __restrict__ enc1T,
    u16* __restrict__ xinH, u16* __restrict__ xinL,
    u16* __restrict__ woCH, u16* __restrict__ woCL,
    u16* __restrict__ WpH, u16* __restrict__ WpL,
    float* __restrict__ biasc, float* __restrict__ biasd,
    float* __restrict__ out_attn, int* __restrict__ bar)
{
    int b = blockIdx.x;
    const int tid = threadIdx.x;

    if (b < 1024) { split1(wih_w, WihH, WihL, (long)b * 256 + tid); return; }
    b -= 1024;
    if (b < 1024) { split1(whh_w, WhhH, WhhL, (long)b * 256 + tid); return; }
    b -= 1024;
    if (b < 1600) { split1(enc1, enc1H, enc1L, (long)b * 256 + tid); return; }
    b -= 1600;
    if (b < 1600) { split1(enc0, enc0H, enc0L, (long)b * 256 + tid); return; }
    b -= 1600;
    if (b < 1024) { wqT1(wq_w, wqTH, wqTL, b * 256 + tid); return; }
    b -= 1024;
    if (b < 1024) { wqT1(wq_d, wqdTH, wqdTL, b * 256 + tid); return; }
    b -= 1024;
    if (b < 512) {
        long i = (long)b * 256 + tid;
        float4 v = ((const float4*)wo_w)[i];
        ((us4*)woB)[i] = {f2bf(v.x), f2bf(v.y), f2bf(v.z), f2bf(v.w)};
        return;
    }
    b -= 512;
    if (b < 16000) {
        long i = (long)b * 256 + tid;
        float4 v = ((const float4*)fcw)[i];
        ((us4*)fcwB)[i] = {f2bf(v.x), f2bf(v.y), f2bf(v.z), f2bf(v.w)};
        return;
    }
    b -= 16000;
    if (b < 6656) {
        long idx = (long)b * 256 + tid;
        int j = (int)(idx % 416);
        long be = idx / 416;
        int e = (int)(be % 512);
        int bb = (int)(be / 512);
        float v = (j < 400) ? enc1[((long)bb * 400 + j) * 512 + e] : 0.f;
        enc1T[idx] = f2bf(v);
        return;
    }
    b -= 6656;
    if (b < 1280) {
        int g = b * 256 + tid;
        int m = g >> 6, e0 = (g & 63) << 3;
        int t = m >> 7, b2 = m & 127;
        int ne = 0;
        for (int s = 0; s < 40; ++s) ne |= (toks[b2 * 40 + s] != 1);
        int pos = ne ? (2 + (b2 & 15)) : 1;
        const float* ep = emb + (long)toks[b2 * 40 + t] * 512 + e0;
        const float* sp = spe + (long)pos * 512 + e0;
        long o = (long)m * 512 + e0;
#pragma unroll
        for (int j = 0; j < 8; ++j) {
            float v = ep[j] + sp[j];
            u16 h = f2bf(v);
            xinH[o + j] = h;
            xinL[o + j] = f2bf(v - bf2f(h));
        }
        return;
    }
    b -= 1280;
    if (b < 1) {
        for (int i = tid; i < 2048; i += 256) {
            biasc[i] = bih_w[i] + bhh_w[i];
            biasd[i] = bih_d[i] + bhh_d[i];
        }
        return;
    }
    b -= 1;
    if (b < 200) {
        out_attn[b * 256 + tid] = 0.f;
        return;
    }
    b -= 200;
    if (b < 1024) {
        int i = b * 256 + tid;
        int d = i >> 9, e = i & 511;
        float v = wo_d[(long)d * 1024 + e];
        u16 h = f2bf(v);
        woCH[i] = h;
        woCL[i] = f2bf(v - bf2f(h));
        return;
    }
    b -= 1024;
    if (b < 1024) {
        long gidx = (long)b * 256 + tid;
        int r = (int)(gidx >> 7);
        int k8 = ((int)gidx & 127) * 8;
        int u = r >> 2, g = r & 3;
        long orow = (long)(g * 512 + u);
#pragma unroll
        for (int j = 0; j < 8; ++j) {
            int k = k8 + j;
            float v = (k < 512) ? wih_d[orow * 512 + k] : whh_d[orow * 512 + k - 512];
            u16 h = f2bf(v);
            WpH[(long)r * 1024 + k] = h;
            WpL[(long)r * 1024 + k] = f2bf(v - bf2f(h));
        }
        return;
    }
    b -= 1024;
    bar[b * 256 + tid] = 0;
}

__global__ __launch_bounds__(256) void word_softmax(
    const float* __restrict__ sc, const unsigned char* __restrict__ mask,
    float* __restrict__ pout, u16* __restrict__ pbf)
{
    const int r = blockIdx.x, tid = threadIdx.x;
    const int b = r / 640;
    const int wv = tid >> 6, lane = tid & 63;
    __shared__ float red[4];
    const int j1 = tid + 256;
    float v0 = sc[(long)r * 512 + tid];
    if (mask[b * 400 + tid]) v0 = -1e9f;
    float v1 = -1e30f;
    if (j1 < 400) {
        v1 = sc[(long)r * 512 + j1];
        if (mask[b * 400 + j1]) v1 = -1e9f;
    }
    float mv = wave_max(fmaxf(v0, v1));
    if (lane == 0) red[wv] = mv;
    __syncthreads();
    if (tid == 0) red[0] = fmaxf(fmaxf(red[0], red[1]), fmaxf(red[2], red[3]));
    __syncthreads();
    const float M = red[0];
    float e0 = expf(v0 - M);
    float e1 = (j1 < 400) ? expf(v1 - M) : 0.f;
    __syncthreads();
    float sv = wave_sum(e0 + e1);
    if (lane == 0) red[wv] = sv;
    __syncthreads();
    if (tid == 0) red[0] = red[0] + red[1] + red[2] + red[3];
    __syncthreads();
    const float inv = 1.f / red[0];
    float p0 = e0 * inv;
    pout[(long)r * 400 + tid] = p0;
    pbf[(long)r * 416 + tid] = f2bf(p0);
    if (j1 < 400) {
        float p1 = e1 * inv;
        pout[(long)r * 400 + j1] = p1;
        pbf[(long)r * 416 + j1] = f2bf(p1);
    } else if (j1 < 416) {
        pbf[(long)r * 416 + j1] = 0;
    }
}

// ---------------------------------------------------------------------------
extern "C" void kernel_launch(void* const* d_in, const int* in_sizes, int n_in,
                              void* d_out, int out_size, void* d_ws, size_t ws_size,
                              hipStream_t stream)
{
    (void)in_sizes; (void)n_in; (void)out_size; (void)ws_size;

    const int*   toks  = (const int*)  d_in[0];
    const float* enc0  = (const float*)d_in[1];
    const float* enc1  = (const float*)d_in[2];
    const unsigned char* mask = (const unsigned char*)d_in[3];
    const float* emb   = (const float*)d_in[4];
    const float* spe   = (const float*)d_in[5];
    const float* wih_d = (const float*)d_in[6];
    const float* whh_d = (const float*)d_in[7];
    const float* bih_d = (const float*)d_in[8];
    const float* bhh_d = (const float*)d_in[9];
    const float* wq_d  = (const float*)d_in[10];
    const float* wo_d  = (const float*)d_in[11];
    const float* wih_w = (const float*)d_in[12];
    const float* whh_w = (const float*)d_in[13];
    const float* bih_w = (const float*)d_in[14];
    const float* bhh_w = (const float*)d_in[15];
    const float* wq_w  = (const float*)d_in[16];
    const float* wo_w  = (const float*)d_in[17];
    const float* fcw   = (const float*)d_in[18];
    const float* fcb   = (const float*)d_in[19];

    float* out_dec  = (float*)d_out;                  // [8,640,32000]
    float* out_attn = out_dec + 163840000L;           // [8,16,400] zeros
    float* out_watt = out_attn + 51200;               // [128,40,400]
    float* out_last = out_watt + 2048000;             // [8,512]

    char* wsp = (char*)d_ws;
    auto alloc = [&](size_t bytes) -> void* {
        void* p = wsp;
        wsp += (bytes + 255) & ~(size_t)255;
        return p;
    };

    float* xW    = (float*)alloc(40L * 128 * 2048 * 4);
    u32* hAllP   = (u32*)alloc(41L * 128 * 512 * 4);
    u16* hAllH   = (u16*)alloc(41L * 128 * 512 * 2);
    u16* hAllL   = (u16*)alloc(41L * 128 * 512 * 2);
    u16* xinH    = (u16*)alloc(5120L * 512 * 2);
    u16* xinL    = (u16*)alloc(5120L * 512 * 2);
    u16* WihH    = (u16*)alloc(2048L * 512 * 2);
    u16* WihL    = (u16*)alloc(2048L * 512 * 2);
    u16* WhhH    = (u16*)alloc(2048L * 512 * 2);
    u16* WhhL    = (u16*)alloc(2048L * 512 * 2);
    u16* wqTH    = (u16*)alloc(512L * 512 * 2);
    u16* wqTL    = (u16*)alloc(512L * 512 * 2);
    u16* wqdTH   = (u16*)alloc(512L * 512 * 2);
    u16* wqdTL   = (u16*)alloc(512L * 512 * 2);
    u16* enc1H   = (u16*)alloc(3200L * 512 * 2);
    u16* enc1L   = (u16*)alloc(3200L * 512 * 2);
    u16* enc0H   = (u16*)alloc(3200L * 512 * 2);
    u16* enc0L   = (u16*)alloc(3200L * 512 * 2);
    u16* sq1H    = (u16*)alloc(3328L * 512 * 2);
    u16* sq1L    = (u16*)alloc(3328L * 512 * 2);
    float* E0q   = (float*)alloc(3200L * 512 * 4);
    float* E0o   = (float*)alloc(3200L * 512 * 4);
    u16* woCH    = (u16*)alloc(512L * 512 * 2);
    u16* woCL    = (u16*)alloc(512L * 512 * 2);
    u16* WpH     = (u16*)alloc(2048L * 1024 * 2);
    u16* WpL     = (u16*)alloc(2048L * 1024 * 2);
    float* wsS   = (float*)alloc(5120L * 512 * 4);
    u16* Pbf     = (u16*)alloc(5120L * 416 * 2);
    u16* enc1T   = (u16*)alloc(8L * 512 * 416 * 2);
    u16* catB    = (u16*)alloc(5120L * 1024 * 2);
    u16* woB     = (u16*)alloc(512L * 1024 * 2);
    u16* Alog    = (u16*)alloc(5120L * 512 * 2);
    u16* fcwB    = (u16*)alloc(32000L * 512 * 2);
    float* biasc = (float*)alloc(2048 * 4);
    float* biasd = (float*)alloc(2048 * 4);
    u32* dxP     = (u32*)alloc(4096 * 4);
    u32* hP0     = (u32*)alloc(4096 * 4);
    u32* hP1     = (u32*)alloc(4096 * 4);
    u32* dcP     = (u32*)alloc(4096 * 4);
    u32* dscP    = (u32*)alloc(3200 * 4);
    float* dsent = (float*)alloc(128L * 512 * 4);
    int* bar     = (int*)alloc(4096 * 4);

    // ---- 1: all prep (also zeroes out_attn and all barrier lines) ----
    prep_all<<<dim3(34009), 256, 0, stream>>>(
        wih_w, whh_w, enc1, enc0, wq_w, wq_d, wo_w, fcw, toks, emb, spe,
        bih_w, bhh_w, bih_d, bhh_d, wih_d, whh_d, wo_d,
        WihH, WihL, WhhH, WhhL, enc1H, enc1L, enc0H, enc0L,
        wqTH, wqTL, wqdTH, wqdTL, woB, fcwB, enc1T, xinH, xinL,
        woCH, woCL, WpH, WpL, biasc, biasd, out_attn, bar);

    // ---- 2-5: input-side GEMMs (split-accurate) ----
    gemm_bt<true, 0, 2><<<dim3(4, 25, 1), 256, 0, stream>>>(
        enc1H, enc1L, 512, 0, wqTH, wqTL, 512, 0,
        nullptr, sq1H, sq1L, 512, 0, nullptr, 512);

    gemm_bt<true, 0, 0><<<dim3(4, 25, 1), 256, 0, stream>>>(
        enc0H, enc0L, 512, 0, wqdTH, wqdTL, 512, 0,
        E0q, nullptr, nullptr, 512, 0, nullptr, 512);

    gemm_bt<true, 0, 0><<<dim3(4, 25, 1), 256, 0, stream>>>(
        enc0H, enc0L, 512, 0, woCH, woCL, 512, 0,
        E0o, nullptr, nullptr, 512, 0, nullptr, 512);

    gemm_bt<true, 0, 1><<<dim3(16, 40, 1), 256, 0, stream>>>(
        xinH, xinL, 512, 0, WihH, WihL, 512, 0,
        xW, nullptr, nullptr, 2048, 0, biasc, 512);

    // ---- 6: document-level loop (256 threads, 4-way K-split) ----
    doc_mega<<<dim3(128), 256, 0, stream>>>(
        enc0, E0q, E0o, mask, emb, WpH, WpL, biasd, wo_d,
        dxP, hP0, hP1, dcP, dscP, dsent, out_last, bar);

    // ---- 7: word-level LSTM recurrence ----
    word_mega<<<dim3(256), 512, 0, stream>>>(
        dsent, hAllP, hAllH, hAllL, WhhH, WhhL, xW, catB, bar);

    // ---- 8: batched word attention scores ----
    gemm_bt<true, 1, 0><<<dim3(4, 5, 8), 256, 0, stream>>>(
        hAllH, hAllL, 0, 0, sq1H, sq1L, 512, 204800L,
        wsS, nullptr, nullptr, 512, 327680L, nullptr, 512);

    // ---- 9: softmax -> out_watt + Pbf ----
    word_softmax<<<dim3(5120), 256, 0, stream>>>(wsS, mask, out_watt, Pbf);

    // ---- 10: ctx = P @ enc1 -> catB[:, 0:512] ----
    gemm_bt<false, 0, 4><<<dim3(4, 5, 8), 256, 0, stream>>>(
        Pbf, nullptr, 416, 266240L, enc1T, nullptr, 416, 212992L,
        nullptr, catB, nullptr, 1024, 655360L, nullptr, 416);

    // ---- 11: out = tanh(cat @ wo^T) ----
    gemm_bt<false, 0, 3><<<dim3(4, 40, 1), 256, 0, stream>>>(
        catB, nullptr, 1024, 0, woB, nullptr, 1024, 0,
        nullptr, Alog, nullptr, 512, 0, nullptr, 1024);

    // ---- 12: logits via global_load_lds GEMM (m-tile fast for B reuse) ----
    gemm_lds_bias<<<dim3(40, 250, 1), 256, 0, stream>>>(
        Alog, fcwB, out_dec, fcb, 32000, 512);
}

// Round 10
// 977.130 us; speedup vs baseline: 6.4657x; 1.1373x over previous
//
#include <hip/hip_runtime.h>
#include <cstdint>

typedef unsigned short u16;
typedef unsigned int u32;
typedef __attribute__((ext_vector_type(8))) short bf16x8;
typedef __attribute__((ext_vector_type(8))) unsigned short u16x8;
typedef __attribute__((ext_vector_type(4))) float f32x4;

struct us4 { u16 a, b, c, d; };

__device__ __forceinline__ u16 f2bf(float f) {
    uint32_t u = __float_as_uint(f);
    uint32_t r = (u + 0x7FFFu + ((u >> 16) & 1u)) >> 16;
    return (u16)r;
}
__device__ __forceinline__ float bf2f(u16 h) { return __uint_as_float(((uint32_t)h) << 16); }
__device__ __forceinline__ float sigm(float x) { return 1.f / (1.f + expf(-x)); }
__device__ __forceinline__ float dot4(float4 a, float4 b) {
    return a.x * b.x + a.y * b.y + a.z * b.z + a.w * b.w;
}
__device__ __forceinline__ float wave_sum(float v) {
#pragma unroll
    for (int o = 32; o; o >>= 1) v += __shfl_down(v, o);
    return v;
}
__device__ __forceinline__ float wave_max(float v) {
#pragma unroll
    for (int o = 32; o; o >>= 1) v = fmaxf(v, __shfl_down(v, o));
    return v;
}

// Coherent (device-scope, relaxed) u32 access: no cache maintenance.
__device__ __forceinline__ void ast(u32* p, u32 v) {
    __hip_atomic_store(p, v, __ATOMIC_RELAXED, __HIP_MEMORY_SCOPE_AGENT);
}
__device__ __forceinline__ u32 ald(const u32* p) {
    return __hip_atomic_load(p, __ATOMIC_RELAXED, __HIP_MEMORY_SCOPE_AGENT);
}
__device__ __forceinline__ u32 packsplit(float v) {
    u16 h = f2bf(v);
    u16 l = f2bf(v - bf2f(h));
    return (u32)h | ((u32)l << 16);
}

// ---------------------------------------------------------------------------
// Flag barrier: one own-cacheline flag per block (contention-free arrival
// store), parallel poll (thread i polls flag i). Every wave drains vmcnt(0)
// before arrival. Flags monotonically count barrier generations; zeroed by
// prep_all each launch.
// ---------------------------------------------------------------------------
template <int NBLK>
__device__ __forceinline__ void fbar(u32* flags, int me, u32 gen) {
    asm volatile("s_waitcnt vmcnt(0)" ::: "memory");   // per-wave store drain
    __syncthreads();
    if (threadIdx.x == 0) ast(&flags[me * 32], gen);
    if (threadIdx.x < NBLK) {
        while (ald(&flags[threadIdx.x * 32]) < gen)
            __builtin_amdgcn_s_sleep(1);
    }
    __syncthreads();
    asm volatile("" ::: "memory");
}

// ---------------------------------------------------------------------------
// Generic 128x128-tile BT GEMM (register-staged) — for mid-size GEMMs.
// ---------------------------------------------------------------------------
template <bool SPLIT, int AMODE, int EPI, int XMAJ = 0>
__global__ __launch_bounds__(256) void gemm_bt(
    const u16* __restrict__ AH, const u16* __restrict__ AL, int lda, long strideA,
    const u16* __restrict__ BH, const u16* __restrict__ BL, int ldb, long strideB,
    float* __restrict__ C, u16* __restrict__ CH, u16* __restrict__ CL,
    int ldc, long strideC, const float* __restrict__ bias, int K)
{
    constexpr int TL = 40;
    constexpr int CHK = 128 * TL;
    __shared__ u16 sm[(SPLIT ? 4 : 2) * CHK];
    u16* sAH = sm;
    u16* sBH = sm + CHK;
    u16* sAL = SPLIT ? sm + 2 * CHK : sm;
    u16* sBL = SPLIT ? sm + 3 * CHK : sm;

    const int tid = threadIdx.x;
    const int lane = tid & 63, w = tid >> 6;
    const int wm = w >> 1, wn = w & 1;
    const int lane15 = lane & 15, q8 = (lane >> 4) << 3;
    const int n0 = (XMAJ ? blockIdx.y : blockIdx.x) * 128;
    const int m0 = (XMAJ ? blockIdx.x : blockIdx.y) * 128;
    const int z = blockIdx.z;

    const int r = tid >> 2, c8 = (tid & 3) * 8;

    long aoff[2], boff[2];
#pragma unroll
    for (int h2 = 0; h2 < 2; ++h2) {
        int row = r + (h2 << 6);
        if (AMODE == 0) {
            aoff[h2] = strideA * z + (long)(m0 + row) * lda + c8;
        } else {
            int m = m0 + row;
            int t = m % 40, dd = m / 40;
            aoff[h2] = ((long)(t + 1) * 128 + (z * 16 + dd)) * 512 + c8;
        }
        boff[h2] = strideB * z + (long)(n0 + row) * ldb + c8;
    }

    f32x4 acc[4][4] = {};

    for (int k0 = 0; k0 < K; k0 += 32) {
#pragma unroll
        for (int h2 = 0; h2 < 2; ++h2) {
            int row = r + (h2 << 6);
            int sidx = row * TL + c8;
            *(u16x8*)&sAH[sidx] = *(const u16x8*)&AH[aoff[h2] + k0];
            *(u16x8*)&sBH[sidx] = *(const u16x8*)&BH[boff[h2] + k0];
            if constexpr (SPLIT) {
                *(u16x8*)&sAL[sidx] = *(const u16x8*)&AL[aoff[h2] + k0];
                *(u16x8*)&sBL[sidx] = *(const u16x8*)&BL[boff[h2] + k0];
            }
        }
        __syncthreads();

        bf16x8 a[4], b[4], al[4], bl[4];
#pragma unroll
        for (int i = 0; i < 4; ++i) {
            a[i] = *(const bf16x8*)&sAH[(wm * 64 + i * 16 + lane15) * TL + q8];
            b[i] = *(const bf16x8*)&sBH[(wn * 64 + i * 16 + lane15) * TL + q8];
            if constexpr (SPLIT) {
                al[i] = *(const bf16x8*)&sAL[(wm * 64 + i * 16 + lane15) * TL + q8];
                bl[i] = *(const bf16x8*)&sBL[(wn * 64 + i * 16 + lane15) * TL + q8];
            }
        }
#pragma unroll
        for (int mt = 0; mt < 4; ++mt)
#pragma unroll
            for (int nt = 0; nt < 4; ++nt) {
                acc[mt][nt] = __builtin_amdgcn_mfma_f32_16x16x32_bf16(a[mt], b[nt], acc[mt][nt], 0, 0, 0);
                if constexpr (SPLIT) {
                    acc[mt][nt] = __builtin_amdgcn_mfma_f32_16x16x32_bf16(a[mt], bl[nt], acc[mt][nt], 0, 0, 0);
                    acc[mt][nt] = __builtin_amdgcn_mfma_f32_16x16x32_bf16(al[mt], b[nt], acc[mt][nt], 0, 0, 0);
                }
            }
        __syncthreads();
    }

#pragma unroll
    for (int mt = 0; mt < 4; ++mt)
#pragma unroll
        for (int nt = 0; nt < 4; ++nt)
#pragma unroll
            for (int i = 0; i < 4; ++i) {
                int row = m0 + wm * 64 + mt * 16 + ((lane >> 4) << 2) + i;
                int col = n0 + wn * 64 + nt * 16 + lane15;
                long off = strideC * z + (long)row * ldc + col;
                float v = acc[mt][nt][i];
                if constexpr (EPI == 0) {
                    C[off] = v;
                } else if constexpr (EPI == 1) {
                    C[off] = v + bias[col];
                } else if constexpr (EPI == 2) {
                    u16 h_ = f2bf(v);
                    CH[off] = h_;
                    CL[off] = f2bf(v - bf2f(h_));
                } else if constexpr (EPI == 3) {
                    CH[off] = f2bf(tanhf(v));
                } else {
                    CH[off] = f2bf(v);
                }
            }
}

// ---------------------------------------------------------------------------
// Merged head GEMMs (sq1 / E0q / E0o / xW) — one 940-block launch.
// All SPLIT, K=512, lda=ldb=512, AMODE0. Region-dispatched by blockIdx.x.
// ---------------------------------------------------------------------------
__global__ __launch_bounds__(256) void gemm_head(
    const u16* __restrict__ enc1H, const u16* __restrict__ enc1L,
    const u16* __restrict__ wqTH,  const u16* __restrict__ wqTL,
    const u16* __restrict__ enc0H, const u16* __restrict__ enc0L,
    const u16* __restrict__ wqdTH, const u16* __restrict__ wqdTL,
    const u16* __restrict__ woCH,  const u16* __restrict__ woCL,
    const u16* __restrict__ xinH,  const u16* __restrict__ xinL,
    const u16* __restrict__ WihH,  const u16* __restrict__ WihL,
    u16* __restrict__ sq1H, u16* __restrict__ sq1L,
    float* __restrict__ E0q, float* __restrict__ E0o,
    float* __restrict__ xW, const float* __restrict__ biasc)
{
    constexpr int TL = 40;
    constexpr int CHK = 128 * TL;
    __shared__ u16 sm[4 * CHK];
    u16* sAH = sm;
    u16* sBH = sm + CHK;
    u16* sAL = sm + 2 * CHK;
    u16* sBL = sm + 3 * CHK;

    const int bid = blockIdx.x;
    const u16 *AH, *AL, *BH, *BL;
    int task, n0, m0, ldc;
    if (bid < 300) {
        task = bid / 100;
        int rr = bid % 100;
        n0 = (rr & 3) * 128; m0 = (rr >> 2) * 128; ldc = 512;
        if (task == 0)      { AH = enc1H; AL = enc1L; BH = wqTH;  BL = wqTL;  }
        else if (task == 1) { AH = enc0H; AL = enc0L; BH = wqdTH; BL = wqdTL; }
        else                { AH = enc0H; AL = enc0L; BH = woCH;  BL = woCL;  }
    } else {
        task = 3;
        int rr = bid - 300;
        n0 = (rr & 15) * 128; m0 = (rr >> 4) * 128; ldc = 2048;
        AH = xinH; AL = xinL; BH = WihH; BL = WihL;
    }

    const int tid = threadIdx.x;
    const int lane = tid & 63, w = tid >> 6;
    const int wm = w >> 1, wn = w & 1;
    const int lane15 = lane & 15, q8 = (lane >> 4) << 3;
    const int r = tid >> 2, c8 = (tid & 3) * 8;

    long aoff[2], boff[2];
#pragma unroll
    for (int h2 = 0; h2 < 2; ++h2) {
        int row = r + (h2 << 6);
        aoff[h2] = (long)(m0 + row) * 512 + c8;
        boff[h2] = (long)(n0 + row) * 512 + c8;
    }

    f32x4 acc[4][4] = {};
    for (int k0 = 0; k0 < 512; k0 += 32) {
#pragma unroll
        for (int h2 = 0; h2 < 2; ++h2) {
            int row = r + (h2 << 6);
            int sidx = row * TL + c8;
            *(u16x8*)&sAH[sidx] = *(const u16x8*)&AH[aoff[h2] + k0];
            *(u16x8*)&sBH[sidx] = *(const u16x8*)&BH[boff[h2] + k0];
            *(u16x8*)&sAL[sidx] = *(const u16x8*)&AL[aoff[h2] + k0];
            *(u16x8*)&sBL[sidx] = *(const u16x8*)&BL[boff[h2] + k0];
        }
        __syncthreads();
        bf16x8 a[4], b[4], al[4], bl[4];
#pragma unroll
        for (int i = 0; i < 4; ++i) {
            a[i]  = *(const bf16x8*)&sAH[(wm * 64 + i * 16 + lane15) * TL + q8];
            b[i]  = *(const bf16x8*)&sBH[(wn * 64 + i * 16 + lane15) * TL + q8];
            al[i] = *(const bf16x8*)&sAL[(wm * 64 + i * 16 + lane15) * TL + q8];
            bl[i] = *(const bf16x8*)&sBL[(wn * 64 + i * 16 + lane15) * TL + q8];
        }
#pragma unroll
        for (int mt = 0; mt < 4; ++mt)
#pragma unroll
            for (int nt = 0; nt < 4; ++nt) {
                acc[mt][nt] = __builtin_amdgcn_mfma_f32_16x16x32_bf16(a[mt],  b[nt],  acc[mt][nt], 0, 0, 0);
                acc[mt][nt] = __builtin_amdgcn_mfma_f32_16x16x32_bf16(a[mt],  bl[nt], acc[mt][nt], 0, 0, 0);
                acc[mt][nt] = __builtin_amdgcn_mfma_f32_16x16x32_bf16(al[mt], b[nt],  acc[mt][nt], 0, 0, 0);
            }
        __syncthreads();
    }

#pragma unroll
    for (int mt = 0; mt < 4; ++mt)
#pragma unroll
        for (int nt = 0; nt < 4; ++nt)
#pragma unroll
            for (int i = 0; i < 4; ++i) {
                int row = m0 + wm * 64 + mt * 16 + ((lane >> 4) << 2) + i;
                int col = n0 + wn * 64 + nt * 16 + lane15;
                long off = (long)row * ldc + col;
                float v = acc[mt][nt][i];
                if (task == 0) {
                    u16 h_ = f2bf(v);
                    sq1H[off] = h_;
                    sq1L[off] = f2bf(v - bf2f(h_));
                } else if (task == 1) {
                    E0q[off] = v;
                } else if (task == 2) {
                    E0o[off] = v;
                } else {
                    xW[off] = v + biasc[col];
                }
            }
}

// ---------------------------------------------------------------------------
// Logits GEMM: global_load_lds staging + NONTEMPORAL C stores (keep fcw B
// tiles L2-resident instead of evicting them with 640 MB of C writes).
// ---------------------------------------------------------------------------
#define GLOAD_LDS16(gsrc, ldst) \
    __builtin_amdgcn_global_load_lds((const __attribute__((address_space(1))) u32*)(gsrc), \
                                     (__attribute__((address_space(3))) u32*)(ldst), 16, 0, 0)

__global__ __launch_bounds__(256) void gemm_lds_bias(
    const u16* __restrict__ A, const u16* __restrict__ B,
    float* __restrict__ C, const float* __restrict__ bias, int ldc, int K)
{
    __shared__ u16 sA[128 * 32];
    __shared__ u16 sB[128 * 32];

    const int tid = threadIdx.x;
    const int lane = tid & 63, w = tid >> 6;
    const int wm = w >> 1, wn = w & 1;
    const int lane15 = lane & 15, q8 = (lane >> 4) << 3;
    const int m0 = blockIdx.x * 128;
    const int n0 = blockIdx.y * 128;

    const int srow = lane >> 2, schunk = (lane & 3) * 8;

    f32x4 acc[4][4] = {};

    for (int k0 = 0; k0 < K; k0 += 32) {
#pragma unroll
        for (int c = 0; c < 2; ++c) {
            int base_r = (w * 2 + c) * 16;
            const u16* ga = A + (long)(m0 + base_r + srow) * 512 + k0 + schunk;
            const u16* gb = B + (long)(n0 + base_r + srow) * 512 + k0 + schunk;
            GLOAD_LDS16(ga, &sA[base_r * 32]);
            GLOAD_LDS16(gb, &sB[base_r * 32]);
        }
        __syncthreads();

        bf16x8 a[4], b[4];
#pragma unroll
        for (int i = 0; i < 4; ++i) {
            a[i] = *(const bf16x8*)&sA[(wm * 64 + i * 16 + lane15) * 32 + q8];
            b[i] = *(const bf16x8*)&sB[(wn * 64 + i * 16 + lane15) * 32 + q8];
        }
#pragma unroll
        for (int mt = 0; mt < 4; ++mt)
#pragma unroll
            for (int nt = 0; nt < 4; ++nt)
                acc[mt][nt] = __builtin_amdgcn_mfma_f32_16x16x32_bf16(a[mt], b[nt], acc[mt][nt], 0, 0, 0);
        __syncthreads();
    }

#pragma unroll
    for (int mt = 0; mt < 4; ++mt)
#pragma unroll
        for (int nt = 0; nt < 4; ++nt)
#pragma unroll
            for (int i = 0; i < 4; ++i) {
                int row = m0 + wm * 64 + mt * 16 + ((lane >> 4) << 2) + i;
                int col = n0 + wn * 64 + nt * 16 + lane15;
                __builtin_nontemporal_store(acc[mt][nt][i] + bias[col], &C[(long)row * ldc + col]);
            }
}

// ---------------------------------------------------------------------------
// Doc-level loop: 128 blocks x 256 threads, flag barriers.
// ---------------------------------------------------------------------------
__global__ __launch_bounds__(256) void doc_mega(
    const float* __restrict__ enc0, const float* __restrict__ E0q,
    const float* __restrict__ E0o, const unsigned char* __restrict__ mask,
    const float* __restrict__ emb,
    const u16* __restrict__ WpH, const u16* __restrict__ WpL,
    const float* __restrict__ biasd, const float* __restrict__ wo_d,
    u32* __restrict__ dxP, u32* __restrict__ hP0, u32* __restrict__ hP1,
    u32* __restrict__ dcP, u32* __restrict__ dscP,
    float* __restrict__ dsent, float* __restrict__ out_last, u32* bar)
{
    __shared__ u16 xhH[16 * 1032];
    __shared__ u16 xhL[16 * 1032];
    __shared__ float red4[4][16 * 17];
    __shared__ float aux2[512];
    __shared__ float sc_s[512];
    __shared__ float whoh_s[32];
    __shared__ float ctxp[8][32];
    __shared__ float rtmp[8];

    const int blk = blockIdx.x, tid = threadIdx.x;
    const int w = tid >> 6, lane = tid & 63;
    const int b_ = blk >> 4, s = blk & 15;
    const int lane15 = lane & 15, q8 = (lane >> 4) << 3;
    u32* fF = bar;                       // 128 flags
    u32* fG = bar + 4096 + b_ * 512;     // 16 flags per batch group
    u32 genF = 0, genG = 0;

    for (int q = tid; q < 8 * 1032; q += 256) { xhH[8 * 1032 + q] = 0; xhL[8 * 1032 + q] = 0; }

    {   // init: dh = dc = mean_j enc0[b,j,:], dx = emb[SOD]
        int dd = tid & 31, part = tid >> 5;
        const float* p0 = enc0 + ((long)b_ * 400 + part * 50) * 512 + s * 32 + dd;
        float sm = 0.f;
#pragma unroll 10
        for (int j = 0; j < 50; ++j) { sm += *p0; p0 += 512; }
        ctxp[part][dd] = sm;
        __syncthreads();
        if (tid < 32) {
            float m = 0.f;
#pragma unroll
            for (int p = 0; p < 8; ++p) m += ctxp[p][tid];
            m *= (1.f / 400.f);
            int e = s * 32 + tid;
            ast(&hP0[b_ * 512 + e], packsplit(m));
            ast(&dcP[b_ * 512 + e], __float_as_uint(m));
            ast(&dxP[b_ * 512 + e], packsplit(emb[1024 + e]));
        }
    }
    fbar<128>(fF, blk, ++genF);

    // dc handoff into registers (block-exclusive thereafter)
    const int eb_b = tid & 7, eb_u4 = tid >> 3, eb_u = blk * 4 + eb_u4;
    float dcr = 0.f;
    if (tid < 32) dcr = __uint_as_float(ald(&dcP[eb_b * 512 + eb_u]));

    const u16* bh_base = WpH + ((long)blk * 16 + lane15) * 1024 + (w << 8) + q8;
    const u16* bl_base = WpL + ((long)blk * 16 + lane15) * 1024 + (w << 8) + q8;
    const u16* ah_base = xhH + lane15 * 1032 + (w << 8) + q8;
    const u16* al_base = xhL + lane15 * 1032 + (w << 8) + q8;

    for (int t = 0; t < 16; ++t) {
        u32* hinP = (t & 1) ? hP1 : hP0;
        u32* houtP = (t & 1) ? hP0 : hP1;

        // ---- A: stage packed x|h into LDS (2 batches of 16 coherent loads) ----
#pragma unroll
        for (int half = 0; half < 2; ++half) {
            u32 px[8], ph[8];
#pragma unroll
            for (int j = 0; j < 8; ++j) {
                int q = half * 2048 + j * 256 + tid;
                px[j] = ald(&dxP[q]);
                ph[j] = ald(&hinP[q]);
            }
#pragma unroll
            for (int j = 0; j < 8; ++j) {
                int q = half * 2048 + j * 256 + tid;
                int o = (q >> 9) * 1032 + (q & 511);
                xhH[o] = (u16)px[j];           xhL[o] = (u16)(px[j] >> 16);
                xhH[o + 512] = (u16)ph[j];     xhL[o + 512] = (u16)(ph[j] >> 16);
            }
        }
        __syncthreads();

        // 4-way K-split MFMA
        f32x4 acc = {};
#pragma unroll
        for (int k0 = 0; k0 < 256; k0 += 32) {
            bf16x8 aH = *(const bf16x8*)&ah_base[k0];
            bf16x8 aL = *(const bf16x8*)&al_base[k0];
            bf16x8 bH = *(const bf16x8*)&bh_base[k0];
            bf16x8 bL = *(const bf16x8*)&bl_base[k0];
            acc = __builtin_amdgcn_mfma_f32_16x16x32_bf16(aH, bH, acc, 0, 0, 0);
            acc = __builtin_amdgcn_mfma_f32_16x16x32_bf16(aH, bL, acc, 0, 0, 0);
            acc = __builtin_amdgcn_mfma_f32_16x16x32_bf16(aL, bH, acc, 0, 0, 0);
        }
#pragma unroll
        for (int i = 0; i < 4; ++i)
            red4[w][((lane >> 4) * 4 + i) * 17 + lane15] = acc[i];
        __syncthreads();

        if (tid < 32) {
            float g4[4];
#pragma unroll
            for (int g = 0; g < 4; ++g)
                g4[g] = red4[0][eb_b * 17 + eb_u4 * 4 + g] + red4[1][eb_b * 17 + eb_u4 * 4 + g]
                      + red4[2][eb_b * 17 + eb_u4 * 4 + g] + red4[3][eb_b * 17 + eb_u4 * 4 + g];
            float gi = g4[0] + biasd[eb_u];
            float gf = g4[1] + biasd[512 + eb_u];
            float gg = g4[2] + biasd[1024 + eb_u];
            float go = g4[3] + biasd[1536 + eb_u];
            dcr = sigm(gf) * dcr + sigm(gi) * tanhf(gg);
            float hv = sigm(go) * tanhf(dcr);
            ast(&houtP[eb_b * 512 + eb_u], packsplit(hv));
        }
        fbar<128>(fF, blk, ++genF);

        // ---- B: scores (j-slice) + whoh (8 rows/wave) ----
        {
            u32 p0 = ald(&houtP[b_ * 512 + tid]);
            u32 p1 = ald(&houtP[b_ * 512 + 256 + tid]);
            aux2[tid] = bf2f((u16)p0) + bf2f((u16)(p0 >> 16));
            aux2[256 + tid] = bf2f((u16)p1) + bf2f((u16)(p1 >> 16));
            __syncthreads();
            for (int jj = w; jj < 25; jj += 4) {
                int j = s * 25 + jj;
                const float4* er = (const float4*)(E0q + ((long)b_ * 400 + j) * 512) + lane * 2;
                const float4* hv = (const float4*)aux2 + lane * 2;
                float sv = dot4(er[0], hv[0]) + dot4(er[1], hv[1]);
                sv = wave_sum(sv);
                if (lane == 0)
                    ast(&dscP[b_ * 400 + j], __float_as_uint(mask[b_ * 400 + j] ? -1e9f : sv));
            }
#pragma unroll
            for (int r = 0; r < 8; ++r) {
                int d = s * 32 + w * 8 + r;
                const float4* wr = (const float4*)(wo_d + (long)d * 1024 + 512) + lane * 2;
                const float4* hv = (const float4*)aux2 + lane * 2;
                float sv = dot4(wr[0], hv[0]) + dot4(wr[1], hv[1]);
                sv = wave_sum(sv);
                if (lane == 0) whoh_s[w * 8 + r] = sv;
            }
        }
        fbar<16>(fG, s, ++genG);   // B->C is batch-group-local

        // ---- C: softmax (block-local) + ctx (d-slice) + out ----
        {
            float v0 = __uint_as_float(ald(&dscP[b_ * 400 + tid]));
            bool h1 = (tid + 256) < 400;
            float v1 = h1 ? __uint_as_float(ald(&dscP[b_ * 400 + tid + 256])) : -1e30f;
            float mx = wave_max(fmaxf(v0, v1));
            if (lane == 0) rtmp[w] = mx;
            __syncthreads();
            float M = fmaxf(fmaxf(rtmp[0], rtmp[1]), fmaxf(rtmp[2], rtmp[3]));
            float e0 = expf(v0 - M);
            float e1 = h1 ? expf(v1 - M) : 0.f;
            float sv = wave_sum(e0 + e1);
            if (lane == 0) rtmp[4 + w] = sv;
            __syncthreads();
            float inv = 1.f / (rtmp[4] + rtmp[5] + rtmp[6] + rtmp[7]);
            sc_s[tid] = e0 * inv;
            if (h1) sc_s[tid + 256] = e1 * inv;
            __syncthreads();
            int dd = tid & 31, part = tid >> 5;
            const float* eo = E0o + ((long)b_ * 400 + part * 50) * 512 + s * 32 + dd;
            float acc2 = 0.f;
#pragma unroll 10
            for (int j = 0; j < 50; ++j) { acc2 += sc_s[part * 50 + j] * (*eo); eo += 512; }
            ctxp[part][dd] = acc2;
            __syncthreads();
            if (tid < 32) {
                int d = s * 32 + tid;
                float o = whoh_s[tid];
#pragma unroll
                for (int p = 0; p < 8; ++p) o += ctxp[p][tid];
                float val = tanhf(o);
                ast(&dxP[b_ * 512 + d], packsplit(val));
                dsent[((b_ << 4) + t) * 512 + d] = val;
                if (t == 15) out_last[b_ * 512 + d] = val;
            }
        }
        fbar<128>(fF, blk, ++genF);
    }
}

// ---------------------------------------------------------------------------
// Word-level loop: 256 blocks x 512 threads, K-split 8, flag barriers.
// ---------------------------------------------------------------------------
__global__ __launch_bounds__(512) void word_mega(
    const float* __restrict__ sentS,
    u32* __restrict__ hAllP,
    u16* __restrict__ hAllH, u16* __restrict__ hAllL,
    const u16* __restrict__ WhhH, const u16* __restrict__ WhhL,
    const float* __restrict__ xW,
    u16* __restrict__ catB, u32* bar)
{
    __shared__ float red[8][4][256];
    const int tid = threadIdx.x, blk = blockIdx.x;
    const int b2t = blk >> 5;
    const int u0 = (blk & 31) << 4;
    u32* fG = bar + 8192 + b2t * 1024;   // 32 flags per b2t group
    u32 genG = 0;

    float wcr = 0.f;
    long cidx = 0;
    int my_b2 = 0, my_u = 0;
    if (tid < 256) {
        my_b2 = b2t * 16 + (tid >> 4);
        my_u = u0 + (tid & 15);
        cidx = (long)my_b2 * 512 + my_u;
        wcr = sentS[cidx];
        ast(&hAllP[cidx], packsplit(wcr));
    }
    fbar<32>(fG, blk & 31, ++genG);

    const int w = tid >> 6, lane = tid & 63;
    const int lane15 = lane & 15, q8 = (lane >> 4) << 3;
    const long arowE = (long)(b2t * 16 + lane15) * 512 + w * 64 + q8;
    long brow[4];
#pragma unroll
    for (int g = 0; g < 4; ++g)
        brow[g] = (long)(g * 512 + u0 + lane15) * 512 + w * 64 + q8;

    for (int t = 0; t < 40; ++t) {
        const u32* hP = hAllP + (long)t * 65536;

        u32 ph[16];
#pragma unroll
        for (int j = 0; j < 16; ++j)
            ph[j] = ald(&hP[arowE + (j >> 3) * 32 + (j & 7)]);

        float xw0 = 0.f, xw1 = 0.f, xw2 = 0.f, xw3 = 0.f;
        if (tid < 256) {
            const float* xr = xW + (long)t * 262144 + (long)my_b2 * 2048;
            xw0 = xr[my_u]; xw1 = xr[512 + my_u]; xw2 = xr[1024 + my_u]; xw3 = xr[1536 + my_u];
        }

        f32x4 acc[4] = {};
#pragma unroll
        for (int half = 0; half < 2; ++half) {
            int k0 = half * 32;
            bf16x8 aH, aL;
#pragma unroll
            for (int j = 0; j < 8; ++j) {
                u32 p = ph[half * 8 + j];
                aH[j] = (short)(p & 0xffffu);
                aL[j] = (short)(p >> 16);
            }
#pragma unroll
            for (int g = 0; g < 4; ++g) {
                bf16x8 bH = *(const bf16x8*)&WhhH[brow[g] + k0];
                bf16x8 bL = *(const bf16x8*)&WhhL[brow[g] + k0];
                acc[g] = __builtin_amdgcn_mfma_f32_16x16x32_bf16(aH, bH, acc[g], 0, 0, 0);
                acc[g] = __builtin_amdgcn_mfma_f32_16x16x32_bf16(aH, bL, acc[g], 0, 0, 0);
                acc[g] = __builtin_amdgcn_mfma_f32_16x16x32_bf16(aL, bH, acc[g], 0, 0, 0);
            }
        }
#pragma unroll
        for (int g = 0; g < 4; ++g)
#pragma unroll
            for (int i = 0; i < 4; ++i)
                red[w][g][((lane >> 4) * 4 + i) * 16 + lane15] = acc[g][i];
        __syncthreads();

        if (tid < 256) {
            float g4[4] = {0.f, 0.f, 0.f, 0.f};
#pragma unroll
            for (int ks = 0; ks < 8; ++ks)
#pragma unroll
                for (int g = 0; g < 4; ++g)
                    g4[g] += red[ks][g][tid];
            float gi = g4[0] + xw0;
            float gf = g4[1] + xw1;
            float gg = g4[2] + xw2;
            float go = g4[3] + xw3;
            wcr = sigm(gf) * wcr + sigm(gi) * tanhf(gg);
            float hv = sigm(go) * tanhf(wcr);
            u16 hh = f2bf(hv);
            u16 ll = f2bf(hv - bf2f(hh));
            long o = (long)(t + 1) * 65536 + cidx;
            ast(&hAllP[o], (u32)hh | ((u32)ll << 16));
            hAllH[o] = hh;
            hAllL[o] = ll;
            catB[((long)my_b2 * 40 + t) * 1024 + 512 + my_u] = hh;
        }
        fbar<32>(fG, blk & 31, ++genG);
    }
}

// ---------------------------------------------------------------------------
// All prep work in one region-dispatched kernel.
// ---------------------------------------------------------------------------
__device__ __forceinline__ void split1(const float* __restrict__ src,
                                       u16* __restrict__ H, u16* __restrict__ L, long i)
{
    float4 v = ((const float4*)src)[i];
    u16 h0 = f2bf(v.x), h1 = f2bf(v.y), h2 = f2bf(v.z), h3 = f2bf(v.w);
    ((us4*)H)[i] = {h0, h1, h2, h3};
    ((us4*)L)[i] = {f2bf(v.x - bf2f(h0)), f2bf(v.y - bf2f(h1)),
                    f2bf(v.z - bf2f(h2)), f2bf(v.w - bf2f(h3))};
}
__device__ __forceinline__ void wqT1(const float* __restrict__ wq,
                                     u16* __restrict__ H, u16* __restrict__ L, int idx)
{
    int e = idx >> 9, d = idx & 511;
    float v = wq[(long)d * 512 + e];
    u16 h = f2bf(v);
    H[idx] = h;
    L[idx] = f2bf(v - bf2f(h));
}

__global__ __launch_bounds__(256) void prep_all(
    const float* __restrict__ wih_w, const float* __restrict__ whh_w,
    const float* __restrict__ enc1, const float* __restrict__ enc0,
    const float* __restrict__ wq_w, const float* __restrict__ wq_d,
    const float* __restrict__ wo_w, const float* __restrict__ fcw,
    const int* __restrict__ toks, const float* __restrict__ emb,
    const float* __restrict__ spe,
    const float* __restrict__ bih_w, const float* __restrict__ bhh_w,
    const float* __restrict__ bih_d, const float* __restrict__ bhh_d,
    const float* __restrict__ wih_d, const float* __restrict__ whh_d,
    const float* __restrict__ wo_d,
    u16* __restrict__ WihH, u16* __restrict__ WihL,
    u16* __restrict__ WhhH, u16* __restrict__ WhhL,
    u16* __restrict__ enc1H, u16* __restrict__ enc1L,
    u16* __restrict__ enc0H, u16* __restrict__ enc0L,
    u16* __restrict__ wqTH, u16* __restrict__ wqTL,
    u16* __restrict__ wqdTH, u16* __restrict__ wqdTL,
    u16* __restrict__ woB, u16* __restrict__ fcwB, u16* __restrict__ enc1T,
    u16* __restrict__ xinH, u16* __restrict__ xinL,
    u16* __restrict__ woCH, u16* __restrict__ woCL,
    u16* __restrict__ WpH, u16* __restrict__ WpL,
    float* __restrict__ biasc, float* __restrict__ biasd,
    float* __restrict__ out_attn, u32* __restrict__ bar)
{
    int b = blockIdx.x;
    const int tid = threadIdx.x;

    if (b < 1024) { split1(wih_w, WihH, WihL, (long)b * 256 + tid); return; }
    b -= 1024;
    if (b < 1024) { split1(whh_w, WhhH, WhhL, (long)b * 256 + tid); return; }
    b -= 1024;
    if (b < 1600) { split1(enc1, enc1H, enc1L, (long)b * 256 + tid); return; }
    b -= 1600;
    if (b < 1600) { split1(enc0, enc0H, enc0L, (long)b * 256 + tid); return; }
    b -= 1600;
    if (b < 1024) { wqT1(wq_w, wqTH, wqTL, b * 256 + tid); return; }
    b -= 1024;
    if (b < 1024) { wqT1(wq_d, wqdTH, wqdTL, b * 256 + tid); return; }
    b -= 1024;
    if (b < 512) {
        long i = (long)b * 256 + tid;
        float4 v = ((const float4*)wo_w)[i];
        ((us4*)woB)[i] = {f2bf(v.x), f2bf(v.y), f2bf(v.z), f2bf(v.w)};
        return;
    }
    b -= 512;
    if (b < 16000) {
        long i = (long)b * 256 + tid;
        float4 v = ((const float4*)fcw)[i];
        ((us4*)fcwB)[i] = {f2bf(v.x), f2bf(v.y), f2bf(v.z), f2bf(v.w)};
        return;
    }
    b -= 16000;
    if (b < 6656) {
        long idx = (long)b * 256 + tid;
        int j = (int)(idx % 416);
        long be = idx / 416;
        int e = (int)(be % 512);
        int bb = (int)(be / 512);
        float v = (j < 400) ? enc1[((long)bb * 400 + j) * 512 + e] : 0.f;
        enc1T[idx] = f2bf(v);
        return;
    }
    b -= 6656;
    if (b < 1280) {
        int g = b * 256 + tid;
        int m = g >> 6, e0 = (g & 63) << 3;
        int t = m >> 7, b2 = m & 127;
        int ne = 0;
        for (int s = 0; s < 40; ++s) ne |= (toks[b2 * 40 + s] != 1);
        int pos = ne ? (2 + (b2 & 15)) : 1;
        const float* ep = emb + (long)toks[b2 * 40 + t] * 512 + e0;
        const float* sp = spe + (long)pos * 512 + e0;
        long o = (long)m * 512 + e0;
#pragma unroll
        for (int j = 0; j < 8; ++j) {
            float v = ep[j] + sp[j];
            u16 h = f2bf(v);
            xinH[o + j] = h;
            xinL[o + j] = f2bf(v - bf2f(h));
        }
        return;
    }
    b -= 1280;
    if (b < 1) {
        for (int i = tid; i < 2048; i += 256) {
            biasc[i] = bih_w[i] + bhh_w[i];
            biasd[i] = bih_d[i] + bhh_d[i];
        }
        return;
    }
    b -= 1;
    if (b < 200) {
        out_attn[b * 256 + tid] = 0.f;
        return;
    }
    b -= 200;
    if (b < 1024) {
        int i = b * 256 + tid;
        int d = i >> 9, e = i & 511;
        float v = wo_d[(long)d * 1024 + e];
        u16 h = f2bf(v);
        woCH[i] = h;
        woCL[i] = f2bf(v - bf2f(h));
        return;
    }
    b -= 1024;
    if (b < 1024) {
        long gidx = (long)b * 256 + tid;
        int r = (int)(gidx >> 7);
        int k8 = ((int)gidx & 127) * 8;
        int u = r >> 2, g = r & 3;
        long orow = (long)(g * 512 + u);
#pragma unroll
        for (int j = 0; j < 8; ++j) {
            int k = k8 + j;
            float v = (k < 512) ? wih_d[orow * 512 + k] : whh_d[orow * 512 + k - 512];
            u16 h = f2bf(v);
            WpH[(long)r * 1024 + k] = h;
            WpL[(long)r * 1024 + k] = f2bf(v - bf2f(h));
        }
        return;
    }
    b -= 1024;
    // zero the flag-barrier region: 64 blocks x 256 = 16384 u32
    bar[b * 256 + tid] = 0;
}

__global__ __launch_bounds__(256) void word_softmax(
    const float* __restrict__ sc, const unsigned char* __restrict__ mask,
    float* __restrict__ pout, u16* __restrict__ pbf)
{
    const int r = blockIdx.x, tid = threadIdx.x;
    const int b = r / 640;
    const int wv = tid >> 6, lane = tid & 63;
    __shared__ float red[4];
    const int j1 = tid + 256;
    float v0 = sc[(long)r * 512 + tid];
    if (mask[b * 400 + tid]) v0 = -1e9f;
    float v1 = -1e30f;
    if (j1 < 400) {
        v1 = sc[(long)r * 512 + j1];
        if (mask[b * 400 + j1]) v1 = -1e9f;
    }
    float mv = wave_max(fmaxf(v0, v1));
    if (lane == 0) red[wv] = mv;
    __syncthreads();
    if (tid == 0) red[0] = fmaxf(fmaxf(red[0], red[1]), fmaxf(red[2], red[3]));
    __syncthreads();
    const float M = red[0];
    float e0 = expf(v0 - M);
    float e1 = (j1 < 400) ? expf(v1 - M) : 0.f;
    __syncthreads();
    float sv = wave_sum(e0 + e1);
    if (lane == 0) red[wv] = sv;
    __syncthreads();
    if (tid == 0) red[0] = red[0] + red[1] + red[2] + red[3];
    __syncthreads();
    const float inv = 1.f / red[0];
    float p0 = e0 * inv;
    pout[(long)r * 400 + tid] = p0;
    pbf[(long)r * 416 + tid] = f2bf(p0);
    if (j1 < 400) {
        float p1 = e1 * inv;
        pout[(long)r * 400 + j1] = p1;
        pbf[(long)r * 416 + j1] = f2bf(p1);
    } else if (j1 < 416) {
        pbf[(long)r * 416 + j1] = 0;
    }
}

// ---------------------------------------------------------------------------
extern "C" void kernel_launch(void* const* d_in, const int* in_sizes, int n_in,
                              void* d_out, int out_size, void* d_ws, size_t ws_size,
                              hipStream_t stream)
{
    (void)in_sizes; (void)n_in; (void)out_size; (void)ws_size;

    const int*   toks  = (const int*)  d_in[0];
    const float* enc0  = (const float*)d_in[1];
    const float* enc1  = (const float*)d_in[2];
    const unsigned char* mask = (const unsigned char*)d_in[3];
    const float* emb   = (const float*)d_in[4];
    const float* spe   = (const float*)d_in[5];
    const float* wih_d = (const float*)d_in[6];
    const float* whh_d = (const float*)d_in[7];
    const float* bih_d = (const float*)d_in[8];
    const float* bhh_d = (const float*)d_in[9];
    const float* wq_d  = (const float*)d_in[10];
    const float* wo_d  = (const float*)d_in[11];
    const float* wih_w = (const float*)d_in[12];
    const float* whh_w = (const float*)d_in[13];
    const float* bih_w = (const float*)d_in[14];
    const float* bhh_w = (const float*)d_in[15];
    const float* wq_w  = (const float*)d_in[16];
    const float* wo_w  = (const float*)d_in[17];
    const float* fcw   = (const float*)d_in[18];
    const float* fcb   = (const float*)d_in[19];

    float* out_dec  = (float*)d_out;                  // [8,640,32000]
    float* out_attn = out_dec + 163840000L;           // [8,16,400] zeros
    float* out_watt = out_attn + 51200;               // [128,40,400]
    float* out_last = out_watt + 2048000;             // [8,512]

    char* wsp = (char*)d_ws;
    auto alloc = [&](size_t bytes) -> void* {
        void* p = wsp;
        wsp += (bytes + 255) & ~(size_t)255;
        return p;
    };

    float* xW    = (float*)alloc(40L * 128 * 2048 * 4);
    u32* hAllP   = (u32*)alloc(41L * 128 * 512 * 4);
    u16* hAllH   = (u16*)alloc(41L * 128 * 512 * 2);
    u16* hAllL   = (u16*)alloc(41L * 128 * 512 * 2);
    u16* xinH    = (u16*)alloc(5120L * 512 * 2);
    u16* xinL    = (u16*)alloc(5120L * 512 * 2);
    u16* WihH    = (u16*)alloc(2048L * 512 * 2);
    u16* WihL    = (u16*)alloc(2048L * 512 * 2);
    u16* WhhH    = (u16*)alloc(2048L * 512 * 2);
    u16* WhhL    = (u16*)alloc(2048L * 512 * 2);
    u16* wqTH    = (u16*)alloc(512L * 512 * 2);
    u16* wqTL    = (u16*)alloc(512L * 512 * 2);
    u16* wqdTH   = (u16*)alloc(512L * 512 * 2);
    u16* wqdTL   = (u16*)alloc(512L * 512 * 2);
    u16* enc1H   = (u16*)alloc(3200L * 512 * 2);
    u16* enc1L   = (u16*)alloc(3200L * 512 * 2);
    u16* enc0H   = (u16*)alloc(3200L * 512 * 2);
    u16* enc0L   = (u16*)alloc(3200L * 512 * 2);
    u16* sq1H    = (u16*)alloc(3328L * 512 * 2);
    u16* sq1L    = (u16*)alloc(3328L * 512 * 2);
    float* E0q   = (float*)alloc(3200L * 512 * 4);
    float* E0o   = (float*)alloc(3200L * 512 * 4);
    u16* woCH    = (u16*)alloc(512L * 512 * 2);
    u16* woCL    = (u16*)alloc(512L * 512 * 2);
    u16* WpH     = (u16*)alloc(2048L * 1024 * 2);
    u16* WpL     = (u16*)alloc(2048L * 1024 * 2);
    float* wsS   = (float*)alloc(5120L * 512 * 4);
    u16* Pbf     = (u16*)alloc(5120L * 416 * 2);
    u16* enc1T   = (u16*)alloc(8L * 512 * 416 * 2);
    u16* catB    = (u16*)alloc(5120L * 1024 * 2);
    u16* woB     = (u16*)alloc(512L * 1024 * 2);
    u16* Alog    = (u16*)alloc(5120L * 512 * 2);
    u16* fcwB    = (u16*)alloc(32000L * 512 * 2);
    float* biasc = (float*)alloc(2048 * 4);
    float* biasd = (float*)alloc(2048 * 4);
    u32* dxP     = (u32*)alloc(4096 * 4);
    u32* hP0     = (u32*)alloc(4096 * 4);
    u32* hP1     = (u32*)alloc(4096 * 4);
    u32* dcP     = (u32*)alloc(4096 * 4);
    u32* dscP    = (u32*)alloc(3200 * 4);
    float* dsent = (float*)alloc(128L * 512 * 4);
    u32* bar     = (u32*)alloc(16384 * 4);   // flag-barrier regions

    // ---- 1: all prep (also zeroes out_attn and all flag lines) ----
    prep_all<<<dim3(34057), 256, 0, stream>>>(
        wih_w, whh_w, enc1, enc0, wq_w, wq_d, wo_w, fcw, toks, emb, spe,
        bih_w, bhh_w, bih_d, bhh_d, wih_d, whh_d, wo_d,
        WihH, WihL, WhhH, WhhL, enc1H, enc1L, enc0H, enc0L,
        wqTH, wqTL, wqdTH, wqdTL, woB, fcwB, enc1T, xinH, xinL,
        woCH, woCL, WpH, WpL, biasc, biasd, out_attn, bar);

    // ---- 2: merged head GEMMs (sq1 / E0q / E0o / xW) ----
    gemm_head<<<dim3(940), 256, 0, stream>>>(
        enc1H, enc1L, wqTH, wqTL, enc0H, enc0L, wqdTH, wqdTL,
        woCH, woCL, xinH, xinL, WihH, WihL,
        sq1H, sq1L, E0q, E0o, xW, biasc);

    // ---- 3: document-level loop (flag barriers) ----
    doc_mega<<<dim3(128), 256, 0, stream>>>(
        enc0, E0q, E0o, mask, emb, WpH, WpL, biasd, wo_d,
        dxP, hP0, hP1, dcP, dscP, dsent, out_last, bar);

    // ---- 4: word-level LSTM recurrence (flag barriers) ----
    word_mega<<<dim3(256), 512, 0, stream>>>(
        dsent, hAllP, hAllH, hAllL, WhhH, WhhL, xW, catB, bar);

    // ---- 5: batched word attention scores ----
    gemm_bt<true, 1, 0><<<dim3(4, 5, 8), 256, 0, stream>>>(
        hAllH, hAllL, 0, 0, sq1H, sq1L, 512, 204800L,
        wsS, nullptr, nullptr, 512, 327680L, nullptr, 512);

    // ---- 6: softmax -> out_watt + Pbf ----
    word_softmax<<<dim3(5120), 256, 0, stream>>>(wsS, mask, out_watt, Pbf);

    // ---- 7: ctx = P @ enc1 -> catB[:, 0:512] ----
    gemm_bt<false, 0, 4><<<dim3(4, 5, 8), 256, 0, stream>>>(
        Pbf, nullptr, 416, 266240L, enc1T, nullptr, 416, 212992L,
        nullptr, catB, nullptr, 1024, 655360L, nullptr, 416);

    // ---- 8: out = tanh(cat @ wo^T) ----
    gemm_bt<false, 0, 3><<<dim3(4, 40, 1), 256, 0, stream>>>(
        catB, nullptr, 1024, 0, woB, nullptr, 1024, 0,
        nullptr, Alog, nullptr, 512, 0, nullptr, 1024);

    // ---- 9: logits via global_load_lds GEMM + nontemporal C stores ----
    gemm_lds_bias<<<dim3(40, 250, 1), 256, 0, stream>>>(
        Alog, fcwB, out_dec, fcb, 32000, 512);
}

// Round 11
// 928.831 us; speedup vs baseline: 6.8019x; 1.0520x over previous
//
#include <hip/hip_runtime.h>
#include <cstdint>

typedef unsigned short u16;
typedef unsigned int u32;
typedef __attribute__((ext_vector_type(8))) short bf16x8;
typedef __attribute__((ext_vector_type(8))) unsigned short u16x8;
typedef __attribute__((ext_vector_type(4))) float f32x4;

struct us4 { u16 a, b, c, d; };

__device__ __forceinline__ u16 f2bf(float f) {
    uint32_t u = __float_as_uint(f);
    uint32_t r = (u + 0x7FFFu + ((u >> 16) & 1u)) >> 16;
    return (u16)r;
}
__device__ __forceinline__ float bf2f(u16 h) { return __uint_as_float(((uint32_t)h) << 16); }
__device__ __forceinline__ float sigm(float x) { return 1.f / (1.f + expf(-x)); }
__device__ __forceinline__ float dot4(float4 a, float4 b) {
    return a.x * b.x + a.y * b.y + a.z * b.z + a.w * b.w;
}
__device__ __forceinline__ float wave_sum(float v) {
#pragma unroll
    for (int o = 32; o; o >>= 1) v += __shfl_down(v, o);
    return v;
}
__device__ __forceinline__ float wave_max(float v) {
#pragma unroll
    for (int o = 32; o; o >>= 1) v = fmaxf(v, __shfl_down(v, o));
    return v;
}

// Coherent (device-scope, relaxed) u32 access: no cache maintenance.
__device__ __forceinline__ void ast(u32* p, u32 v) {
    __hip_atomic_store(p, v, __ATOMIC_RELAXED, __HIP_MEMORY_SCOPE_AGENT);
}
__device__ __forceinline__ u32 ald(const u32* p) {
    return __hip_atomic_load(p, __ATOMIC_RELAXED, __HIP_MEMORY_SCOPE_AGENT);
}
__device__ __forceinline__ u32 packsplit(float v) {
    u16 h = f2bf(v);
    u16 l = f2bf(v - bf2f(h));
    return (u32)h | ((u32)l << 16);
}

// Flag barrier: one own-cacheline flag per block, parallel poll.
template <int NBLK>
__device__ __forceinline__ void fbar(u32* flags, int me, u32 gen) {
    asm volatile("s_waitcnt vmcnt(0)" ::: "memory");
    __syncthreads();
    if (threadIdx.x == 0) ast(&flags[me * 32], gen);
    if (threadIdx.x < NBLK) {
        while (ald(&flags[threadIdx.x * 32]) < gen)
            __builtin_amdgcn_s_sleep(1);
    }
    __syncthreads();
    asm volatile("" ::: "memory");
}

// ---------------------------------------------------------------------------
// Generic 128x128-tile BT GEMM (register-staged) — mid-size GEMMs.
// ---------------------------------------------------------------------------
template <bool SPLIT, int AMODE, int EPI, int XMAJ = 0>
__global__ __launch_bounds__(256) void gemm_bt(
    const u16* __restrict__ AH, const u16* __restrict__ AL, int lda, long strideA,
    const u16* __restrict__ BH, const u16* __restrict__ BL, int ldb, long strideB,
    float* __restrict__ C, u16* __restrict__ CH, u16* __restrict__ CL,
    int ldc, long strideC, const float* __restrict__ bias, int K)
{
    constexpr int TL = 40;
    constexpr int CHK = 128 * TL;
    __shared__ u16 sm[(SPLIT ? 4 : 2) * CHK];
    u16* sAH = sm;
    u16* sBH = sm + CHK;
    u16* sAL = SPLIT ? sm + 2 * CHK : sm;
    u16* sBL = SPLIT ? sm + 3 * CHK : sm;

    const int tid = threadIdx.x;
    const int lane = tid & 63, w = tid >> 6;
    const int wm = w >> 1, wn = w & 1;
    const int lane15 = lane & 15, q8 = (lane >> 4) << 3;
    const int n0 = (XMAJ ? blockIdx.y : blockIdx.x) * 128;
    const int m0 = (XMAJ ? blockIdx.x : blockIdx.y) * 128;
    const int z = blockIdx.z;

    const int r = tid >> 2, c8 = (tid & 3) * 8;

    long aoff[2], boff[2];
#pragma unroll
    for (int h2 = 0; h2 < 2; ++h2) {
        int row = r + (h2 << 6);
        if (AMODE == 0) {
            aoff[h2] = strideA * z + (long)(m0 + row) * lda + c8;
        } else {
            int m = m0 + row;
            int t = m % 40, dd = m / 40;
            aoff[h2] = ((long)(t + 1) * 128 + (z * 16 + dd)) * 512 + c8;
        }
        boff[h2] = strideB * z + (long)(n0 + row) * ldb + c8;
    }

    f32x4 acc[4][4] = {};

    for (int k0 = 0; k0 < K; k0 += 32) {
#pragma unroll
        for (int h2 = 0; h2 < 2; ++h2) {
            int row = r + (h2 << 6);
            int sidx = row * TL + c8;
            *(u16x8*)&sAH[sidx] = *(const u16x8*)&AH[aoff[h2] + k0];
            *(u16x8*)&sBH[sidx] = *(const u16x8*)&BH[boff[h2] + k0];
            if constexpr (SPLIT) {
                *(u16x8*)&sAL[sidx] = *(const u16x8*)&AL[aoff[h2] + k0];
                *(u16x8*)&sBL[sidx] = *(const u16x8*)&BL[boff[h2] + k0];
            }
        }
        __syncthreads();

        bf16x8 a[4], b[4], al[4], bl[4];
#pragma unroll
        for (int i = 0; i < 4; ++i) {
            a[i] = *(const bf16x8*)&sAH[(wm * 64 + i * 16 + lane15) * TL + q8];
            b[i] = *(const bf16x8*)&sBH[(wn * 64 + i * 16 + lane15) * TL + q8];
            if constexpr (SPLIT) {
                al[i] = *(const bf16x8*)&sAL[(wm * 64 + i * 16 + lane15) * TL + q8];
                bl[i] = *(const bf16x8*)&sBL[(wn * 64 + i * 16 + lane15) * TL + q8];
            }
        }
#pragma unroll
        for (int mt = 0; mt < 4; ++mt)
#pragma unroll
            for (int nt = 0; nt < 4; ++nt) {
                acc[mt][nt] = __builtin_amdgcn_mfma_f32_16x16x32_bf16(a[mt], b[nt], acc[mt][nt], 0, 0, 0);
                if constexpr (SPLIT) {
                    acc[mt][nt] = __builtin_amdgcn_mfma_f32_16x16x32_bf16(a[mt], bl[nt], acc[mt][nt], 0, 0, 0);
                    acc[mt][nt] = __builtin_amdgcn_mfma_f32_16x16x32_bf16(al[mt], b[nt], acc[mt][nt], 0, 0, 0);
                }
            }
        __syncthreads();
    }

#pragma unroll
    for (int mt = 0; mt < 4; ++mt)
#pragma unroll
        for (int nt = 0; nt < 4; ++nt)
#pragma unroll
            for (int i = 0; i < 4; ++i) {
                int row = m0 + wm * 64 + mt * 16 + ((lane >> 4) << 2) + i;
                int col = n0 + wn * 64 + nt * 16 + lane15;
                long off = strideC * z + (long)row * ldc + col;
                float v = acc[mt][nt][i];
                if constexpr (EPI == 0) {
                    C[off] = v;
                } else if constexpr (EPI == 1) {
                    C[off] = v + bias[col];
                } else if constexpr (EPI == 2) {
                    u16 h_ = f2bf(v);
                    CH[off] = h_;
                    CL[off] = f2bf(v - bf2f(h_));
                } else if constexpr (EPI == 3) {
                    CH[off] = f2bf(tanhf(v));
                } else {
                    CH[off] = f2bf(v);
                }
            }
}

// ---------------------------------------------------------------------------
// Head GEMM body (shared by standalone kernel + merged doc kernel).
// bid mapping: 0-99 sq1; 100-199 E0q; 200-299 E0o; 300-939 xW.
// ---------------------------------------------------------------------------
__device__ __forceinline__ void run_head_gemm(
    int bid, u16* __restrict__ smem,
    const u16* __restrict__ enc1H, const u16* __restrict__ enc1L,
    const u16* __restrict__ wqTH,  const u16* __restrict__ wqTL,
    const u16* __restrict__ enc0H, const u16* __restrict__ enc0L,
    const u16* __restrict__ wqdTH, const u16* __restrict__ wqdTL,
    const u16* __restrict__ woCH,  const u16* __restrict__ woCL,
    const u16* __restrict__ xinH,  const u16* __restrict__ xinL,
    const u16* __restrict__ WihH,  const u16* __restrict__ WihL,
    u16* __restrict__ sq1H, u16* __restrict__ sq1L,
    float* __restrict__ E0q, float* __restrict__ E0o,
    float* __restrict__ xW, const float* __restrict__ biasc)
{
    constexpr int TL = 40;
    constexpr int CHK = 128 * TL;
    u16* sAH = smem;
    u16* sBH = smem + CHK;
    u16* sAL = smem + 2 * CHK;
    u16* sBL = smem + 3 * CHK;

    const u16 *AH, *AL, *BH, *BL;
    int task, n0, m0, ldc;
    if (bid < 300) {
        task = bid / 100;
        int rr = bid % 100;
        n0 = (rr & 3) * 128; m0 = (rr >> 2) * 128; ldc = 512;
        if (task == 0)      { AH = enc1H; AL = enc1L; BH = wqTH;  BL = wqTL;  }
        else if (task == 1) { AH = enc0H; AL = enc0L; BH = wqdTH; BL = wqdTL; }
        else                { AH = enc0H; AL = enc0L; BH = woCH;  BL = woCL;  }
    } else {
        task = 3;
        int rr = bid - 300;
        n0 = (rr & 15) * 128; m0 = (rr >> 4) * 128; ldc = 2048;
        AH = xinH; AL = xinL; BH = WihH; BL = WihL;
    }

    const int tid = threadIdx.x;
    const int lane = tid & 63, w = tid >> 6;
    const int wm = w >> 1, wn = w & 1;
    const int lane15 = lane & 15, q8 = (lane >> 4) << 3;
    const int r = tid >> 2, c8 = (tid & 3) * 8;

    long aoff[2], boff[2];
#pragma unroll
    for (int h2 = 0; h2 < 2; ++h2) {
        int row = r + (h2 << 6);
        aoff[h2] = (long)(m0 + row) * 512 + c8;
        boff[h2] = (long)(n0 + row) * 512 + c8;
    }

    f32x4 acc[4][4] = {};
    for (int k0 = 0; k0 < 512; k0 += 32) {
#pragma unroll
        for (int h2 = 0; h2 < 2; ++h2) {
            int row = r + (h2 << 6);
            int sidx = row * TL + c8;
            *(u16x8*)&sAH[sidx] = *(const u16x8*)&AH[aoff[h2] + k0];
            *(u16x8*)&sBH[sidx] = *(const u16x8*)&BH[boff[h2] + k0];
            *(u16x8*)&sAL[sidx] = *(const u16x8*)&AL[aoff[h2] + k0];
            *(u16x8*)&sBL[sidx] = *(const u16x8*)&BL[boff[h2] + k0];
        }
        __syncthreads();
        bf16x8 a[4], b[4], al[4], bl[4];
#pragma unroll
        for (int i = 0; i < 4; ++i) {
            a[i]  = *(const bf16x8*)&sAH[(wm * 64 + i * 16 + lane15) * TL + q8];
            b[i]  = *(const bf16x8*)&sBH[(wn * 64 + i * 16 + lane15) * TL + q8];
            al[i] = *(const bf16x8*)&sAL[(wm * 64 + i * 16 + lane15) * TL + q8];
            bl[i] = *(const bf16x8*)&sBL[(wn * 64 + i * 16 + lane15) * TL + q8];
        }
#pragma unroll
        for (int mt = 0; mt < 4; ++mt)
#pragma unroll
            for (int nt = 0; nt < 4; ++nt) {
                acc[mt][nt] = __builtin_amdgcn_mfma_f32_16x16x32_bf16(a[mt],  b[nt],  acc[mt][nt], 0, 0, 0);
                acc[mt][nt] = __builtin_amdgcn_mfma_f32_16x16x32_bf16(a[mt],  bl[nt], acc[mt][nt], 0, 0, 0);
                acc[mt][nt] = __builtin_amdgcn_mfma_f32_16x16x32_bf16(al[mt], b[nt],  acc[mt][nt], 0, 0, 0);
            }
        __syncthreads();
    }

#pragma unroll
    for (int mt = 0; mt < 4; ++mt)
#pragma unroll
        for (int nt = 0; nt < 4; ++nt)
#pragma unroll
            for (int i = 0; i < 4; ++i) {
                int row = m0 + wm * 64 + mt * 16 + ((lane >> 4) << 2) + i;
                int col = n0 + wn * 64 + nt * 16 + lane15;
                long off = (long)row * ldc + col;
                float v = acc[mt][nt][i];
                if (task == 0) {
                    u16 h_ = f2bf(v);
                    sq1H[off] = h_;
                    sq1L[off] = f2bf(v - bf2f(h_));
                } else if (task == 1) {
                    E0q[off] = v;
                } else if (task == 2) {
                    E0o[off] = v;
                } else {
                    xW[off] = v + biasc[col];
                }
            }
}

__global__ __launch_bounds__(256) void gemm_head_k(
    int bid_off,
    const u16* __restrict__ enc1H, const u16* __restrict__ enc1L,
    const u16* __restrict__ wqTH,  const u16* __restrict__ wqTL,
    const u16* __restrict__ enc0H, const u16* __restrict__ enc0L,
    const u16* __restrict__ wqdTH, const u16* __restrict__ wqdTL,
    const u16* __restrict__ woCH,  const u16* __restrict__ woCL,
    const u16* __restrict__ xinH,  const u16* __restrict__ xinL,
    const u16* __restrict__ WihH,  const u16* __restrict__ WihL,
    u16* __restrict__ sq1H, u16* __restrict__ sq1L,
    float* __restrict__ E0q, float* __restrict__ E0o,
    float* __restrict__ xW, const float* __restrict__ biasc)
{
    __shared__ u16 sm[4 * 128 * 40];
    run_head_gemm(blockIdx.x + bid_off, sm,
                  enc1H, enc1L, wqTH, wqTL, enc0H, enc0L, wqdTH, wqdTL,
                  woCH, woCL, xinH, xinL, WihH, WihL,
                  sq1H, sq1L, E0q, E0o, xW, biasc);
}

// ---------------------------------------------------------------------------
// Logits GEMM: 256x128 tile, 512 threads (8 waves = 4m x 2n),
// global_load_lds staging + nontemporal C stores.
// ---------------------------------------------------------------------------
#define GLOAD_LDS16(gsrc, ldst) \
    __builtin_amdgcn_global_load_lds((const __attribute__((address_space(1))) u32*)(gsrc), \
                                     (__attribute__((address_space(3))) u32*)(ldst), 16, 0, 0)

__global__ __launch_bounds__(512) void gemm_lds_bias256(
    const u16* __restrict__ A, const u16* __restrict__ B,
    float* __restrict__ C, const float* __restrict__ bias, int ldc, int K)
{
    __shared__ u16 sA[256 * 32];
    __shared__ u16 sB[128 * 32];

    const int tid = threadIdx.x;
    const int lane = tid & 63, w = tid >> 6;
    const int wm = w >> 1, wn = w & 1;        // 4m x 2n wave grid
    const int lane15 = lane & 15, q8 = (lane >> 4) << 3;
    const int m0 = blockIdx.x * 256;          // m fast: consecutive bids share B
    const int n0 = blockIdx.y * 128;

    const int srow = lane >> 2, schunk = (lane & 3) * 8;

    f32x4 acc[4][4] = {};

    for (int k0 = 0; k0 < K; k0 += 32) {
        // A: 256 rows, 32 rows/wave (2 calls); B: 128 rows, 16 rows/wave (1 call)
#pragma unroll
        for (int c = 0; c < 2; ++c) {
            int base_r = w * 32 + c * 16;
            const u16* ga = A + (long)(m0 + base_r + srow) * 512 + k0 + schunk;
            GLOAD_LDS16(ga, &sA[base_r * 32]);
        }
        {
            int base_r = w * 16;
            const u16* gb = B + (long)(n0 + base_r + srow) * 512 + k0 + schunk;
            GLOAD_LDS16(gb, &sB[base_r * 32]);
        }
        __syncthreads();

        bf16x8 a[4], b[4];
#pragma unroll
        for (int i = 0; i < 4; ++i) {
            a[i] = *(const bf16x8*)&sA[(wm * 64 + i * 16 + lane15) * 32 + q8];
            b[i] = *(const bf16x8*)&sB[(wn * 64 + i * 16 + lane15) * 32 + q8];
        }
#pragma unroll
        for (int mt = 0; mt < 4; ++mt)
#pragma unroll
            for (int nt = 0; nt < 4; ++nt)
                acc[mt][nt] = __builtin_amdgcn_mfma_f32_16x16x32_bf16(a[mt], b[nt], acc[mt][nt], 0, 0, 0);
        __syncthreads();
    }

#pragma unroll
    for (int mt = 0; mt < 4; ++mt)
#pragma unroll
        for (int nt = 0; nt < 4; ++nt)
#pragma unroll
            for (int i = 0; i < 4; ++i) {
                int row = m0 + wm * 64 + mt * 16 + ((lane >> 4) << 2) + i;
                int col = n0 + wn * 64 + nt * 16 + lane15;
                __builtin_nontemporal_store(acc[mt][nt][i] + bias[col], &C[(long)row * ldc + col]);
            }
}

// ---------------------------------------------------------------------------
// Merged kernel: blocks 0-127 = doc loop; blocks 128-867 = sq1/xW GEMMs
// (fill CUs left idle by doc's barrier waits; always terminate -> no deadlock).
// ---------------------------------------------------------------------------
__global__ __launch_bounds__(256) void doc_plus_gemm(
    const float* __restrict__ enc0, const float* __restrict__ E0q,
    const float* __restrict__ E0o, const unsigned char* __restrict__ mask,
    const float* __restrict__ emb,
    const u16* __restrict__ WpH, const u16* __restrict__ WpL,
    const float* __restrict__ biasd, const float* __restrict__ wo_d,
    u32* __restrict__ dxP, u32* __restrict__ hP0, u32* __restrict__ hP1,
    u32* __restrict__ dcP, u32* __restrict__ dscP,
    float* __restrict__ dsent, float* __restrict__ out_last, u32* bar,
    const u16* __restrict__ enc1H, const u16* __restrict__ enc1L,
    const u16* __restrict__ wqTH,  const u16* __restrict__ wqTL,
    const u16* __restrict__ enc0H, const u16* __restrict__ enc0L,
    const u16* __restrict__ wqdTH, const u16* __restrict__ wqdTL,
    const u16* __restrict__ woCH,  const u16* __restrict__ woCL,
    const u16* __restrict__ xinH,  const u16* __restrict__ xinL,
    const u16* __restrict__ WihH,  const u16* __restrict__ WihL,
    u16* __restrict__ sq1H, u16* __restrict__ sq1L,
    float* __restrict__ xW, const float* __restrict__ biasc)
{
    __shared__ __attribute__((aligned(16))) char SM[75776];

    if (blockIdx.x >= 128) {
        int g = blockIdx.x - 128;
        int bid = (g < 100) ? g : g + 200;     // 0-99 sq1, 300-939 xW
        run_head_gemm(bid, (u16*)SM,
                      enc1H, enc1L, wqTH, wqTL, enc0H, enc0L, wqdTH, wqdTL,
                      woCH, woCL, xinH, xinL, WihH, WihL,
                      sq1H, sq1L, nullptr, nullptr, xW, biasc);
        return;
    }

    // ---- doc region ----
    u16* xhH = (u16*)SM;                         // [16][1032]
    u16* xhL = xhH + 16 * 1032;
    float* fb = (float*)(SM + 66048);
    float* red4 = fb;                            // [4][272]
    float* aux2 = fb + 1088;                     // [512]
    float* sc_s = fb + 1600;                     // [512]
    float* whoh_s = fb + 2112;                   // [32]
    float* ctxp = fb + 2144;                     // [8][32]
    float* rtmp = fb + 2400;                     // [8]

    const int blk = blockIdx.x, tid = threadIdx.x;
    const int w = tid >> 6, lane = tid & 63;
    const int b_ = blk >> 4, s = blk & 15;
    const int lane15 = lane & 15, q8 = (lane >> 4) << 3;
    u32* fF = bar;
    u32* fG = bar + 4096 + b_ * 512;
    u32 genF = 0, genG = 0;

    for (int q = tid; q < 8 * 1032; q += 256) { xhH[8 * 1032 + q] = 0; xhL[8 * 1032 + q] = 0; }

    {   // init: dh = dc = mean_j enc0[b,j,:], dx = emb[SOD]
        int dd = tid & 31, part = tid >> 5;
        const float* p0 = enc0 + ((long)b_ * 400 + part * 50) * 512 + s * 32 + dd;
        float sm = 0.f;
#pragma unroll 10
        for (int j = 0; j < 50; ++j) { sm += *p0; p0 += 512; }
        ctxp[part * 32 + dd] = sm;
        __syncthreads();
        if (tid < 32) {
            float m = 0.f;
#pragma unroll
            for (int p = 0; p < 8; ++p) m += ctxp[p * 32 + tid];
            m *= (1.f / 400.f);
            int e = s * 32 + tid;
            ast(&hP0[b_ * 512 + e], packsplit(m));
            ast(&dcP[b_ * 512 + e], __float_as_uint(m));
            ast(&dxP[b_ * 512 + e], packsplit(emb[1024 + e]));
        }
    }
    fbar<128>(fF, blk, ++genF);

    const int eb_b = tid & 7, eb_u4 = tid >> 3, eb_u = blk * 4 + eb_u4;
    float dcr = 0.f;
    if (tid < 32) dcr = __uint_as_float(ald(&dcP[eb_b * 512 + eb_u]));

    const u16* bh_base = WpH + ((long)blk * 16 + lane15) * 1024 + (w << 8) + q8;
    const u16* bl_base = WpL + ((long)blk * 16 + lane15) * 1024 + (w << 8) + q8;
    const u16* ah_base = xhH + lane15 * 1032 + (w << 8) + q8;
    const u16* al_base = xhL + lane15 * 1032 + (w << 8) + q8;

    for (int t = 0; t < 16; ++t) {
        u32* hinP = (t & 1) ? hP1 : hP0;
        u32* houtP = (t & 1) ? hP0 : hP1;

        // ---- A: stage packed x|h into LDS (2 batches of 16 coherent loads) ----
#pragma unroll
        for (int half = 0; half < 2; ++half) {
            u32 px[8], ph[8];
#pragma unroll
            for (int j = 0; j < 8; ++j) {
                int q = half * 2048 + j * 256 + tid;
                px[j] = ald(&dxP[q]);
                ph[j] = ald(&hinP[q]);
            }
#pragma unroll
            for (int j = 0; j < 8; ++j) {
                int q = half * 2048 + j * 256 + tid;
                int o = (q >> 9) * 1032 + (q & 511);
                xhH[o] = (u16)px[j];           xhL[o] = (u16)(px[j] >> 16);
                xhH[o + 512] = (u16)ph[j];     xhL[o + 512] = (u16)(ph[j] >> 16);
            }
        }
        __syncthreads();

        // 4-way K-split MFMA
        f32x4 acc = {};
#pragma unroll
        for (int k0 = 0; k0 < 256; k0 += 32) {
            bf16x8 aH = *(const bf16x8*)&ah_base[k0];
            bf16x8 aL = *(const bf16x8*)&al_base[k0];
            bf16x8 bH = *(const bf16x8*)&bh_base[k0];
            bf16x8 bL = *(const bf16x8*)&bl_base[k0];
            acc = __builtin_amdgcn_mfma_f32_16x16x32_bf16(aH, bH, acc, 0, 0, 0);
            acc = __builtin_amdgcn_mfma_f32_16x16x32_bf16(aH, bL, acc, 0, 0, 0);
            acc = __builtin_amdgcn_mfma_f32_16x16x32_bf16(aL, bH, acc, 0, 0, 0);
        }
#pragma unroll
        for (int i = 0; i < 4; ++i)
            red4[w * 272 + ((lane >> 4) * 4 + i) * 17 + lane15] = acc[i];
        __syncthreads();

        if (tid < 32) {
            float g4[4];
#pragma unroll
            for (int g = 0; g < 4; ++g)
                g4[g] = red4[0 * 272 + eb_b * 17 + eb_u4 * 4 + g] + red4[1 * 272 + eb_b * 17 + eb_u4 * 4 + g]
                      + red4[2 * 272 + eb_b * 17 + eb_u4 * 4 + g] + red4[3 * 272 + eb_b * 17 + eb_u4 * 4 + g];
            float gi = g4[0] + biasd[eb_u];
            float gf = g4[1] + biasd[512 + eb_u];
            float gg = g4[2] + biasd[1024 + eb_u];
            float go = g4[3] + biasd[1536 + eb_u];
            dcr = sigm(gf) * dcr + sigm(gi) * tanhf(gg);
            float hv = sigm(go) * tanhf(dcr);
            ast(&houtP[eb_b * 512 + eb_u], packsplit(hv));
        }
        fbar<128>(fF, blk, ++genF);

        // ---- B: scores (j-slice) + whoh (8 rows/wave) ----
        {
            u32 p0 = ald(&houtP[b_ * 512 + tid]);
            u32 p1 = ald(&houtP[b_ * 512 + 256 + tid]);
            aux2[tid] = bf2f((u16)p0) + bf2f((u16)(p0 >> 16));
            aux2[256 + tid] = bf2f((u16)p1) + bf2f((u16)(p1 >> 16));
            __syncthreads();
            for (int jj = w; jj < 25; jj += 4) {
                int j = s * 25 + jj;
                const float4* er = (const float4*)(E0q + ((long)b_ * 400 + j) * 512) + lane * 2;
                const float4* hv = (const float4*)aux2 + lane * 2;
                float sv = dot4(er[0], hv[0]) + dot4(er[1], hv[1]);
                sv = wave_sum(sv);
                if (lane == 0)
                    ast(&dscP[b_ * 400 + j], __float_as_uint(mask[b_ * 400 + j] ? -1e9f : sv));
            }
#pragma unroll
            for (int r = 0; r < 8; ++r) {
                int d = s * 32 + w * 8 + r;
                const float4* wr = (const float4*)(wo_d + (long)d * 1024 + 512) + lane * 2;
                const float4* hv = (const float4*)aux2 + lane * 2;
                float sv = dot4(wr[0], hv[0]) + dot4(wr[1], hv[1]);
                sv = wave_sum(sv);
                if (lane == 0) whoh_s[w * 8 + r] = sv;
            }
        }
        fbar<16>(fG, s, ++genG);

        // ---- C: softmax + ctx (d-slice) + out ----
        {
            float v0 = __uint_as_float(ald(&dscP[b_ * 400 + tid]));
            bool h1 = (tid + 256) < 400;
            float v1 = h1 ? __uint_as_float(ald(&dscP[b_ * 400 + tid + 256])) : -1e30f;
            float mx = wave_max(fmaxf(v0, v1));
            if (lane == 0) rtmp[w] = mx;
            __syncthreads();
            float M = fmaxf(fmaxf(rtmp[0], rtmp[1]), fmaxf(rtmp[2], rtmp[3]));
            float e0 = expf(v0 - M);
            float e1 = h1 ? expf(v1 - M) : 0.f;
            float sv = wave_sum(e0 + e1);
            if (lane == 0) rtmp[4 + w] = sv;
            __syncthreads();
            float inv = 1.f / (rtmp[4] + rtmp[5] + rtmp[6] + rtmp[7]);
            sc_s[tid] = e0 * inv;
            if (h1) sc_s[tid + 256] = e1 * inv;
            __syncthreads();
            int dd = tid & 31, part = tid >> 5;
            const float* eo = E0o + ((long)b_ * 400 + part * 50) * 512 + s * 32 + dd;
            float acc2 = 0.f;
#pragma unroll 10
            for (int j = 0; j < 50; ++j) { acc2 += sc_s[part * 50 + j] * (*eo); eo += 512; }
            ctxp[part * 32 + dd] = acc2;
            __syncthreads();
            if (tid < 32) {
                int d = s * 32 + tid;
                float o = whoh_s[tid];
#pragma unroll
                for (int p = 0; p < 8; ++p) o += ctxp[p * 32 + tid];
                float val = tanhf(o);
                ast(&dxP[b_ * 512 + d], packsplit(val));
                dsent[((b_ << 4) + t) * 512 + d] = val;
                if (t == 15) out_last[b_ * 512 + d] = val;
            }
        }
        fbar<128>(fF, blk, ++genF);
    }
}

// ---------------------------------------------------------------------------
// Word-level loop (unchanged from round 10).
// ---------------------------------------------------------------------------
__global__ __launch_bounds__(512) void word_mega(
    const float* __restrict__ sentS,
    u32* __restrict__ hAllP,
    u16* __restrict__ hAllH, u16* __restrict__ hAllL,
    const u16* __restrict__ WhhH, const u16* __restrict__ WhhL,
    const float* __restrict__ xW,
    u16* __restrict__ catB, u32* bar)
{
    __shared__ float red[8][4][256];
    const int tid = threadIdx.x, blk = blockIdx.x;
    const int b2t = blk >> 5;
    const int u0 = (blk & 31) << 4;
    u32* fG = bar + 8192 + b2t * 1024;
    u32 genG = 0;

    float wcr = 0.f;
    long cidx = 0;
    int my_b2 = 0, my_u = 0;
    if (tid < 256) {
        my_b2 = b2t * 16 + (tid >> 4);
        my_u = u0 + (tid & 15);
        cidx = (long)my_b2 * 512 + my_u;
        wcr = sentS[cidx];
        ast(&hAllP[cidx], packsplit(wcr));
    }
    fbar<32>(fG, blk & 31, ++genG);

    const int w = tid >> 6, lane = tid & 63;
    const int lane15 = lane & 15, q8 = (lane >> 4) << 3;
    const long arowE = (long)(b2t * 16 + lane15) * 512 + w * 64 + q8;
    long brow[4];
#pragma unroll
    for (int g = 0; g < 4; ++g)
        brow[g] = (long)(g * 512 + u0 + lane15) * 512 + w * 64 + q8;

    for (int t = 0; t < 40; ++t) {
        const u32* hP = hAllP + (long)t * 65536;

        u32 ph[16];
#pragma unroll
        for (int j = 0; j < 16; ++j)
            ph[j] = ald(&hP[arowE + (j >> 3) * 32 + (j & 7)]);

        float xw0 = 0.f, xw1 = 0.f, xw2 = 0.f, xw3 = 0.f;
        if (tid < 256) {
            const float* xr = xW + (long)t * 262144 + (long)my_b2 * 2048;
            xw0 = xr[my_u]; xw1 = xr[512 + my_u]; xw2 = xr[1024 + my_u]; xw3 = xr[1536 + my_u];
        }

        f32x4 acc[4] = {};
#pragma unroll
        for (int half = 0; half < 2; ++half) {
            int k0 = half * 32;
            bf16x8 aH, aL;
#pragma unroll
            for (int j = 0; j < 8; ++j) {
                u32 p = ph[half * 8 + j];
                aH[j] = (short)(p & 0xffffu);
                aL[j] = (short)(p >> 16);
            }
#pragma unroll
            for (int g = 0; g < 4; ++g) {
                bf16x8 bH = *(const bf16x8*)&WhhH[brow[g] + k0];
                bf16x8 bL = *(const bf16x8*)&WhhL[brow[g] + k0];
                acc[g] = __builtin_amdgcn_mfma_f32_16x16x32_bf16(aH, bH, acc[g], 0, 0, 0);
                acc[g] = __builtin_amdgcn_mfma_f32_16x16x32_bf16(aH, bL, acc[g], 0, 0, 0);
                acc[g] = __builtin_amdgcn_mfma_f32_16x16x32_bf16(aL, bH, acc[g], 0, 0, 0);
            }
        }
#pragma unroll
        for (int g = 0; g < 4; ++g)
#pragma unroll
            for (int i = 0; i < 4; ++i)
                red[w][g][((lane >> 4) * 4 + i) * 16 + lane15] = acc[g][i];
        __syncthreads();

        if (tid < 256) {
            float g4[4] = {0.f, 0.f, 0.f, 0.f};
#pragma unroll
            for (int ks = 0; ks < 8; ++ks)
#pragma unroll
                for (int g = 0; g < 4; ++g)
                    g4[g] += red[ks][g][tid];
            float gi = g4[0] + xw0;
            float gf = g4[1] + xw1;
            float gg = g4[2] + xw2;
            float go = g4[3] + xw3;
            wcr = sigm(gf) * wcr + sigm(gi) * tanhf(gg);
            float hv = sigm(go) * tanhf(wcr);
            u16 hh = f2bf(hv);
            u16 ll = f2bf(hv - bf2f(hh));
            long o = (long)(t + 1) * 65536 + cidx;
            ast(&hAllP[o], (u32)hh | ((u32)ll << 16));
            hAllH[o] = hh;
            hAllL[o] = ll;
            catB[((long)my_b2 * 40 + t) * 1024 + 512 + my_u] = hh;
        }
        fbar<32>(fG, blk & 31, ++genG);
    }
}

// ---------------------------------------------------------------------------
// All prep work in one region-dispatched kernel.
// ---------------------------------------------------------------------------
__device__ __forceinline__ void split1(const float* __restrict__ src,
                                       u16* __restrict__ H, u16* __restrict__ L, long i)
{
    float4 v = ((const float4*)src)[i];
    u16 h0 = f2bf(v.x), h1 = f2bf(v.y), h2 = f2bf(v.z), h3 = f2bf(v.w);
    ((us4*)H)[i] = {h0, h1, h2, h3};
    ((us4*)L)[i] = {f2bf(v.x - bf2f(h0)), f2bf(v.y - bf2f(h1)),
                    f2bf(v.z - bf2f(h2)), f2bf(v.w - bf2f(h3))};
}
__device__ __forceinline__ void wqT1(const float* __restrict__ wq,
                                     u16* __restrict__ H, u16* __restrict__ L, int idx)
{
    int e = idx >> 9, d = idx & 511;
    float v = wq[(long)d * 512 + e];
    u16 h = f2bf(v);
    H[idx] = h;
    L[idx] = f2bf(v - bf2f(h));
}

__global__ __launch_bounds__(256) void prep_all(
    const float* __restrict__ wih_w, const float* __restrict__ whh_w,
    const float* __restrict__ enc1, const float* __restrict__ enc0,
    const float* __restrict__ wq_w, const float* __restrict__ wq_d,
    const float* __restrict__ wo_w, const float* __restrict__ fcw,
    const int* __restrict__ toks, const float* __restrict__ emb,
    const float* __restrict__ spe,
    const float* __restrict__ bih_w, const float* __restrict__ bhh_w,
    const float* __restrict__ bih_d, const float* __restrict__ bhh_d,
    const float* __restrict__ wih_d, const float* __restrict__ whh_d,
    const float* __restrict__ wo_d,
    u16* __restrict__ WihH, u16* __restrict__ WihL,
    u16* __restrict__ WhhH, u16* __restrict__ WhhL,
    u16* __restrict__ enc1H, u16* __restrict__ enc1L,
    u16* __restrict__ enc0H, u16* __restrict__ enc0L,
    u16* __restrict__ wqTH, u16* __restrict__ wqTL,
    u16* __restrict__ wqdTH, u16* __restrict__ wqdTL,
    u16* __restrict__ woB, u16* __restrict__ fcwB, u16* __restrict__ enc1T,
    u16* __restrict__ xinH, u16* __restrict__ xinL,
    u16* __restrict__ woCH, u16* __restrict__ woCL,
    u16* __restrict__ WpH, u16* __restrict__ WpL,
    float* __restrict__ biasc, float* __restrict__ biasd,
    float* __restrict__ out_attn, u32* __restrict__ bar)
{
    int b = blockIdx.x;
    const int tid = threadIdx.x;

    if (b < 1024) { split1(wih_w, WihH, WihL, (long)b * 256 + tid); return; }
    b -= 1024;
    if (b < 1024) { split1(whh_w, WhhH, WhhL, (long)b * 256 + tid); return; }
    b -= 1024;
    if (b < 1600) { split1(enc1, enc1H, enc1L, (long)b * 256 + tid); return; }
    b -= 1600;
    if (b < 1600) { split1(enc0, enc0H, enc0L, (long)b * 256 + tid); return; }
    b -= 1600;
    if (b < 1024) { wqT1(wq_w, wqTH, wqTL, b * 256 + tid); return; }
    b -= 1024;
    if (b < 1024) { wqT1(wq_d, wqdTH, wqdTL, b * 256 + tid); return; }
    b -= 1024;
    if (b < 512) {
        long i = (long)b * 256 + tid;
        float4 v = ((const float4*)wo_w)[i];
        ((us4*)woB)[i] = {f2bf(v.x), f2bf(v.y), f2bf(v.z), f2bf(v.w)};
        return;
    }
    b -= 512;
    if (b < 16000) {
        long i = (long)b * 256 + tid;
        float4 v = ((const float4*)fcw)[i];
        ((us4*)fcwB)[i] = {f2bf(v.x), f2bf(v.y), f2bf(v.z), f2bf(v.w)};
        return;
    }
    b -= 16000;
    if (b < 6656) {
        long idx = (long)b * 256 + tid;
        int j = (int)(idx % 416);
        long be = idx / 416;
        int e = (int)(be % 512);
        int bb = (int)(be / 512);
        float v = (j < 400) ? enc1[((long)bb * 400 + j) * 512 + e] : 0.f;
        enc1T[idx] = f2bf(v);
        return;
    }
    b -= 6656;
    if (b < 1280) {
        int g = b * 256 + tid;
        int m = g >> 6, e0 = (g & 63) << 3;
        int t = m >> 7, b2 = m & 127;
        int ne = 0;
        for (int s = 0; s < 40; ++s) ne |= (toks[b2 * 40 + s] != 1);
        int pos = ne ? (2 + (b2 & 15)) : 1;
        const float* ep = emb + (long)toks[b2 * 40 + t] * 512 + e0;
        const float* sp = spe + (long)pos * 512 + e0;
        long o = (long)m * 512 + e0;
#pragma unroll
        for (int j = 0; j < 8; ++j) {
            float v = ep[j] + sp[j];
            u16 h = f2bf(v);
            xinH[o + j] = h;
            xinL[o + j] = f2bf(v - bf2f(h));
        }
        return;
    }
    b -= 1280;
    if (b < 1) {
        for (int i = tid; i < 2048; i += 256) {
            biasc[i] = bih_w[i] + bhh_w[i];
            biasd[i] = bih_d[i] + bhh_d[i];
        }
        return;
    }
    b -= 1;
    if (b < 200) {
        out_attn[b * 256 + tid] = 0.f;
        return;
    }
    b -= 200;
    if (b < 1024) {
        int i = b * 256 + tid;
        int d = i >> 9, e = i & 511;
        float v = wo_d[(long)d * 1024 + e];
        u16 h = f2bf(v);
        woCH[i] = h;
        woCL[i] = f2bf(v - bf2f(h));
        return;
    }
    b -= 1024;
    if (b < 1024) {
        long gidx = (long)b * 256 + tid;
        int r = (int)(gidx >> 7);
        int k8 = ((int)gidx & 127) * 8;
        int u = r >> 2, g = r & 3;
        long orow = (long)(g * 512 + u);
#pragma unroll
        for (int j = 0; j < 8; ++j) {
            int k = k8 + j;
            float v = (k < 512) ? wih_d[orow * 512 + k] : whh_d[orow * 512 + k - 512];
            u16 h = f2bf(v);
            WpH[(long)r * 1024 + k] = h;
            WpL[(long)r * 1024 + k] = f2bf(v - bf2f(h));
        }
        return;
    }
    b -= 1024;
    // zero the flag-barrier region: 64 blocks x 256 = 16384 u32
    bar[b * 256 + tid] = 0;
}

__global__ __launch_bounds__(256) void word_softmax(
    const float* __restrict__ sc, const unsigned char* __restrict__ mask,
    float* __restrict__ pout, u16* __restrict__ pbf)
{
    const int r = blockIdx.x, tid = threadIdx.x;
    const int b = r / 640;
    const int wv = tid >> 6, lane = tid & 63;
    __shared__ float red[4];
    const int j1 = tid + 256;
    float v0 = sc[(long)r * 512 + tid];
    if (mask[b * 400 + tid]) v0 = -1e9f;
    float v1 = -1e30f;
    if (j1 < 400) {
        v1 = sc[(long)r * 512 + j1];
        if (mask[b * 400 + j1]) v1 = -1e9f;
    }
    float mv = wave_max(fmaxf(v0, v1));
    if (lane == 0) red[wv] = mv;
    __syncthreads();
    if (tid == 0) red[0] = fmaxf(fmaxf(red[0], red[1]), fmaxf(red[2], red[3]));
    __syncthreads();
    const float M = red[0];
    float e0 = expf(v0 - M);
    float e1 = (j1 < 400) ? expf(v1 - M) : 0.f;
    __syncthreads();
    float sv = wave_sum(e0 + e1);
    if (lane == 0) red[wv] = sv;
    __syncthreads();
    if (tid == 0) red[0] = red[0] + red[1] + red[2] + red[3];
    __syncthreads();
    const float inv = 1.f / red[0];
    float p0 = e0 * inv;
    __builtin_nontemporal_store(p0, &pout[(long)r * 400 + tid]);
    pbf[(long)r * 416 + tid] = f2bf(p0);
    if (j1 < 400) {
        float p1 = e1 * inv;
        __builtin_nontemporal_store(p1, &pout[(long)r * 400 + j1]);
        pbf[(long)r * 416 + j1] = f2bf(p1);
    } else if (j1 < 416) {
        pbf[(long)r * 416 + j1] = 0;
    }
}

// ---------------------------------------------------------------------------
extern "C" void kernel_launch(void* const* d_in, const int* in_sizes, int n_in,
                              void* d_out, int out_size, void* d_ws, size_t ws_size,
                              hipStream_t stream)
{
    (void)in_sizes; (void)n_in; (void)out_size; (void)ws_size;

    const int*   toks  = (const int*)  d_in[0];
    const float* enc0  = (const float*)d_in[1];
    const float* enc1  = (const float*)d_in[2];
    const unsigned char* mask = (const unsigned char*)d_in[3];
    const float* emb   = (const float*)d_in[4];
    const float* spe   = (const float*)d_in[5];
    const float* wih_d = (const float*)d_in[6];
    const float* whh_d = (const float*)d_in[7];
    const float* bih_d = (const float*)d_in[8];
    const float* bhh_d = (const float*)d_in[9];
    const float* wq_d  = (const float*)d_in[10];
    const float* wo_d  = (const float*)d_in[11];
    const float* wih_w = (const float*)d_in[12];
    const float* whh_w = (const float*)d_in[13];
    const float* bih_w = (const float*)d_in[14];
    const float* bhh_w = (const float*)d_in[15];
    const float* wq_w  = (const float*)d_in[16];
    const float* wo_w  = (const float*)d_in[17];
    const float* fcw   = (const float*)d_in[18];
    const float* fcb   = (const float*)d_in[19];

    float* out_dec  = (float*)d_out;                  // [8,640,32000]
    float* out_attn = out_dec + 163840000L;           // [8,16,400] zeros
    float* out_watt = out_attn + 51200;               // [128,40,400]
    float* out_last = out_watt + 2048000;             // [8,512]

    char* wsp = (char*)d_ws;
    auto alloc = [&](size_t bytes) -> void* {
        void* p = wsp;
        wsp += (bytes + 255) & ~(size_t)255;
        return p;
    };

    float* xW    = (float*)alloc(40L * 128 * 2048 * 4);
    u32* hAllP   = (u32*)alloc(41L * 128 * 512 * 4);
    u16* hAllH   = (u16*)alloc(41L * 128 * 512 * 2);
    u16* hAllL   = (u16*)alloc(41L * 128 * 512 * 2);
    u16* xinH    = (u16*)alloc(5120L * 512 * 2);
    u16* xinL    = (u16*)alloc(5120L * 512 * 2);
    u16* WihH    = (u16*)alloc(2048L * 512 * 2);
    u16* WihL    = (u16*)alloc(2048L * 512 * 2);
    u16* WhhH    = (u16*)alloc(2048L * 512 * 2);
    u16* WhhL    = (u16*)alloc(2048L * 512 * 2);
    u16* wqTH    = (u16*)alloc(512L * 512 * 2);
    u16* wqTL    = (u16*)alloc(512L * 512 * 2);
    u16* wqdTH   = (u16*)alloc(512L * 512 * 2);
    u16* wqdTL   = (u16*)alloc(512L * 512 * 2);
    u16* enc1H   = (u16*)alloc(3200L * 512 * 2);
    u16* enc1L   = (u16*)alloc(3200L * 512 * 2);
    u16* enc0H   = (u16*)alloc(3200L * 512 * 2);
    u16* enc0L   = (u16*)alloc(3200L * 512 * 2);
    u16* sq1H    = (u16*)alloc(3328L * 512 * 2);
    u16* sq1L    = (u16*)alloc(3328L * 512 * 2);
    float* E0q   = (float*)alloc(3200L * 512 * 4);
    float* E0o   = (float*)alloc(3200L * 512 * 4);
    u16* woCH    = (u16*)alloc(512L * 512 * 2);
    u16* woCL    = (u16*)alloc(512L * 512 * 2);
    u16* WpH     = (u16*)alloc(2048L * 1024 * 2);
    u16* WpL     = (u16*)alloc(2048L * 1024 * 2);
    float* wsS   = (float*)alloc(5120L * 512 * 4);
    u16* Pbf     = (u16*)alloc(5120L * 416 * 2);
    u16* enc1T   = (u16*)alloc(8L * 512 * 416 * 2);
    u16* catB    = (u16*)alloc(5120L * 1024 * 2);
    u16* woB     = (u16*)alloc(512L * 1024 * 2);
    u16* Alog    = (u16*)alloc(5120L * 512 * 2);
    u16* fcwB    = (u16*)alloc(32000L * 512 * 2);
    float* biasc = (float*)alloc(2048 * 4);
    float* biasd = (float*)alloc(2048 * 4);
    u32* dxP     = (u32*)alloc(4096 * 4);
    u32* hP0     = (u32*)alloc(4096 * 4);
    u32* hP1     = (u32*)alloc(4096 * 4);
    u32* dcP     = (u32*)alloc(4096 * 4);
    u32* dscP    = (u32*)alloc(3200 * 4);
    float* dsent = (float*)alloc(128L * 512 * 4);
    u32* bar     = (u32*)alloc(16384 * 4);

    // ---- 1: all prep (also zeroes out_attn and all flag lines) ----
    prep_all<<<dim3(34057), 256, 0, stream>>>(
        wih_w, whh_w, enc1, enc0, wq_w, wq_d, wo_w, fcw, toks, emb, spe,
        bih_w, bhh_w, bih_d, bhh_d, wih_d, whh_d, wo_d,
        WihH, WihL, WhhH, WhhL, enc1H, enc1L, enc0H, enc0L,
        wqTH, wqTL, wqdTH, wqdTL, woB, fcwB, enc1T, xinH, xinL,
        woCH, woCL, WpH, WpL, biasc, biasd, out_attn, bar);

    // ---- 2: E0q + E0o head GEMMs (needed by doc) ----
    gemm_head_k<<<dim3(200), 256, 0, stream>>>(
        100,
        enc1H, enc1L, wqTH, wqTL, enc0H, enc0L, wqdTH, wqdTL,
        woCH, woCL, xinH, xinL, WihH, WihL,
        sq1H, sq1L, E0q, E0o, xW, biasc);

    // ---- 3: doc loop (blocks 0-127) + sq1/xW GEMMs (blocks 128-867) ----
    doc_plus_gemm<<<dim3(868), 256, 0, stream>>>(
        enc0, E0q, E0o, mask, emb, WpH, WpL, biasd, wo_d,
        dxP, hP0, hP1, dcP, dscP, dsent, out_last, bar,
        enc1H, enc1L, wqTH, wqTL, enc0H, enc0L, wqdTH, wqdTL,
        woCH, woCL, xinH, xinL, WihH, WihL,
        sq1H, sq1L, xW, biasc);

    // ---- 4: word-level LSTM recurrence ----
    word_mega<<<dim3(256), 512, 0, stream>>>(
        dsent, hAllP, hAllH, hAllL, WhhH, WhhL, xW, catB, bar);

    // ---- 5: batched word attention scores ----
    gemm_bt<true, 1, 0><<<dim3(4, 5, 8), 256, 0, stream>>>(
        hAllH, hAllL, 0, 0, sq1H, sq1L, 512, 204800L,
        wsS, nullptr, nullptr, 512, 327680L, nullptr, 512);

    // ---- 6: softmax -> out_watt (nt) + Pbf ----
    word_softmax<<<dim3(5120), 256, 0, stream>>>(wsS, mask, out_watt, Pbf);

    // ---- 7: ctx = P @ enc1 -> catB[:, 0:512] ----
    gemm_bt<false, 0, 4><<<dim3(4, 5, 8), 256, 0, stream>>>(
        Pbf, nullptr, 416, 266240L, enc1T, nullptr, 416, 212992L,
        nullptr, catB, nullptr, 1024, 655360L, nullptr, 416);

    // ---- 8: out = tanh(cat @ wo^T) ----
    gemm_bt<false, 0, 3><<<dim3(4, 40, 1), 256, 0, stream>>>(
        catB, nullptr, 1024, 0, woB, nullptr, 1024, 0,
        nullptr, Alog, nullptr, 512, 0, nullptr, 1024);

    // ---- 9: logits via 256x128 global_load_lds GEMM + nt C stores ----
    gemm_lds_bias256<<<dim3(20, 250, 1), 512, 0, stream>>>(
        Alog, fcwB, out_dec, fcb, 32000, 512);
}